// Round 1
// baseline (2102.420 us; speedup 1.0000x reference)
//
#include <hip/hip_runtime.h>
#include <hip/hip_bf16.h>
#include <cstdint>

typedef unsigned short u16;
typedef __attribute__((ext_vector_type(4))) float f32x4;
typedef __attribute__((ext_vector_type(8))) short s16x8;

#define DEV __device__ __forceinline__

DEV u16 f2bf(float x) {                       // RNE f32 -> bf16
  unsigned u = __float_as_uint(x);
  u += 0x7FFFu + ((u >> 16) & 1u);
  return (u16)(u >> 16);
}
DEV float bf2f(u16 b) { return __uint_as_float(((unsigned)b) << 16); }

// block-wide (256 thr) reduce; maxop=false -> sum, true -> max
template<bool MAXOP>
DEV float blockRed256(float v) {
  for (int o = 32; o; o >>= 1) {
    float t = __shfl_xor(v, o);
    v = MAXOP ? fmaxf(v, t) : v + t;
  }
  __shared__ float s[4];
  __syncthreads();
  if ((threadIdx.x & 63) == 0) s[threadIdx.x >> 6] = v;
  __syncthreads();
  return MAXOP ? fmaxf(fmaxf(s[0], s[1]), fmaxf(s[2], s[3]))
               : (s[0] + s[1] + s[2] + s[3]);
}

// ---------------------------------------------------------------- GEMM ----
// C[M,N] = A[M,K] @ B ; A bf16 row-major. BNN=1: B f32 (K,N) row-major
// (transpose-converted into LDS). BNN=0: B bf16 (N,K) row-major (NT).
// 128x128 tile, BK=64, 4 waves (2x2), 16x16x32 bf16 MFMA, XOR-swizzled LDS.
struct GemmP {
  const u16* A; int lda; long long sAz;
  const void* B; int ldb; long long sBz;
  void* C; int ldc; long long sCz;
  int M, N, K;
  int gqa;      // 1: B batch index = (z>>4)*4 + ((z&15)>>2)   (GQA 16q/4kv)
  int czmode;   // 1: C base = b*1048576 + h*64  (attn concat store)
  const float *p0, *p1, *p2, *p3;
  float scale; int eidx; int first;
};

template<int EPI, int BNN>
__global__ __launch_bounds__(256) void gemm_k(GemmP p) {
  __shared__ u16 Al[128 * 64];
  __shared__ u16 Bl[128 * 64];
  const int z = blockIdx.z;
  const int t = threadIdx.x;
  const int lane = t & 63, wid = t >> 6;
  const int wm = wid >> 1, wn = wid & 1;
  const int m0 = blockIdx.y * 128, n0 = blockIdx.x * 128;

  const u16* Ab = p.A + (long long)z * p.sAz;
  long long bz = p.gqa ? (long long)(((z >> 4) << 2) + ((z & 15) >> 2)) * p.sBz
                       : (long long)z * p.sBz;

  f32x4 acc[4][4];
#pragma unroll
  for (int i = 0; i < 4; ++i)
#pragma unroll
    for (int j = 0; j < 4; ++j) acc[i][j] = f32x4{0.f, 0.f, 0.f, 0.f};

  for (int k0 = 0; k0 < p.K; k0 += 64) {
    {  // stage A tile (128x64 bf16), swizzled
      const int g = t & 7, r0 = t >> 3;
#pragma unroll
      for (int ps = 0; ps < 4; ++ps) {
        int row = ps * 32 + r0;
        s16x8 v = *(const s16x8*)(Ab + (long long)(m0 + row) * p.lda + k0 + g * 8);
        *(s16x8*)&Al[row * 64 + ((g ^ (row & 7)) * 8)] = v;
      }
    }
    if (BNN) {  // stage B: f32 (K,N) -> LDS (N,K) bf16, transpose
      const float* Bf = (const float*)p.B + bz;
      const int k = t & 63, nq = t >> 6;
#pragma unroll
      for (int j = 0; j < 8; ++j) {
        int nc = nq * 32 + j * 4;
        int gn = n0 + nc;
        float4 v{0.f, 0.f, 0.f, 0.f};
        if (gn + 4 <= p.N) v = *(const float4*)(Bf + (long long)(k0 + k) * p.ldb + gn);
        float vv[4] = {v.x, v.y, v.z, v.w};
#pragma unroll
        for (int i = 0; i < 4; ++i) {
          int n = nc + i;
          Bl[n * 64 + (((k >> 3) ^ (n & 7)) * 8) + (k & 7)] = f2bf(vv[i]);
        }
      }
    } else {    // stage B: bf16 (N,K), same as A, guard rows >= N
      const int g = t & 7, r0 = t >> 3;
      const u16* Bt = (const u16*)p.B + bz;
#pragma unroll
      for (int ps = 0; ps < 4; ++ps) {
        int row = ps * 32 + r0;
        s16x8 v = {0, 0, 0, 0, 0, 0, 0, 0};
        if (n0 + row < p.N)
          v = *(const s16x8*)(Bt + (long long)(n0 + row) * p.ldb + k0 + g * 8);
        *(s16x8*)&Bl[row * 64 + ((g ^ (row & 7)) * 8)] = v;
      }
    }
    __syncthreads();
    const int lr = lane & 15, lk = lane >> 4;
#pragma unroll
    for (int kk = 0; kk < 2; ++kk) {
      s16x8 af[4], bfr[4];
      int g = kk * 4 + lk;
#pragma unroll
      for (int i = 0; i < 4; ++i) {
        int ra = wm * 64 + i * 16 + lr;
        af[i] = *(const s16x8*)&Al[ra * 64 + ((g ^ (ra & 7)) * 8)];
        int rb = wn * 64 + i * 16 + lr;
        bfr[i] = *(const s16x8*)&Bl[rb * 64 + ((g ^ (rb & 7)) * 8)];
      }
#pragma unroll
      for (int i = 0; i < 4; ++i)
#pragma unroll
        for (int j = 0; j < 4; ++j)
          acc[i][j] = __builtin_amdgcn_mfma_f32_16x16x32_bf16(af[i], bfr[j], acc[i][j], 0, 0, 0);
    }
    __syncthreads();
  }

  long long cb;
  if (p.czmode == 1) { int b = z >> 4, h = z & 15; cb = (long long)b * 1048576 + h * 64; }
  else cb = (long long)z * p.sCz;
  const int lr = lane & 15, lq = lane >> 4;
#pragma unroll
  for (int i = 0; i < 4; ++i) {
#pragma unroll
    for (int j = 0; j < 4; ++j) {
      int col = n0 + wn * 64 + j * 16 + lr;
      if (col >= p.N) continue;
#pragma unroll
      for (int q = 0; q < 4; ++q) {
        int row = m0 + wm * 64 + i * 16 + lq * 4 + q;
        float v = acc[i][j][q];
        if (EPI == 0) {          // plain bf16 store
          ((u16*)p.C)[cb + (long long)row * p.ldc + col] = f2bf(v);
        } else if (EPI == 1) {   // plain f32 store
          ((float*)p.C)[cb + (long long)row * p.ldc + col] = v;
        } else if (EPI == 2) {   // sigmoid(acc+gb) * (y_small + xn*Dp) -> bf16
          float gg = 1.f / (1.f + __expf(-(v + p.p0[col])));
          float yv = p.p1[row * 16 + (col >> 6)] +
                     p.p2[(long long)row * 1024 + col] * p.p3[col >> 6];
          ((u16*)p.C)[cb + (long long)row * p.ldc + col] = f2bf(gg * yv);
        } else if (EPI == 3) {   // +bias -> f32
          ((float*)p.C)[cb + (long long)row * p.ldc + col] = v + p.p0[col];
        } else if (EPI == 4) {   // moe (+)= wfull[:,e]*(acc+bias)
          float wv = p.p1[row * 4 + p.eidx];
          float val = wv * (v + p.p0[col]);
          float* cp = (float*)p.C + cb + (long long)row * p.ldc + col;
          if (p.first) *cp = val; else *cp += val;
        } else if (EPI == 5) {   // scaled bf16 (attention scores)
          ((u16*)p.C)[cb + (long long)row * p.ldc + col] = f2bf(v * p.scale);
        } else if (EPI == 6) {   // V-transpose store: (b,l)x(kvh,d) -> vT[b,kvh,d,l]
          int b = row >> 10, l = row & 1023, kvh = col >> 6, d = col & 63;
          ((u16*)p.C)[(((long long)(b * 4 + kvh) * 64 + d) << 10) + l] = f2bf(v);
        }
      }
    }
  }
}

// --------------------------------------------------------- small kernels --
__global__ void rms1_k(const float* x, const float* goal, const float* w,
                       float* xn, u16* xnb) {
  int m = blockIdx.x, t = threadIdx.x;
  const float* xr = x + (long long)m * 1024;
  float v[4]; float ss = 0.f;
#pragma unroll
  for (int i = 0; i < 4; ++i) { v[i] = xr[t + i * 256]; ss += v[i] * v[i]; }
  ss = blockRed256<false>(ss);
  float r = rsqrtf(ss * (1.f / 1024.f) + 1e-6f);
#pragma unroll
  for (int i = 0; i < 4; ++i) {
    int c = t + i * 256;
    float o = v[i] * r * w[c] + goal[(long long)m * 1024 + c];
    xn[(long long)m * 1024 + c] = o;
    xnb[(long long)m * 1024 + c] = f2bf(o);
  }
}

__global__ void router_k(const float* xn, const float* rw, float* wout) {
  int m = blockIdx.x, t = threadIdx.x;
  const float* xr = xn + (long long)m * 1024;
  float a[4] = {0.f, 0.f, 0.f, 0.f};
  for (int i = t; i < 1024; i += 256) {
    float xv = xr[i];
    const float* r = rw + i * 4;
    a[0] += xv * r[0]; a[1] += xv * r[1]; a[2] += xv * r[2]; a[3] += xv * r[3];
  }
#pragma unroll
  for (int j = 0; j < 4; ++j) a[j] = blockRed256<false>(a[j]);
  if (t == 0) {
    float mx = fmaxf(fmaxf(a[0], a[1]), fmaxf(a[2], a[3]));
    float e[4]; float s = 0.f;
    for (int j = 0; j < 4; ++j) { e[j] = __expf(a[j] - mx); s += e[j]; }
    const float mix[4] = {0.5f, 0.2f, 0.15f, 0.15f};
    float ws = 0.f;
    for (int j = 0; j < 4; ++j) { e[j] = e[j] / s * mix[j]; ws += e[j]; }
    for (int j = 0; j < 4; ++j) wout[m * 4 + j] = e[j] / ws;
  }
}

DEV float softplus_f(float x) { return x > 15.f ? x : log1pf(__expf(x)); }

// chunked scan: 64 chunks of 16. blk = b*1024 + h*64 + c ; 64 thr (n)
__global__ void scanA_k(const float* ssm, const float* A, float* aprod, float* sloc) {
  int blk = blockIdx.x, n = threadIdx.x;
  int c = blk & 63, h = (blk >> 6) & 15, b = blk >> 10;
  float Ah = A[h * 64 + n];
  float ap = 1.f, s = 0.f;
  int l0 = c * 16;
  for (int j = 0; j < 16; ++j) {
    long long off = (long long)(b * 1024 + l0 + j) * 144;
    float d = softplus_f(ssm[off + 128 + h] + ssm[off + n]);
    float a = __expf(d * Ah);
    s = a * s + d * d;
    ap *= a;
  }
  long long o = (long long)blk * 64 + n;
  aprod[o] = ap; sloc[o] = s;
}

__global__ void scanB_k(const float* aprod, const float* sloc, float* cin) {
  int bh = blockIdx.x, n = threadIdx.x;
  float carry = 0.f;
  for (int c = 0; c < 64; ++c) {
    long long o = (long long)(bh * 64 + c) * 64 + n;
    cin[o] = carry;
    carry = aprod[o] * carry + sloc[o];
  }
}

__global__ void scanC_k(const float* ssm, const float* A, const float* cin, float* ysm) {
  int blk = blockIdx.x, n = threadIdx.x;
  int c = blk & 63, h = (blk >> 6) & 15, b = blk >> 10;
  float Ah = A[h * 64 + n];
  float s = cin[(long long)blk * 64 + n];
  int l0 = c * 16;
  for (int j = 0; j < 16; ++j) {
    long long off = (long long)(b * 1024 + l0 + j) * 144;
    float d = softplus_f(ssm[off + 128 + h] + ssm[off + n]);
    float a = __expf(d * Ah);
    s = a * s + d * d;
    float yv = s * ssm[off + 64 + n];
    for (int o2 = 32; o2; o2 >>= 1) yv += __shfl_xor(yv, o2);
    if (n == 0) ysm[(long long)(b * 1024 + l0 + j) * 16 + h] = yv;
  }
}

// RMS(qn/kn) + RoPE ; 4 rows per block (1 wave/row, lane = d)
__global__ void rope_k(const u16* qpre, const u16* kpre, const float* qnw,
                       const float* knw, u16* qro, u16* kro) {
  int rid = blockIdx.x * 4 + (threadIdx.x >> 6);
  int lane = threadIdx.x & 63;
  float v; const float* nw; int l; u16* dst;
  if (rid < 32768) {
    int b = rid >> 14, h = (rid >> 10) & 15; l = rid & 1023;
    v = bf2f(qpre[(long long)(b * 1024 + l) * 1024 + h * 64 + lane]);
    nw = qnw; dst = qro + (long long)rid * 64;
  } else {
    int r2 = rid - 32768;
    int b = r2 >> 12, kvh = (r2 >> 10) & 3; l = r2 & 1023;
    v = bf2f(kpre[(long long)(b * 1024 + l) * 256 + kvh * 64 + lane]);
    nw = knw; dst = kro + (long long)r2 * 64;
  }
  float ss = v * v;
  for (int o = 32; o; o >>= 1) ss += __shfl_xor(ss, o);
  float r = rsqrtf(ss * (1.f / 64.f) + 1e-6f);
  float vn = v * r * nw[lane];
  float pt = __shfl_xor(vn, 32);
  int i = lane & 31;
  float invf = powf(10000.f, -(float)i * (1.f / 32.f));
  float fr = (float)l * invf;
  float o2 = vn * cosf(fr) + ((lane < 32) ? -pt : pt) * sinf(fr);
  dst[lane] = f2bf(o2);
}

__global__ void softmax_k(u16* sc) {
  u16* r = sc + (long long)blockIdx.x * 1024;
  int t = threadIdx.x;
  float v[4]; float mx = -1e30f;
#pragma unroll
  for (int i = 0; i < 4; ++i) { v[i] = bf2f(r[t + i * 256]); mx = fmaxf(mx, v[i]); }
  mx = blockRed256<true>(mx);
  float s = 0.f;
#pragma unroll
  for (int i = 0; i < 4; ++i) { v[i] = __expf(v[i] - mx); s += v[i]; }
  s = blockRed256<false>(s);
  float inv = 1.f / s;
#pragma unroll
  for (int i = 0; i < 4; ++i) r[t + i * 256] = f2bf(v[i] * inv);
}

__global__ void conv_k(const float* xn, const float* dww, const float* dwb, u16* outb) {
  int m = blockIdx.x; int l = m & 1023;
#pragma unroll
  for (int i = 0; i < 4; ++i) {
    int d = threadIdx.x + i * 256;
    float xm = l > 0    ? xn[(long long)(m - 1) * 1024 + d] : 0.f;
    float x0 =            xn[(long long)m * 1024 + d];
    float xp = l < 1023 ? xn[(long long)(m + 1) * 1024 + d] : 0.f;
    float dv = xm * dww[d * 3] + x0 * dww[d * 3 + 1] + xp * dww[d * 3 + 2] + dwb[d];
    outb[(long long)m * 1024 + d] = f2bf(dv / (1.f + __expf(-dv)));
  }
}

__global__ void mix_k(const float* x, const float* w, const float* oss,
                      const float* oat, const float* ocv, const float* mem,
                      float* x2, u16* x2b) {
  int m = blockIdx.x;
  float w0 = w[m * 4], w1 = w[m * 4 + 1], w2 = w[m * 4 + 2], w3 = w[m * 4 + 3];
#pragma unroll
  for (int j = 0; j < 4; ++j) {
    long long i = (long long)m * 1024 + threadIdx.x + j * 256;
    float v = x[i] + w0 * oss[i] + w1 * oat[i] + w2 * ocv[i] + w3 * mem[i];
    x2[i] = v; x2b[i] = f2bf(v);
  }
}

__global__ void moegate_k(const float* x2, const float* n2w, const float* mg, float* wf) {
  int m = blockIdx.x, t = threadIdx.x;
  const float* xr = x2 + (long long)m * 1024;
  float ss = 0.f, a[4] = {0.f, 0.f, 0.f, 0.f};
  for (int i = t; i < 1024; i += 256) {
    float v = xr[i]; ss += v * v;
    float vw = v * n2w[i];
    const float* g = mg + i * 4;
    a[0] += vw * g[0]; a[1] += vw * g[1]; a[2] += vw * g[2]; a[3] += vw * g[3];
  }
  ss = blockRed256<false>(ss);
#pragma unroll
  for (int j = 0; j < 4; ++j) a[j] = blockRed256<false>(a[j]);
  if (t == 0) {
    float r = rsqrtf(ss * (1.f / 1024.f) + 1e-6f);
    float mx = -1e30f;
    for (int j = 0; j < 4; ++j) { a[j] *= r; mx = fmaxf(mx, a[j]); }
    float e[4]; float s = 0.f;
    for (int j = 0; j < 4; ++j) { e[j] = __expf(a[j] - mx); s += e[j]; }
    for (int j = 0; j < 4; ++j) e[j] /= s;
    int i0 = 0;
    for (int j = 1; j < 4; ++j) if (e[j] > e[i0]) i0 = j;
    int i1 = -1;
    for (int j = 0; j < 4; ++j) { if (j == i0) continue; if (i1 < 0 || e[j] > e[i1]) i1 = j; }
    for (int j = 0; j < 4; ++j) wf[m * 4 + j] = (j == i0 || j == i1) ? e[j] : 0.f;
  }
}

__global__ void swiglu_k(const u16* h, u16* act) {
  long long i = (long long)blockIdx.x * 256 + threadIdx.x;  // 2048*4096 total
  long long m = i >> 12, j = i & 4095;
  float a = bf2f(h[m * 8192 + j]), g = bf2f(h[m * 8192 + 4096 + j]);
  float s = a / (1.f + __expf(-a));
  act[i] = f2bf(s * g);
}

__global__ void final_k(const float* x2, const float* moe, float* out) {
  long long i = (long long)blockIdx.x * 256 + threadIdx.x;
  out[i] = x2[i] + moe[i];
}

// ------------------------------------------------------------------ host --
extern "C" void kernel_launch(void* const* d_in, const int* in_sizes, int n_in,
                              void* d_out, int out_size, void* d_ws, size_t ws_size,
                              hipStream_t stream) {
  const float* x    = (const float*)d_in[0];
  const float* goal = (const float*)d_in[1];
  const float* mem  = (const float*)d_in[2];
  const float* n1w  = (const float*)d_in[3];
  const float* n2w  = (const float*)d_in[4];
  const float* rw   = (const float*)d_in[5];
  const float* xpw  = (const float*)d_in[6];
  const float* Amat = (const float*)d_in[7];
  const float* Dp   = (const float*)d_in[8];
  const float* gw   = (const float*)d_in[9];
  const float* gb   = (const float*)d_in[10];
  const float* sow  = (const float*)d_in[11];
  const float* qw   = (const float*)d_in[12];
  const float* kw   = (const float*)d_in[13];
  const float* vw   = (const float*)d_in[14];
  const float* ow   = (const float*)d_in[15];
  const float* qnw  = (const float*)d_in[16];
  const float* knw  = (const float*)d_in[17];
  const float* dww  = (const float*)d_in[18];
  const float* dwb  = (const float*)d_in[19];
  const float* pww  = (const float*)d_in[20];
  const float* pwb  = (const float*)d_in[21];
  const float* mgw  = (const float*)d_in[22];
  const float* ew1  = (const float*)d_in[23];
  const float* ew2  = (const float*)d_in[24];
  const float* elw  = (const float*)d_in[25];
  const float* elb  = (const float*)d_in[26];
  float* out = (float*)d_out;

  char* base = (char*)d_ws; size_t off = 0;
  auto alloc = [&](size_t b) { void* p = base + off; off += (b + 255) & ~(size_t)255; return p; };
  float* xn    = (float*)alloc(2048ull * 1024 * 4);
  u16*   xnb   = (u16*)  alloc(2048ull * 1024 * 2);
  float* wr    = (float*)alloc(2048ull * 4 * 4);
  float* ssm   = (float*)alloc(2048ull * 144 * 4);
  float* aprod = (float*)alloc(2048ull * 64 * 4);
  float* sloc  = (float*)alloc(2048ull * 64 * 4);
  float* cin   = (float*)alloc(2048ull * 64 * 4);
  float* ysm   = (float*)alloc(2048ull * 16 * 4);
  u16*   ssdin = (u16*)  alloc(2048ull * 1024 * 2);
  float* outss = (float*)alloc(2048ull * 1024 * 4);
  u16*   qpre  = (u16*)  alloc(2048ull * 1024 * 2);
  u16*   kpre  = (u16*)  alloc(2048ull * 256 * 2);
  u16*   vT    = (u16*)  alloc(2048ull * 256 * 2);
  u16*   qro   = (u16*)  alloc(2048ull * 1024 * 2);
  u16*   kro   = (u16*)  alloc(2048ull * 256 * 2);
  u16*   acat  = (u16*)  alloc(2048ull * 1024 * 2);
  float* outat = (float*)alloc(2048ull * 1024 * 4);
  u16*   cva   = (u16*)  alloc(2048ull * 1024 * 2);
  float* outcv = (float*)alloc(2048ull * 1024 * 4);
  float* x2    = (float*)alloc(2048ull * 1024 * 4);
  u16*   x2b   = (u16*)  alloc(2048ull * 1024 * 2);
  float* wfull = (float*)alloc(2048ull * 4 * 4);
  float* moe   = (float*)alloc(2048ull * 1024 * 4);
  char*  big   = (char*) alloc(67108864ull);   // scores | (h, act, t2)
  u16* scores = (u16*)big;
  u16* hbuf   = (u16*)big;
  u16* act    = (u16*)(big + 33554432);
  u16* t2     = (u16*)(big + 50331648);

  rms1_k<<<2048, 256, 0, stream>>>(x, goal, n1w, xn, xnb);
  router_k<<<2048, 256, 0, stream>>>(xn, rw, wr);

  { GemmP p{}; p.A = xnb; p.lda = 1024; p.B = xpw; p.ldb = 144; p.C = ssm; p.ldc = 144;
    p.M = 2048; p.N = 144; p.K = 1024;
    gemm_k<1, 1><<<dim3(2, 16, 1), 256, 0, stream>>>(p); }

  scanA_k<<<2048, 64, 0, stream>>>(ssm, Amat, aprod, sloc);
  scanB_k<<<32, 64, 0, stream>>>(aprod, sloc, cin);
  scanC_k<<<2048, 64, 0, stream>>>(ssm, Amat, cin, ysm);

  { GemmP p{}; p.A = xnb; p.lda = 1024; p.B = gw; p.ldb = 1024; p.C = ssdin; p.ldc = 1024;
    p.M = 2048; p.N = 1024; p.K = 1024; p.p0 = gb; p.p1 = ysm; p.p2 = xn; p.p3 = Dp;
    gemm_k<2, 1><<<dim3(8, 16, 1), 256, 0, stream>>>(p); }
  { GemmP p{}; p.A = ssdin; p.lda = 1024; p.B = sow; p.ldb = 1024; p.C = outss; p.ldc = 1024;
    p.M = 2048; p.N = 1024; p.K = 1024;
    gemm_k<1, 1><<<dim3(8, 16, 1), 256, 0, stream>>>(p); }

  { GemmP p{}; p.A = xnb; p.lda = 1024; p.B = qw; p.ldb = 1024; p.C = qpre; p.ldc = 1024;
    p.M = 2048; p.N = 1024; p.K = 1024;
    gemm_k<0, 1><<<dim3(8, 16, 1), 256, 0, stream>>>(p); }
  { GemmP p{}; p.A = xnb; p.lda = 1024; p.B = kw; p.ldb = 256; p.C = kpre; p.ldc = 256;
    p.M = 2048; p.N = 256; p.K = 1024;
    gemm_k<0, 1><<<dim3(2, 16, 1), 256, 0, stream>>>(p); }
  { GemmP p{}; p.A = xnb; p.lda = 1024; p.B = vw; p.ldb = 256; p.C = vT; p.ldc = 0;
    p.M = 2048; p.N = 256; p.K = 1024;
    gemm_k<6, 1><<<dim3(2, 16, 1), 256, 0, stream>>>(p); }

  rope_k<<<10240, 256, 0, stream>>>(qpre, kpre, qnw, knw, qro, kro);

  { GemmP p{}; p.A = qro; p.lda = 64; p.sAz = 65536; p.B = kro; p.ldb = 64; p.sBz = 65536;
    p.gqa = 1; p.C = scores; p.ldc = 1024; p.sCz = 1048576;
    p.M = 1024; p.N = 1024; p.K = 64; p.scale = 0.125f;
    gemm_k<5, 0><<<dim3(8, 8, 32), 256, 0, stream>>>(p); }
  softmax_k<<<32768, 256, 0, stream>>>(scores);
  { GemmP p{}; p.A = scores; p.lda = 1024; p.sAz = 1048576; p.B = vT; p.ldb = 1024; p.sBz = 65536;
    p.gqa = 1; p.C = acat; p.ldc = 1024; p.czmode = 1;
    p.M = 1024; p.N = 64; p.K = 1024;
    gemm_k<0, 0><<<dim3(1, 8, 32), 256, 0, stream>>>(p); }
  { GemmP p{}; p.A = acat; p.lda = 1024; p.B = ow; p.ldb = 1024; p.C = outat; p.ldc = 1024;
    p.M = 2048; p.N = 1024; p.K = 1024;
    gemm_k<1, 1><<<dim3(8, 16, 1), 256, 0, stream>>>(p); }

  conv_k<<<2048, 256, 0, stream>>>(xn, dww, dwb, cva);
  { GemmP p{}; p.A = cva; p.lda = 1024; p.B = pww; p.ldb = 1024; p.C = outcv; p.ldc = 1024;
    p.M = 2048; p.N = 1024; p.K = 1024; p.p0 = pwb;
    gemm_k<3, 1><<<dim3(8, 16, 1), 256, 0, stream>>>(p); }

  mix_k<<<2048, 256, 0, stream>>>(x, wr, outss, outat, outcv, mem, x2, x2b);
  moegate_k<<<2048, 256, 0, stream>>>(x2, n2w, mgw, wfull);

  for (int e = 0; e < 4; ++e) {
    { GemmP p{}; p.A = x2b; p.lda = 1024; p.B = ew1 + (long long)e * 1024 * 8192; p.ldb = 8192;
      p.C = hbuf; p.ldc = 8192; p.M = 2048; p.N = 8192; p.K = 1024;
      gemm_k<0, 1><<<dim3(64, 16, 1), 256, 0, stream>>>(p); }
    swiglu_k<<<32768, 256, 0, stream>>>(hbuf, act);
    { GemmP p{}; p.A = act; p.lda = 4096; p.B = ew2 + (long long)e * 4096 * 1024; p.ldb = 1024;
      p.C = t2; p.ldc = 1024; p.M = 2048; p.N = 1024; p.K = 4096;
      gemm_k<0, 1><<<dim3(8, 16, 1), 256, 0, stream>>>(p); }
    { GemmP p{}; p.A = t2; p.lda = 1024; p.B = elw + (long long)e * 1024 * 1024; p.ldb = 1024;
      p.C = moe; p.ldc = 1024; p.M = 2048; p.N = 1024; p.K = 1024;
      p.p0 = elb + e * 1024; p.p1 = wfull; p.eidx = e; p.first = (e == 0);
      gemm_k<4, 1><<<dim3(8, 16, 1), 256, 0, stream>>>(p); }
  }

  final_k<<<8192, 256, 0, stream>>>(x2, moe, out);
}

// Round 2
// 1218.163 us; speedup vs baseline: 1.7259x; 1.7259x over previous
//
#include <hip/hip_runtime.h>
#include <hip/hip_bf16.h>
#include <cstdint>

typedef unsigned short u16;
typedef __attribute__((ext_vector_type(4))) float f32x4;
typedef __attribute__((ext_vector_type(8))) short s16x8;

#define DEV __device__ __forceinline__

DEV u16 f2bf(float x) {                       // RNE f32 -> bf16
  unsigned u = __float_as_uint(x);
  u += 0x7FFFu + ((u >> 16) & 1u);
  return (u16)(u >> 16);
}
DEV float bf2f(u16 b) { return __uint_as_float(((unsigned)b) << 16); }

DEV void gload16(const void* g, void* l) {    // async global->LDS, 16B/lane
  __builtin_amdgcn_global_load_lds(
      (const __attribute__((address_space(1))) void*)g,
      (__attribute__((address_space(3))) void*)l, 16, 0, 0);
}

template<bool MAXOP>
DEV float blockRed256(float v) {
  for (int o = 32; o; o >>= 1) {
    float t = __shfl_xor(v, o);
    v = MAXOP ? fmaxf(v, t) : v + t;
  }
  __shared__ float s[4];
  __syncthreads();
  if ((threadIdx.x & 63) == 0) s[threadIdx.x >> 6] = v;
  __syncthreads();
  return MAXOP ? fmaxf(fmaxf(s[0], s[1]), fmaxf(s[2], s[3]))
               : (s[0] + s[1] + s[2] + s[3]);
}

// ------------------------------------------------- weight transpose ------
// f32 (K,N) row-major -> bf16 (N,K) row-major. 64x64 tile, 256 thr.
__global__ __launch_bounds__(256) void wtrans_k(const float* __restrict__ in,
                                                u16* __restrict__ out,
                                                int K, int N) {
  __shared__ float t[64][68];
  const int n0 = blockIdx.x * 64, k0 = blockIdx.y * 64;
  const int tt = threadIdx.x;
  const int kl = tt >> 4, nl = (tt & 15) * 4;
#pragma unroll
  for (int i = 0; i < 4; ++i) {
    int k = kl + i * 16;
    float4 v{0.f, 0.f, 0.f, 0.f};
    if (n0 + nl + 3 < N) {
      v = *(const float4*)(in + (long long)(k0 + k) * N + n0 + nl);
    } else {
      for (int j = 0; j < 4; ++j)
        if (n0 + nl + j < N) ((float*)&v)[j] = in[(long long)(k0 + k) * N + n0 + nl + j];
    }
    t[nl + 0][k] = v.x; t[nl + 1][k] = v.y; t[nl + 2][k] = v.z; t[nl + 3][k] = v.w;
  }
  __syncthreads();
  const int n = tt >> 2, kq = (tt & 3) * 16;
  if (n0 + n < N) {
    s16x8 o0, o1;
#pragma unroll
    for (int j = 0; j < 8; ++j) { o0[j] = (short)f2bf(t[n][kq + j]); o1[j] = (short)f2bf(t[n][kq + 8 + j]); }
    u16* op = out + (long long)(n0 + n) * K + k0 + kq;
    *(s16x8*)op = o0; *(s16x8*)(op + 8) = o1;
  }
}

// ---------------------------------------------------------------- GEMM ----
// C[M,N] = A[M,K] @ B^T ; A bf16 (M,K) rm, B bf16 (N,K) rm.
// 128x128 tile, BK=64, 4 waves (2x2), 16x16x32 bf16 MFMA, XOR-swizzled LDS,
// staged via global_load_lds (pre-swizzled per-lane source).
struct GemmP {
  const u16* A; int lda; long long sAz;
  const u16* B; int ldb; long long sBz;
  void* C; int ldc; long long sCz;
  int M, N, K;
  int gqa;      // 1: B batch index = (z>>4)*4 + ((z&15)>>2)   (GQA 16q/4kv)
  int czmode;   // 1: C base = b*1048576 + h*64  (attn concat store)
  const float *p0, *p1, *p2, *p3;
  float scale; int eidx; int first;
  u16 *aux0, *aux1, *aux2;   // EPI7: qpre, kpre, vT
};

template<int EPI>
__global__ __launch_bounds__(256) void gemm_k(GemmP p) {
  __shared__ u16 Al[128 * 64];
  __shared__ u16 Bl[128 * 64];
  const int z = blockIdx.z;
  const int t = threadIdx.x;
  const int lane = t & 63, wid = t >> 6;
  const int wm = wid >> 1, wn = wid & 1;
  const int m0 = blockIdx.y * 128, n0 = blockIdx.x * 128;

  const u16* Ab = p.A + (long long)z * p.sAz;
  const u16* Bb = p.B + (p.gqa ? (long long)(((z >> 4) << 2) + ((z & 15) >> 2)) * p.sBz
                               : (long long)z * p.sBz);
  // staging geometry: per wave, 4 calls of 8 rows (1 KiB) each for A and B
  const int sr = lane >> 3;                 // sub-row 0..7
  const int sg = (lane & 7) ^ sr;           // pre-swizzled k-group
  const u16* pa[4]; const u16* pb[4]; u16* la[4]; u16* lb[4];
#pragma unroll
  for (int c = 0; c < 4; ++c) {
    int rbase = c * 32 + wid * 8;
    int ra = m0 + rbase + sr; if (ra > p.M - 1) ra = p.M - 1;
    int rb = n0 + rbase + sr; if (rb > p.N - 1) rb = p.N - 1;
    pa[c] = Ab + (long long)ra * p.lda + sg * 8;
    pb[c] = Bb + (long long)rb * p.ldb + sg * 8;
    la[c] = &Al[rbase * 64];
    lb[c] = &Bl[rbase * 64];
  }

  f32x4 acc[4][4];
#pragma unroll
  for (int i = 0; i < 4; ++i)
#pragma unroll
    for (int j = 0; j < 4; ++j) acc[i][j] = f32x4{0.f, 0.f, 0.f, 0.f};

  const int lr = lane & 15, lk = lane >> 4;
  for (int k0 = 0; k0 < p.K; k0 += 64) {
#pragma unroll
    for (int c = 0; c < 4; ++c) {
      gload16(pa[c] + k0, la[c]);
      gload16(pb[c] + k0, lb[c]);
    }
    __syncthreads();
#pragma unroll
    for (int kk = 0; kk < 2; ++kk) {
      s16x8 af[4], bfr[4];
      int g = kk * 4 + lk;
#pragma unroll
      for (int i = 0; i < 4; ++i) {
        int ra = wm * 64 + i * 16 + lr;
        af[i] = *(const s16x8*)&Al[ra * 64 + ((g ^ (ra & 7)) * 8)];
        int rb = wn * 64 + i * 16 + lr;
        bfr[i] = *(const s16x8*)&Bl[rb * 64 + ((g ^ (rb & 7)) * 8)];
      }
#pragma unroll
      for (int i = 0; i < 4; ++i)
#pragma unroll
        for (int j = 0; j < 4; ++j)
          acc[i][j] = __builtin_amdgcn_mfma_f32_16x16x32_bf16(af[i], bfr[j], acc[i][j], 0, 0, 0);
    }
    __syncthreads();
  }

  long long cb;
  if (p.czmode == 1) { int b = z >> 4, h = z & 15; cb = (long long)b * 1048576 + h * 64; }
  else cb = (long long)z * p.sCz;
  const int lq = lane >> 4;
#pragma unroll
  for (int i = 0; i < 4; ++i) {
#pragma unroll
    for (int j = 0; j < 4; ++j) {
      int col = n0 + wn * 64 + j * 16 + lr;
      if (col >= p.N) continue;
#pragma unroll
      for (int q = 0; q < 4; ++q) {
        int row = m0 + wm * 64 + i * 16 + lq * 4 + q;
        float v = acc[i][j][q];
        if (EPI == 0) {          // plain bf16 store
          ((u16*)p.C)[cb + (long long)row * p.ldc + col] = f2bf(v);
        } else if (EPI == 1) {   // plain f32 store
          ((float*)p.C)[cb + (long long)row * p.ldc + col] = v;
        } else if (EPI == 2) {   // sigmoid(acc+gb) * (y_small + xn*Dp) -> bf16
          float gg = 1.f / (1.f + __expf(-(v + p.p0[col])));
          float yv = p.p1[row * 16 + (col >> 6)] +
                     p.p2[(long long)row * 1024 + col] * p.p3[col >> 6];
          ((u16*)p.C)[cb + (long long)row * p.ldc + col] = f2bf(gg * yv);
        } else if (EPI == 3) {   // +bias -> f32
          ((float*)p.C)[cb + (long long)row * p.ldc + col] = v + p.p0[col];
        } else if (EPI == 4) {   // moe (+)= wfull[:,e]*(acc+bias)
          float wv = p.p1[row * 4 + p.eidx];
          float val = wv * (v + p.p0[col]);
          float* cp = (float*)p.C + cb + (long long)row * p.ldc + col;
          if (p.first) *cp = val; else *cp += val;
        } else if (EPI == 5) {   // scaled bf16 (attention scores)
          ((u16*)p.C)[cb + (long long)row * p.ldc + col] = f2bf(v * p.scale);
        } else if (EPI == 7) {   // fused qkv routing
          if (col < 1024) {
            p.aux0[(long long)row * 1024 + col] = f2bf(v);
          } else if (col < 1280) {
            p.aux1[(long long)row * 256 + (col - 1024)] = f2bf(v);
          } else {
            int cc = col - 1280;
            int b = row >> 10, l = row & 1023, kvh = cc >> 6, d = cc & 63;
            p.aux2[(((long long)(b * 4 + kvh) * 64 + d) << 10) + l] = f2bf(v);
          }
        }
      }
    }
  }
}

// --------------------------------------------------------- small kernels --
__global__ void rms1_k(const float* x, const float* goal, const float* w,
                       float* xn, u16* xnb) {
  int m = blockIdx.x, t = threadIdx.x;
  const float* xr = x + (long long)m * 1024;
  float v[4]; float ss = 0.f;
#pragma unroll
  for (int i = 0; i < 4; ++i) { v[i] = xr[t + i * 256]; ss += v[i] * v[i]; }
  ss = blockRed256<false>(ss);
  float r = rsqrtf(ss * (1.f / 1024.f) + 1e-6f);
#pragma unroll
  for (int i = 0; i < 4; ++i) {
    int c = t + i * 256;
    float o = v[i] * r * w[c] + goal[(long long)m * 1024 + c];
    xn[(long long)m * 1024 + c] = o;
    xnb[(long long)m * 1024 + c] = f2bf(o);
  }
}

__global__ void router_k(const float* xn, const float* rw, float* wout) {
  int m = blockIdx.x, t = threadIdx.x;
  const float* xr = xn + (long long)m * 1024;
  float a[4] = {0.f, 0.f, 0.f, 0.f};
  for (int i = t; i < 1024; i += 256) {
    float xv = xr[i];
    const float* r = rw + i * 4;
    a[0] += xv * r[0]; a[1] += xv * r[1]; a[2] += xv * r[2]; a[3] += xv * r[3];
  }
#pragma unroll
  for (int j = 0; j < 4; ++j) a[j] = blockRed256<false>(a[j]);
  if (t == 0) {
    float mx = fmaxf(fmaxf(a[0], a[1]), fmaxf(a[2], a[3]));
    float e[4]; float s = 0.f;
    for (int j = 0; j < 4; ++j) { e[j] = __expf(a[j] - mx); s += e[j]; }
    const float mix[4] = {0.5f, 0.2f, 0.15f, 0.15f};
    float ws = 0.f;
    for (int j = 0; j < 4; ++j) { e[j] = e[j] / s * mix[j]; ws += e[j]; }
    for (int j = 0; j < 4; ++j) wout[m * 4 + j] = e[j] / ws;
  }
}

DEV float softplus_f(float x) { return x > 15.f ? x : log1pf(__expf(x)); }

__global__ void scanA_k(const float* ssm, const float* A, float* aprod, float* sloc) {
  int blk = blockIdx.x, n = threadIdx.x;
  int c = blk & 63, h = (blk >> 6) & 15, b = blk >> 10;
  float Ah = A[h * 64 + n];
  float ap = 1.f, s = 0.f;
  int l0 = c * 16;
  for (int j = 0; j < 16; ++j) {
    long long off = (long long)(b * 1024 + l0 + j) * 144;
    float d = softplus_f(ssm[off + 128 + h] + ssm[off + n]);
    float a = __expf(d * Ah);
    s = a * s + d * d;
    ap *= a;
  }
  long long o = (long long)blk * 64 + n;
  aprod[o] = ap; sloc[o] = s;
}

__global__ void scanB_k(const float* aprod, const float* sloc, float* cin) {
  int bh = blockIdx.x, n = threadIdx.x;
  float carry = 0.f;
  for (int c = 0; c < 64; ++c) {
    long long o = (long long)(bh * 64 + c) * 64 + n;
    cin[o] = carry;
    carry = aprod[o] * carry + sloc[o];
  }
}

__global__ void scanC_k(const float* ssm, const float* A, const float* cin, float* ysm) {
  int blk = blockIdx.x, n = threadIdx.x;
  int c = blk & 63, h = (blk >> 6) & 15, b = blk >> 10;
  float Ah = A[h * 64 + n];
  float s = cin[(long long)blk * 64 + n];
  int l0 = c * 16;
  for (int j = 0; j < 16; ++j) {
    long long off = (long long)(b * 1024 + l0 + j) * 144;
    float d = softplus_f(ssm[off + 128 + h] + ssm[off + n]);
    float a = __expf(d * Ah);
    s = a * s + d * d;
    float yv = s * ssm[off + 64 + n];
    for (int o2 = 32; o2; o2 >>= 1) yv += __shfl_xor(yv, o2);
    if (n == 0) ysm[(long long)(b * 1024 + l0 + j) * 16 + h] = yv;
  }
}

__global__ void rope_k(const u16* qpre, const u16* kpre, const float* qnw,
                       const float* knw, u16* qro, u16* kro) {
  int rid = blockIdx.x * 4 + (threadIdx.x >> 6);
  int lane = threadIdx.x & 63;
  float v; const float* nw; int l; u16* dst;
  if (rid < 32768) {
    int b = rid >> 14, h = (rid >> 10) & 15; l = rid & 1023;
    v = bf2f(qpre[(long long)(b * 1024 + l) * 1024 + h * 64 + lane]);
    nw = qnw; dst = qro + (long long)rid * 64;
  } else {
    int r2 = rid - 32768;
    int b = r2 >> 12, kvh = (r2 >> 10) & 3; l = r2 & 1023;
    v = bf2f(kpre[(long long)(b * 1024 + l) * 256 + kvh * 64 + lane]);
    nw = knw; dst = kro + (long long)r2 * 64;
  }
  float ss = v * v;
  for (int o = 32; o; o >>= 1) ss += __shfl_xor(ss, o);
  float r = rsqrtf(ss * (1.f / 64.f) + 1e-6f);
  float vn = v * r * nw[lane];
  float pt = __shfl_xor(vn, 32);
  int i = lane & 31;
  float invf = powf(10000.f, -(float)i * (1.f / 32.f));
  float fr = (float)l * invf;
  float o2 = vn * cosf(fr) + ((lane < 32) ? -pt : pt) * sinf(fr);
  dst[lane] = f2bf(o2);
}

__global__ void softmax_k(u16* sc) {
  u16* r = sc + (long long)blockIdx.x * 1024;
  int t = threadIdx.x;
  float v[4]; float mx = -1e30f;
#pragma unroll
  for (int i = 0; i < 4; ++i) { v[i] = bf2f(r[t + i * 256]); mx = fmaxf(mx, v[i]); }
  mx = blockRed256<true>(mx);
  float s = 0.f;
#pragma unroll
  for (int i = 0; i < 4; ++i) { v[i] = __expf(v[i] - mx); s += v[i]; }
  s = blockRed256<false>(s);
  float inv = 1.f / s;
#pragma unroll
  for (int i = 0; i < 4; ++i) r[t + i * 256] = f2bf(v[i] * inv);
}

__global__ void conv_k(const float* xn, const float* dww, const float* dwb, u16* outb) {
  int m = blockIdx.x; int l = m & 1023;
#pragma unroll
  for (int i = 0; i < 4; ++i) {
    int d = threadIdx.x + i * 256;
    float xm = l > 0    ? xn[(long long)(m - 1) * 1024 + d] : 0.f;
    float x0 =            xn[(long long)m * 1024 + d];
    float xp = l < 1023 ? xn[(long long)(m + 1) * 1024 + d] : 0.f;
    float dv = xm * dww[d * 3] + x0 * dww[d * 3 + 1] + xp * dww[d * 3 + 2] + dwb[d];
    outb[(long long)m * 1024 + d] = f2bf(dv / (1.f + __expf(-dv)));
  }
}

__global__ void mix_k(const float* x, const float* w, const float* oss,
                      const float* oat, const float* ocv, const float* mem,
                      float* x2, u16* x2b) {
  int m = blockIdx.x;
  float w0 = w[m * 4], w1 = w[m * 4 + 1], w2 = w[m * 4 + 2], w3 = w[m * 4 + 3];
#pragma unroll
  for (int j = 0; j < 4; ++j) {
    long long i = (long long)m * 1024 + threadIdx.x + j * 256;
    float v = x[i] + w0 * oss[i] + w1 * oat[i] + w2 * ocv[i] + w3 * mem[i];
    x2[i] = v; x2b[i] = f2bf(v);
  }
}

__global__ void moegate_k(const float* x2, const float* n2w, const float* mg, float* wf) {
  int m = blockIdx.x, t = threadIdx.x;
  const float* xr = x2 + (long long)m * 1024;
  float ss = 0.f, a[4] = {0.f, 0.f, 0.f, 0.f};
  for (int i = t; i < 1024; i += 256) {
    float v = xr[i]; ss += v * v;
    float vw = v * n2w[i];
    const float* g = mg + i * 4;
    a[0] += vw * g[0]; a[1] += vw * g[1]; a[2] += vw * g[2]; a[3] += vw * g[3];
  }
  ss = blockRed256<false>(ss);
#pragma unroll
  for (int j = 0; j < 4; ++j) a[j] = blockRed256<false>(a[j]);
  if (t == 0) {
    float r = rsqrtf(ss * (1.f / 1024.f) + 1e-6f);
    float mx = -1e30f;
    for (int j = 0; j < 4; ++j) { a[j] *= r; mx = fmaxf(mx, a[j]); }
    float e[4]; float s = 0.f;
    for (int j = 0; j < 4; ++j) { e[j] = __expf(a[j] - mx); s += e[j]; }
    for (int j = 0; j < 4; ++j) e[j] /= s;
    int i0 = 0;
    for (int j = 1; j < 4; ++j) if (e[j] > e[i0]) i0 = j;
    int i1 = -1;
    for (int j = 0; j < 4; ++j) { if (j == i0) continue; if (i1 < 0 || e[j] > e[i1]) i1 = j; }
    for (int j = 0; j < 4; ++j) wf[m * 4 + j] = (j == i0 || j == i1) ? e[j] : 0.f;
  }
}

__global__ void swiglu_k(const u16* h, u16* act) {
  long long i = ((long long)blockIdx.x * 256 + threadIdx.x) * 8;  // 2048*4096 elems
  long long m = i >> 12, j = i & 4095;
  s16x8 a = *(const s16x8*)(h + m * 8192 + j);
  s16x8 g = *(const s16x8*)(h + m * 8192 + 4096 + j);
  s16x8 o;
#pragma unroll
  for (int q = 0; q < 8; ++q) {
    float av = bf2f((u16)a[q]), gv = bf2f((u16)g[q]);
    o[q] = (short)f2bf(av / (1.f + __expf(-av)) * gv);
  }
  *(s16x8*)(act + i) = o;
}

__global__ void final_k(const float* x2, const float* moe, float* out) {
  long long i = ((long long)blockIdx.x * 256 + threadIdx.x) * 4;
  float4 a = *(const float4*)(x2 + i);
  float4 b = *(const float4*)(moe + i);
  float4 o{a.x + b.x, a.y + b.y, a.z + b.z, a.w + b.w};
  *(float4*)(out + i) = o;
}

// ------------------------------------------------------------------ host --
extern "C" void kernel_launch(void* const* d_in, const int* in_sizes, int n_in,
                              void* d_out, int out_size, void* d_ws, size_t ws_size,
                              hipStream_t stream) {
  const float* x    = (const float*)d_in[0];
  const float* goal = (const float*)d_in[1];
  const float* mem  = (const float*)d_in[2];
  const float* n1w  = (const float*)d_in[3];
  const float* n2w  = (const float*)d_in[4];
  const float* rw   = (const float*)d_in[5];
  const float* xpw  = (const float*)d_in[6];
  const float* Amat = (const float*)d_in[7];
  const float* Dp   = (const float*)d_in[8];
  const float* gw   = (const float*)d_in[9];
  const float* gb   = (const float*)d_in[10];
  const float* sow  = (const float*)d_in[11];
  const float* qw   = (const float*)d_in[12];
  const float* kw   = (const float*)d_in[13];
  const float* vw   = (const float*)d_in[14];
  const float* ow   = (const float*)d_in[15];
  const float* qnw  = (const float*)d_in[16];
  const float* knw  = (const float*)d_in[17];
  const float* dww  = (const float*)d_in[18];
  const float* dwb  = (const float*)d_in[19];
  const float* pww  = (const float*)d_in[20];
  const float* pwb  = (const float*)d_in[21];
  const float* mgw  = (const float*)d_in[22];
  const float* ew1  = (const float*)d_in[23];
  const float* ew2  = (const float*)d_in[24];
  const float* elw  = (const float*)d_in[25];
  const float* elb  = (const float*)d_in[26];
  float* out = (float*)d_out;

  char* base = (char*)d_ws; size_t off = 0;
  auto alloc = [&](size_t b) { void* p = base + off; off += (b + 255) & ~(size_t)255; return p; };
  float* xn    = (float*)alloc(2048ull * 1024 * 4);
  u16*   xnb   = (u16*)  alloc(2048ull * 1024 * 2);
  float* wr    = (float*)alloc(2048ull * 4 * 4);
  float* ssm   = (float*)alloc(2048ull * 144 * 4);
  float* aprod = (float*)alloc(2048ull * 64 * 4);
  float* sloc  = (float*)alloc(2048ull * 64 * 4);
  float* cin   = (float*)alloc(2048ull * 64 * 4);
  float* ysm   = (float*)alloc(2048ull * 16 * 4);
  u16*   ssdin = (u16*)  alloc(2048ull * 1024 * 2);
  float* outss = (float*)alloc(2048ull * 1024 * 4);
  u16*   qpre  = (u16*)  alloc(2048ull * 1024 * 2);
  u16*   kpre  = (u16*)  alloc(2048ull * 256 * 2);
  u16*   vT    = (u16*)  alloc(2048ull * 256 * 2);
  u16*   qro   = (u16*)  alloc(2048ull * 1024 * 2);
  u16*   kro   = (u16*)  alloc(2048ull * 256 * 2);
  u16*   acat  = (u16*)  alloc(2048ull * 1024 * 2);
  float* outat = (float*)alloc(2048ull * 1024 * 4);
  u16*   cva   = (u16*)  alloc(2048ull * 1024 * 2);
  float* outcv = (float*)alloc(2048ull * 1024 * 4);
  float* x2    = (float*)alloc(2048ull * 1024 * 4);
  u16*   x2b   = (u16*)  alloc(2048ull * 1024 * 2);
  float* wfull = (float*)alloc(2048ull * 4 * 4);
  float* moe   = (float*)alloc(2048ull * 1024 * 4);
  // transposed bf16 weights (persistent through launch)
  u16* xpwt = (u16*)alloc(256ull  * 1024 * 2);
  u16* gwt  = (u16*)alloc(1024ull * 1024 * 2);
  u16* sowt = (u16*)alloc(1024ull * 1024 * 2);
  u16* qkvt = (u16*)alloc(1536ull * 1024 * 2);
  u16* owt  = (u16*)alloc(1024ull * 1024 * 2);
  u16* pwwt = (u16*)alloc(1024ull * 1024 * 2);
  // per-expert staging (reused each iteration)
  u16* ew1t = (u16*)alloc(8192ull * 1024 * 2);
  u16* ew2t = (u16*)alloc(1024ull * 4096 * 2);
  u16* ewlt = (u16*)alloc(1024ull * 1024 * 2);
  char* big = (char*)alloc(67108864ull);   // scores | (h, act, t2)
  u16* scores = (u16*)big;
  u16* hbuf   = (u16*)big;
  u16* act    = (u16*)(big + 33554432);
  u16* t2     = (u16*)(big + 50331648);

  // ---- front transposes (independent of activations)
  wtrans_k<<<dim3(3, 16), 256, 0, stream>>>(xpw, xpwt, 1024, 144);
  wtrans_k<<<dim3(16, 16), 256, 0, stream>>>(gw, gwt, 1024, 1024);
  wtrans_k<<<dim3(16, 16), 256, 0, stream>>>(sow, sowt, 1024, 1024);
  wtrans_k<<<dim3(16, 16), 256, 0, stream>>>(qw, qkvt, 1024, 1024);
  wtrans_k<<<dim3(4, 16), 256, 0, stream>>>(kw, qkvt + 1024ull * 1024, 1024, 256);
  wtrans_k<<<dim3(4, 16), 256, 0, stream>>>(vw, qkvt + 1280ull * 1024, 1024, 256);
  wtrans_k<<<dim3(16, 16), 256, 0, stream>>>(ow, owt, 1024, 1024);
  wtrans_k<<<dim3(16, 16), 256, 0, stream>>>(pww, pwwt, 1024, 1024);

  rms1_k<<<2048, 256, 0, stream>>>(x, goal, n1w, xn, xnb);
  router_k<<<2048, 256, 0, stream>>>(xn, rw, wr);

  { GemmP p{}; p.A = xnb; p.lda = 1024; p.B = xpwt; p.ldb = 1024; p.C = ssm; p.ldc = 144;
    p.M = 2048; p.N = 144; p.K = 1024;
    gemm_k<1><<<dim3(2, 16, 1), 256, 0, stream>>>(p); }

  scanA_k<<<2048, 64, 0, stream>>>(ssm, Amat, aprod, sloc);
  scanB_k<<<32, 64, 0, stream>>>(aprod, sloc, cin);
  scanC_k<<<2048, 64, 0, stream>>>(ssm, Amat, cin, ysm);

  { GemmP p{}; p.A = xnb; p.lda = 1024; p.B = gwt; p.ldb = 1024; p.C = ssdin; p.ldc = 1024;
    p.M = 2048; p.N = 1024; p.K = 1024; p.p0 = gb; p.p1 = ysm; p.p2 = xn; p.p3 = Dp;
    gemm_k<2><<<dim3(8, 16, 1), 256, 0, stream>>>(p); }
  { GemmP p{}; p.A = ssdin; p.lda = 1024; p.B = sowt; p.ldb = 1024; p.C = outss; p.ldc = 1024;
    p.M = 2048; p.N = 1024; p.K = 1024;
    gemm_k<1><<<dim3(8, 16, 1), 256, 0, stream>>>(p); }

  { GemmP p{}; p.A = xnb; p.lda = 1024; p.B = qkvt; p.ldb = 1024; p.C = nullptr; p.ldc = 0;
    p.M = 2048; p.N = 1536; p.K = 1024; p.aux0 = qpre; p.aux1 = kpre; p.aux2 = vT;
    gemm_k<7><<<dim3(12, 16, 1), 256, 0, stream>>>(p); }

  rope_k<<<10240, 256, 0, stream>>>(qpre, kpre, qnw, knw, qro, kro);

  { GemmP p{}; p.A = qro; p.lda = 64; p.sAz = 65536; p.B = kro; p.ldb = 64; p.sBz = 65536;
    p.gqa = 1; p.C = scores; p.ldc = 1024; p.sCz = 1048576;
    p.M = 1024; p.N = 1024; p.K = 64; p.scale = 0.125f;
    gemm_k<5><<<dim3(8, 8, 32), 256, 0, stream>>>(p); }
  softmax_k<<<32768, 256, 0, stream>>>(scores);
  { GemmP p{}; p.A = scores; p.lda = 1024; p.sAz = 1048576; p.B = vT; p.ldb = 1024; p.sBz = 65536;
    p.gqa = 1; p.C = acat; p.ldc = 1024; p.czmode = 1;
    p.M = 1024; p.N = 64; p.K = 1024;
    gemm_k<0><<<dim3(1, 8, 32), 256, 0, stream>>>(p); }
  { GemmP p{}; p.A = acat; p.lda = 1024; p.B = owt; p.ldb = 1024; p.C = outat; p.ldc = 1024;
    p.M = 2048; p.N = 1024; p.K = 1024;
    gemm_k<1><<<dim3(8, 16, 1), 256, 0, stream>>>(p); }

  conv_k<<<2048, 256, 0, stream>>>(xn, dww, dwb, cva);
  { GemmP p{}; p.A = cva; p.lda = 1024; p.B = pwwt; p.ldb = 1024; p.C = outcv; p.ldc = 1024;
    p.M = 2048; p.N = 1024; p.K = 1024; p.p0 = pwb;
    gemm_k<3><<<dim3(8, 16, 1), 256, 0, stream>>>(p); }

  mix_k<<<2048, 256, 0, stream>>>(x, wr, outss, outat, outcv, mem, x2, x2b);
  moegate_k<<<2048, 256, 0, stream>>>(x2, n2w, mgw, wfull);

  for (int e = 0; e < 4; ++e) {
    wtrans_k<<<dim3(128, 16), 256, 0, stream>>>(ew1 + (long long)e * 1024 * 8192, ew1t, 1024, 8192);
    { GemmP p{}; p.A = x2b; p.lda = 1024; p.B = ew1t; p.ldb = 1024;
      p.C = hbuf; p.ldc = 8192; p.M = 2048; p.N = 8192; p.K = 1024;
      gemm_k<0><<<dim3(64, 16, 1), 256, 0, stream>>>(p); }
    swiglu_k<<<4096, 256, 0, stream>>>(hbuf, act);
    wtrans_k<<<dim3(16, 64), 256, 0, stream>>>(ew2 + (long long)e * 4096 * 1024, ew2t, 4096, 1024);
    { GemmP p{}; p.A = act; p.lda = 4096; p.B = ew2t; p.ldb = 4096;
      p.C = t2; p.ldc = 1024; p.M = 2048; p.N = 1024; p.K = 4096;
      gemm_k<0><<<dim3(8, 16, 1), 256, 0, stream>>>(p); }
    wtrans_k<<<dim3(16, 16), 256, 0, stream>>>(elw + (long long)e * 1024 * 1024, ewlt, 1024, 1024);
    { GemmP p{}; p.A = t2; p.lda = 1024; p.B = ewlt; p.ldb = 1024;
      p.C = moe; p.ldc = 1024; p.M = 2048; p.N = 1024; p.K = 1024;
      p.p0 = elb + e * 1024; p.p1 = wfull; p.eidx = e; p.first = (e == 0);
      gemm_k<4><<<dim3(8, 16, 1), 256, 0, stream>>>(p); }
  }

  final_k<<<2048, 256, 0, stream>>>(x2, moe, out);
}

// Round 3
// 778.101 us; speedup vs baseline: 2.7020x; 1.5656x over previous
//
#include <hip/hip_runtime.h>
#include <hip/hip_bf16.h>
#include <cstdint>

typedef unsigned short u16;
typedef __attribute__((ext_vector_type(4))) float f32x4;
typedef __attribute__((ext_vector_type(8))) short s16x8;

#define DEV __device__ __forceinline__

DEV u16 f2bf(float x) {                       // RNE f32 -> bf16
  unsigned u = __float_as_uint(x);
  u += 0x7FFFu + ((u >> 16) & 1u);
  return (u16)(u >> 16);
}
DEV float bf2f(u16 b) { return __uint_as_float(((unsigned)b) << 16); }

DEV void gload16(const void* g, void* l) {    // async global->LDS, 16B/lane
  __builtin_amdgcn_global_load_lds(
      (const __attribute__((address_space(1))) void*)g,
      (__attribute__((address_space(3))) void*)l, 16, 0, 0);
}

template<bool MAXOP>
DEV float blockRed256(float v) {
  for (int o = 32; o; o >>= 1) {
    float t = __shfl_xor(v, o);
    v = MAXOP ? fmaxf(v, t) : v + t;
  }
  __shared__ float s[4];
  __syncthreads();
  if ((threadIdx.x & 63) == 0) s[threadIdx.x >> 6] = v;
  __syncthreads();
  return MAXOP ? fmaxf(fmaxf(s[0], s[1]), fmaxf(s[2], s[3]))
               : (s[0] + s[1] + s[2] + s[3]);
}

// ------------------------------------------------- weight transpose ------
// f32 (K,N) row-major -> bf16 (N,K) row-major. ilv=1: swiglu row interleave.
__global__ __launch_bounds__(256) void wtrans_k(const float* __restrict__ in,
                                                u16* __restrict__ out,
                                                int K, int N, int ilv) {
  __shared__ float t[64][68];
  const int n0 = blockIdx.x * 64, k0 = blockIdx.y * 64;
  const int tt = threadIdx.x;
  const int kl = tt >> 4, nl = (tt & 15) * 4;
#pragma unroll
  for (int i = 0; i < 4; ++i) {
    int k = kl + i * 16;
    float4 v{0.f, 0.f, 0.f, 0.f};
    if (n0 + nl + 3 < N) {
      v = *(const float4*)(in + (long long)(k0 + k) * N + n0 + nl);
    } else {
      for (int j = 0; j < 4; ++j)
        if (n0 + nl + j < N) ((float*)&v)[j] = in[(long long)(k0 + k) * N + n0 + nl + j];
    }
    t[nl + 0][k] = v.x; t[nl + 1][k] = v.y; t[nl + 2][k] = v.z; t[nl + 3][k] = v.w;
  }
  __syncthreads();
  const int n = tt >> 2, kq = (tt & 3) * 16;
  if (n0 + n < N) {
    s16x8 o0, o1;
#pragma unroll
    for (int j = 0; j < 8; ++j) { o0[j] = (short)f2bf(t[n][kq + j]); o1[j] = (short)f2bf(t[n][kq + 8 + j]); }
    int c = n0 + n;
    int r = ilv ? ((((c & 4095) >> 4) << 5) + ((c >> 12) << 4) + (c & 15)) : c;
    u16* op = out + (long long)r * K + k0 + kq;
    *(s16x8*)op = o0; *(s16x8*)(op + 8) = o1;
  }
}

// ---------------------------------------------------------------- GEMM ----
// C[M,N] = A[M,K] @ B^T ; A bf16 (M,K) rm, B bf16 (N,K) rm.
// 128xTN tile, BK=64, 4 waves (2x2), 16x16x32 bf16 MFMA, XOR-swizzled LDS,
// double-buffered global_load_lds pipeline (prefetch t+1 over compute t).
struct GemmP {
  const u16* A; int lda; long long sAz;
  const u16* B; int ldb; long long sBz;
  void* C; int ldc; long long sCz;
  int M, N, K;
  int gqa;      // 1: B batch index = (z>>4)*4 + ((z&15)>>2)   (GQA 16q/4kv)
  int czmode;   // 1: C base = b*1048576 + h*64  (attn concat store)
  const float *p0, *p1, *p2, *p3;
  float scale; int eidx;
  u16 *aux0, *aux1, *aux2;   // EPI7: qpre, kpre, vT
};

template<int EPI, int TN>
__global__ __launch_bounds__(256) void gemm_k(GemmP p) {
  constexpr int NF = TN / 32;                 // B fragments per wave
  __shared__ u16 Al[2][128 * 64];
  __shared__ u16 Bl[2][TN * 64];
  const int z = blockIdx.z;
  const int t = threadIdx.x;
  const int lane = t & 63, wid = t >> 6;
  const int wm = wid >> 1, wn = wid & 1;
  const int m0 = blockIdx.y * 128, n0 = blockIdx.x * TN;

  const u16* Ab = p.A + (long long)z * p.sAz;
  const u16* Bb = p.B + (p.gqa ? (long long)(((z >> 4) << 2) + ((z & 15) >> 2)) * p.sBz
                               : (long long)z * p.sBz);
  const int sr = lane >> 3;                 // sub-row 0..7
  const int sg = (lane & 7) ^ sr;           // pre-swizzled k-group
  long long pao[4]; int lao[4];
  long long pbo[NF]; int lbo[NF];
#pragma unroll
  for (int c = 0; c < 4; ++c) {
    int rbase = c * 32 + wid * 8;
    int ra = m0 + rbase + sr; if (ra > p.M - 1) ra = p.M - 1;
    pao[c] = (long long)ra * p.lda + sg * 8;
    lao[c] = rbase * 64;
  }
#pragma unroll
  for (int c = 0; c < NF; ++c) {
    int rbase = c * 32 + wid * 8;
    int rb = n0 + rbase + sr; if (rb > p.N - 1) rb = p.N - 1;
    pbo[c] = (long long)rb * p.ldb + sg * 8;
    lbo[c] = rbase * 64;
  }

  f32x4 acc[4][NF];
#pragma unroll
  for (int i = 0; i < 4; ++i)
#pragma unroll
    for (int j = 0; j < NF; ++j) acc[i][j] = f32x4{0.f, 0.f, 0.f, 0.f};

  // prologue: stage tile 0 into buffer 0
#pragma unroll
  for (int c = 0; c < 4; ++c) gload16(Ab + pao[c], &Al[0][lao[c]]);
#pragma unroll
  for (int c = 0; c < NF; ++c) gload16(Bb + pbo[c], &Bl[0][lbo[c]]);
  __syncthreads();

  const int lr = lane & 15, lk = lane >> 4;
  int cur = 0;
  for (int k0 = 0; k0 < p.K; k0 += 64) {
    int nxt = cur ^ 1;
    if (k0 + 64 < p.K) {     // prefetch next tile (stays in flight over MFMA)
#pragma unroll
      for (int c = 0; c < 4; ++c) gload16(Ab + pao[c] + k0 + 64, &Al[nxt][lao[c]]);
#pragma unroll
      for (int c = 0; c < NF; ++c) gload16(Bb + pbo[c] + k0 + 64, &Bl[nxt][lbo[c]]);
    }
#pragma unroll
    for (int kk = 0; kk < 2; ++kk) {
      s16x8 af[4], bfr[NF];
      int g = kk * 4 + lk;
#pragma unroll
      for (int i = 0; i < 4; ++i) {
        int ra = wm * 64 + i * 16 + lr;
        af[i] = *(const s16x8*)&Al[cur][ra * 64 + ((g ^ (ra & 7)) * 8)];
      }
#pragma unroll
      for (int j = 0; j < NF; ++j) {
        int rb = wn * (TN / 2) + j * 16 + lr;
        bfr[j] = *(const s16x8*)&Bl[cur][rb * 64 + ((g ^ (rb & 7)) * 8)];
      }
#pragma unroll
      for (int i = 0; i < 4; ++i)
#pragma unroll
        for (int j = 0; j < NF; ++j)
          acc[i][j] = __builtin_amdgcn_mfma_f32_16x16x32_bf16(af[i], bfr[j], acc[i][j], 0, 0, 0);
    }
    __syncthreads();         // vmcnt(0)+lgkmcnt(0)+barrier: next tile ready
    cur = nxt;
  }

  long long cb;
  if (p.czmode == 1) { int b = z >> 4, h = z & 15; cb = (long long)b * 1048576 + h * 64; }
  else cb = (long long)z * p.sCz;
  const int lq = lane >> 4;

  if (EPI == 8) {            // fused swiglu: pairs (a,g) in fragment j=2u,2u+1
#pragma unroll
    for (int i = 0; i < 4; ++i) {
#pragma unroll
      for (int u = 0; u < NF / 2; ++u) {
        int pcol = n0 / 2 + wn * (TN / 4) + u * 16 + lr;
#pragma unroll
        for (int q = 0; q < 4; ++q) {
          int row = m0 + wm * 64 + i * 16 + lq * 4 + q;
          float a = acc[i][2 * u][q], gg = acc[i][2 * u + 1][q];
          float s = a / (1.f + __expf(-a)) * gg;
          ((u16*)p.C)[cb + (long long)row * p.ldc + pcol] = f2bf(s);
        }
      }
    }
    return;
  }
#pragma unroll
  for (int i = 0; i < 4; ++i) {
#pragma unroll
    for (int j = 0; j < NF; ++j) {
      int col = n0 + wn * (TN / 2) + j * 16 + lr;
      if (col >= p.N) continue;
#pragma unroll
      for (int q = 0; q < 4; ++q) {
        int row = m0 + wm * 64 + i * 16 + lq * 4 + q;
        float v = acc[i][j][q];
        if (EPI == 0) {          // plain bf16 store
          ((u16*)p.C)[cb + (long long)row * p.ldc + col] = f2bf(v);
        } else if (EPI == 1) {   // plain f32 store
          ((float*)p.C)[cb + (long long)row * p.ldc + col] = v;
        } else if (EPI == 2) {   // sigmoid(acc+gb) * (y_small + xn*Dp) -> bf16
          float gg = 1.f / (1.f + __expf(-(v + p.p0[col])));
          float yv = p.p1[row * 16 + (col >> 6)] +
                     p.p2[(long long)row * 1024 + col] * p.p3[col >> 6];
          ((u16*)p.C)[cb + (long long)row * p.ldc + col] = f2bf(gg * yv);
        } else if (EPI == 3) {   // +bias -> f32
          ((float*)p.C)[cb + (long long)row * p.ldc + col] = v + p.p0[col];
        } else if (EPI == 4) {   // moe partial: wfull[:,eidx+z]*(acc+bias)
          float wv = p.p1[row * 4 + p.eidx + z];
          float val = wv * (v + p.p0[z * 1024 + col]);
          ((float*)p.C)[cb + (long long)row * p.ldc + col] = val;
        } else if (EPI == 5) {   // scaled bf16 (attention scores)
          ((u16*)p.C)[cb + (long long)row * p.ldc + col] = f2bf(v * p.scale);
        } else if (EPI == 7) {   // fused qkv routing
          if (col < 1024) {
            p.aux0[(long long)row * 1024 + col] = f2bf(v);
          } else if (col < 1280) {
            p.aux1[(long long)row * 256 + (col - 1024)] = f2bf(v);
          } else {
            int cc = col - 1280;
            int b = row >> 10, l = row & 1023, kvh = cc >> 6, d = cc & 63;
            p.aux2[(((long long)(b * 4 + kvh) * 64 + d) << 10) + l] = f2bf(v);
          }
        }
      }
    }
  }
}

// --------------------------------------------------------- small kernels --
__global__ void rms1_k(const float* x, const float* goal, const float* w,
                       float* xn, u16* xnb) {
  int m = blockIdx.x, t = threadIdx.x;
  const float* xr = x + (long long)m * 1024;
  float v[4]; float ss = 0.f;
#pragma unroll
  for (int i = 0; i < 4; ++i) { v[i] = xr[t + i * 256]; ss += v[i] * v[i]; }
  ss = blockRed256<false>(ss);
  float r = rsqrtf(ss * (1.f / 1024.f) + 1e-6f);
#pragma unroll
  for (int i = 0; i < 4; ++i) {
    int c = t + i * 256;
    float o = v[i] * r * w[c] + goal[(long long)m * 1024 + c];
    xn[(long long)m * 1024 + c] = o;
    xnb[(long long)m * 1024 + c] = f2bf(o);
  }
}

__global__ void router_k(const float* xn, const float* rw, float* wout) {
  int m = blockIdx.x, t = threadIdx.x;
  const float* xr = xn + (long long)m * 1024;
  float a[4] = {0.f, 0.f, 0.f, 0.f};
  for (int i = t; i < 1024; i += 256) {
    float xv = xr[i];
    const float* r = rw + i * 4;
    a[0] += xv * r[0]; a[1] += xv * r[1]; a[2] += xv * r[2]; a[3] += xv * r[3];
  }
#pragma unroll
  for (int j = 0; j < 4; ++j) a[j] = blockRed256<false>(a[j]);
  if (t == 0) {
    float mx = fmaxf(fmaxf(a[0], a[1]), fmaxf(a[2], a[3]));
    float e[4]; float s = 0.f;
    for (int j = 0; j < 4; ++j) { e[j] = __expf(a[j] - mx); s += e[j]; }
    const float mix[4] = {0.5f, 0.2f, 0.15f, 0.15f};
    float ws = 0.f;
    for (int j = 0; j < 4; ++j) { e[j] = e[j] / s * mix[j]; ws += e[j]; }
    for (int j = 0; j < 4; ++j) wout[m * 4 + j] = e[j] / ws;
  }
}

DEV float softplus_f(float x) { return x > 15.f ? x : log1pf(__expf(x)); }

__global__ void scanA_k(const float* ssm, const float* A, float* aprod, float* sloc) {
  int blk = blockIdx.x, n = threadIdx.x;
  int c = blk & 63, h = (blk >> 6) & 15, b = blk >> 10;
  float Ah = A[h * 64 + n];
  float ap = 1.f, s = 0.f;
  int l0 = c * 16;
  for (int j = 0; j < 16; ++j) {
    long long off = (long long)(b * 1024 + l0 + j) * 144;
    float d = softplus_f(ssm[off + 128 + h] + ssm[off + n]);
    float a = __expf(d * Ah);
    s = a * s + d * d;
    ap *= a;
  }
  long long o = (long long)blk * 64 + n;
  aprod[o] = ap; sloc[o] = s;
}

__global__ void scanB_k(const float* aprod, const float* sloc, float* cin) {
  int bh = blockIdx.x, n = threadIdx.x;
  float carry = 0.f;
  for (int c = 0; c < 64; ++c) {
    long long o = (long long)(bh * 64 + c) * 64 + n;
    cin[o] = carry;
    carry = aprod[o] * carry + sloc[o];
  }
}

__global__ void scanC_k(const float* ssm, const float* A, const float* cin, float* ysm) {
  int blk = blockIdx.x, n = threadIdx.x;
  int c = blk & 63, h = (blk >> 6) & 15, b = blk >> 10;
  float Ah = A[h * 64 + n];
  float s = cin[(long long)blk * 64 + n];
  int l0 = c * 16;
  for (int j = 0; j < 16; ++j) {
    long long off = (long long)(b * 1024 + l0 + j) * 144;
    float d = softplus_f(ssm[off + 128 + h] + ssm[off + n]);
    float a = __expf(d * Ah);
    s = a * s + d * d;
    float yv = s * ssm[off + 64 + n];
    for (int o2 = 32; o2; o2 >>= 1) yv += __shfl_xor(yv, o2);
    if (n == 0) ysm[(long long)(b * 1024 + l0 + j) * 16 + h] = yv;
  }
}

__global__ void rope_k(const u16* qpre, const u16* kpre, const float* qnw,
                       const float* knw, u16* qro, u16* kro) {
  int rid = blockIdx.x * 4 + (threadIdx.x >> 6);
  int lane = threadIdx.x & 63;
  float v; const float* nw; int l; u16* dst;
  if (rid < 32768) {
    int b = rid >> 14, h = (rid >> 10) & 15; l = rid & 1023;
    v = bf2f(qpre[(long long)(b * 1024 + l) * 1024 + h * 64 + lane]);
    nw = qnw; dst = qro + (long long)rid * 64;
  } else {
    int r2 = rid - 32768;
    int b = r2 >> 12, kvh = (r2 >> 10) & 3; l = r2 & 1023;
    v = bf2f(kpre[(long long)(b * 1024 + l) * 256 + kvh * 64 + lane]);
    nw = knw; dst = kro + (long long)r2 * 64;
  }
  float ss = v * v;
  for (int o = 32; o; o >>= 1) ss += __shfl_xor(ss, o);
  float r = rsqrtf(ss * (1.f / 64.f) + 1e-6f);
  float vn = v * r * nw[lane];
  float pt = __shfl_xor(vn, 32);
  int i = lane & 31;
  float invf = powf(10000.f, -(float)i * (1.f / 32.f));
  float fr = (float)l * invf;
  float o2 = vn * cosf(fr) + ((lane < 32) ? -pt : pt) * sinf(fr);
  dst[lane] = f2bf(o2);
}

__global__ void softmax_k(u16* sc) {
  u16* r = sc + (long long)blockIdx.x * 1024;
  int t = threadIdx.x;
  float v[4]; float mx = -1e30f;
#pragma unroll
  for (int i = 0; i < 4; ++i) { v[i] = bf2f(r[t + i * 256]); mx = fmaxf(mx, v[i]); }
  mx = blockRed256<true>(mx);
  float s = 0.f;
#pragma unroll
  for (int i = 0; i < 4; ++i) { v[i] = __expf(v[i] - mx); s += v[i]; }
  s = blockRed256<false>(s);
  float inv = 1.f / s;
#pragma unroll
  for (int i = 0; i < 4; ++i) r[t + i * 256] = f2bf(v[i] * inv);
}

__global__ void conv_k(const float* xn, const float* dww, const float* dwb, u16* outb) {
  int m = blockIdx.x; int l = m & 1023;
#pragma unroll
  for (int i = 0; i < 4; ++i) {
    int d = threadIdx.x + i * 256;
    float xm = l > 0    ? xn[(long long)(m - 1) * 1024 + d] : 0.f;
    float x0 =            xn[(long long)m * 1024 + d];
    float xp = l < 1023 ? xn[(long long)(m + 1) * 1024 + d] : 0.f;
    float dv = xm * dww[d * 3] + x0 * dww[d * 3 + 1] + xp * dww[d * 3 + 2] + dwb[d];
    outb[(long long)m * 1024 + d] = f2bf(dv / (1.f + __expf(-dv)));
  }
}

__global__ void mix_k(const float* x, const float* w, const float* oss,
                      const float* oat, const float* ocv, const float* mem,
                      float* x2, u16* x2b) {
  int m = blockIdx.x;
  float w0 = w[m * 4], w1 = w[m * 4 + 1], w2 = w[m * 4 + 2], w3 = w[m * 4 + 3];
#pragma unroll
  for (int j = 0; j < 4; ++j) {
    long long i = (long long)m * 1024 + threadIdx.x + j * 256;
    float v = x[i] + w0 * oss[i] + w1 * oat[i] + w2 * ocv[i] + w3 * mem[i];
    x2[i] = v; x2b[i] = f2bf(v);
  }
}

__global__ void moegate_k(const float* x2, const float* n2w, const float* mg, float* wf) {
  int m = blockIdx.x, t = threadIdx.x;
  const float* xr = x2 + (long long)m * 1024;
  float ss = 0.f, a[4] = {0.f, 0.f, 0.f, 0.f};
  for (int i = t; i < 1024; i += 256) {
    float v = xr[i]; ss += v * v;
    float vw = v * n2w[i];
    const float* g = mg + i * 4;
    a[0] += vw * g[0]; a[1] += vw * g[1]; a[2] += vw * g[2]; a[3] += vw * g[3];
  }
  ss = blockRed256<false>(ss);
#pragma unroll
  for (int j = 0; j < 4; ++j) a[j] = blockRed256<false>(a[j]);
  if (t == 0) {
    float r = rsqrtf(ss * (1.f / 1024.f) + 1e-6f);
    float mx = -1e30f;
    for (int j = 0; j < 4; ++j) { a[j] *= r; mx = fmaxf(mx, a[j]); }
    float e[4]; float s = 0.f;
    for (int j = 0; j < 4; ++j) { e[j] = __expf(a[j] - mx); s += e[j]; }
    for (int j = 0; j < 4; ++j) e[j] /= s;
    int i0 = 0;
    for (int j = 1; j < 4; ++j) if (e[j] > e[i0]) i0 = j;
    int i1 = -1;
    for (int j = 0; j < 4; ++j) { if (j == i0) continue; if (i1 < 0 || e[j] > e[i1]) i1 = j; }
    for (int j = 0; j < 4; ++j) wf[m * 4 + j] = (j == i0 || j == i1) ? e[j] : 0.f;
  }
}

__global__ void final_k(const float* x2, const float* m0, const float* m1,
                        const float* m2, const float* m3, float* out) {
  long long i = ((long long)blockIdx.x * 256 + threadIdx.x) * 4;
  float4 a = *(const float4*)(x2 + i);
  float4 b0 = *(const float4*)(m0 + i);
  float4 b1 = *(const float4*)(m1 + i);
  float4 b2 = *(const float4*)(m2 + i);
  float4 b3 = *(const float4*)(m3 + i);
  float4 o{a.x + b0.x + b1.x + b2.x + b3.x, a.y + b0.y + b1.y + b2.y + b3.y,
           a.z + b0.z + b1.z + b2.z + b3.z, a.w + b0.w + b1.w + b2.w + b3.w};
  *(float4*)(out + i) = o;
}

// ------------------------------------------------------------------ host --
extern "C" void kernel_launch(void* const* d_in, const int* in_sizes, int n_in,
                              void* d_out, int out_size, void* d_ws, size_t ws_size,
                              hipStream_t stream) {
  const float* x    = (const float*)d_in[0];
  const float* goal = (const float*)d_in[1];
  const float* mem  = (const float*)d_in[2];
  const float* n1w  = (const float*)d_in[3];
  const float* n2w  = (const float*)d_in[4];
  const float* rw   = (const float*)d_in[5];
  const float* xpw  = (const float*)d_in[6];
  const float* Amat = (const float*)d_in[7];
  const float* Dp   = (const float*)d_in[8];
  const float* gw   = (const float*)d_in[9];
  const float* gb   = (const float*)d_in[10];
  const float* sow  = (const float*)d_in[11];
  const float* qw   = (const float*)d_in[12];
  const float* kw   = (const float*)d_in[13];
  const float* vw   = (const float*)d_in[14];
  const float* ow   = (const float*)d_in[15];
  const float* qnw  = (const float*)d_in[16];
  const float* knw  = (const float*)d_in[17];
  const float* dww  = (const float*)d_in[18];
  const float* dwb  = (const float*)d_in[19];
  const float* pww  = (const float*)d_in[20];
  const float* pwb  = (const float*)d_in[21];
  const float* mgw  = (const float*)d_in[22];
  const float* ew1  = (const float*)d_in[23];
  const float* ew2  = (const float*)d_in[24];
  const float* elw  = (const float*)d_in[25];
  const float* elb  = (const float*)d_in[26];
  float* out = (float*)d_out;

  char* base = (char*)d_ws; size_t off = 0;
  auto alloc = [&](size_t b) { void* p = base + off; off += (b + 255) & ~(size_t)255; return p; };
  float* xn    = (float*)alloc(2048ull * 1024 * 4);
  u16*   xnb   = (u16*)  alloc(2048ull * 1024 * 2);
  float* wr    = (float*)alloc(2048ull * 4 * 4);
  float* ssm   = (float*)alloc(2048ull * 144 * 4);
  float* aprod = (float*)alloc(2048ull * 64 * 4);
  float* sloc  = (float*)alloc(2048ull * 64 * 4);
  float* cin   = (float*)alloc(2048ull * 64 * 4);
  float* ysm   = (float*)alloc(2048ull * 16 * 4);
  u16*   ssdin = (u16*)  alloc(2048ull * 1024 * 2);
  // U1: front = outss|outat|outcv (24MB); MoE = t2 (8MB per expert pair)
  char*  U1    = (char*) alloc(25165824ull);
  float* outss = (float*)U1;
  float* outat = (float*)(U1 + 8388608);
  float* outcv = (float*)(U1 + 16777216);
  u16*   t2    = (u16*)  U1;
  u16*   qpre  = (u16*)  alloc(2048ull * 1024 * 2);
  u16*   kpre  = (u16*)  alloc(2048ull * 256 * 2);
  u16*   vT    = (u16*)  alloc(2048ull * 256 * 2);
  u16*   qro   = (u16*)  alloc(2048ull * 1024 * 2);
  u16*   kro   = (u16*)  alloc(2048ull * 256 * 2);
  u16*   acat  = (u16*)  alloc(2048ull * 1024 * 2);
  u16*   cva   = (u16*)  alloc(2048ull * 1024 * 2);
  float* x2    = (float*)alloc(2048ull * 1024 * 4);
  u16*   x2b   = (u16*)  alloc(2048ull * 1024 * 2);
  float* wfull = (float*)alloc(2048ull * 4 * 4);
  // transposed bf16 front weights
  u16* xpwt = (u16*)alloc(256ull  * 1024 * 2);
  u16* gwt  = (u16*)alloc(1024ull * 1024 * 2);
  u16* sowt = (u16*)alloc(1024ull * 1024 * 2);
  u16* qkvt = (u16*)alloc(1536ull * 1024 * 2);
  u16* owt  = (u16*)alloc(1024ull * 1024 * 2);
  u16* pwwt = (u16*)alloc(1024ull * 1024 * 2);
  // BIG 64MB: scores | (act 32MB @0, moe4 32MB @32MB)
  char* BIG = (char*)alloc(67108864ull);
  u16*   scores = (u16*)BIG;
  u16*   actb   = (u16*)BIG;                       // 2 experts x 2048x4096 bf16
  float* moe4   = (float*)(BIG + 33554432);        // 4 x 2048x1024 f32
  // EW 32MB: per-pair ew1t (32MB) -> ew2t (16MB) -> ewlt (4MB)
  char* EW = (char*)alloc(33554432ull);
  u16* ew1t = (u16*)EW;
  u16* ew2t = (u16*)EW;
  u16* ewlt = (u16*)EW;

  // ---- front weight transposes
  wtrans_k<<<dim3(3, 16), 256, 0, stream>>>(xpw, xpwt, 1024, 144, 0);
  wtrans_k<<<dim3(16, 16), 256, 0, stream>>>(gw, gwt, 1024, 1024, 0);
  wtrans_k<<<dim3(16, 16), 256, 0, stream>>>(sow, sowt, 1024, 1024, 0);
  wtrans_k<<<dim3(16, 16), 256, 0, stream>>>(qw, qkvt, 1024, 1024, 0);
  wtrans_k<<<dim3(4, 16), 256, 0, stream>>>(kw, qkvt + 1024ull * 1024, 1024, 256, 0);
  wtrans_k<<<dim3(4, 16), 256, 0, stream>>>(vw, qkvt + 1280ull * 1024, 1024, 256, 0);
  wtrans_k<<<dim3(16, 16), 256, 0, stream>>>(ow, owt, 1024, 1024, 0);
  wtrans_k<<<dim3(16, 16), 256, 0, stream>>>(pww, pwwt, 1024, 1024, 0);

  rms1_k<<<2048, 256, 0, stream>>>(x, goal, n1w, xn, xnb);
  router_k<<<2048, 256, 0, stream>>>(xn, rw, wr);

  { GemmP p{}; p.A = xnb; p.lda = 1024; p.B = xpwt; p.ldb = 1024; p.C = ssm; p.ldc = 144;
    p.M = 2048; p.N = 144; p.K = 1024;
    gemm_k<1, 64><<<dim3(3, 16, 1), 256, 0, stream>>>(p); }

  scanA_k<<<2048, 64, 0, stream>>>(ssm, Amat, aprod, sloc);
  scanB_k<<<32, 64, 0, stream>>>(aprod, sloc, cin);
  scanC_k<<<2048, 64, 0, stream>>>(ssm, Amat, cin, ysm);

  { GemmP p{}; p.A = xnb; p.lda = 1024; p.B = gwt; p.ldb = 1024; p.C = ssdin; p.ldc = 1024;
    p.M = 2048; p.N = 1024; p.K = 1024; p.p0 = gb; p.p1 = ysm; p.p2 = xn; p.p3 = Dp;
    gemm_k<2, 64><<<dim3(16, 16, 1), 256, 0, stream>>>(p); }
  { GemmP p{}; p.A = ssdin; p.lda = 1024; p.B = sowt; p.ldb = 1024; p.C = outss; p.ldc = 1024;
    p.M = 2048; p.N = 1024; p.K = 1024;
    gemm_k<1, 64><<<dim3(16, 16, 1), 256, 0, stream>>>(p); }

  { GemmP p{}; p.A = xnb; p.lda = 1024; p.B = qkvt; p.ldb = 1024; p.C = nullptr; p.ldc = 0;
    p.M = 2048; p.N = 1536; p.K = 1024; p.aux0 = qpre; p.aux1 = kpre; p.aux2 = vT;
    gemm_k<7, 64><<<dim3(24, 16, 1), 256, 0, stream>>>(p); }

  rope_k<<<10240, 256, 0, stream>>>(qpre, kpre, qnw, knw, qro, kro);

  { GemmP p{}; p.A = qro; p.lda = 64; p.sAz = 65536; p.B = kro; p.ldb = 64; p.sBz = 65536;
    p.gqa = 1; p.C = scores; p.ldc = 1024; p.sCz = 1048576;
    p.M = 1024; p.N = 1024; p.K = 64; p.scale = 0.125f;
    gemm_k<5, 128><<<dim3(8, 8, 32), 256, 0, stream>>>(p); }
  softmax_k<<<32768, 256, 0, stream>>>(scores);
  { GemmP p{}; p.A = scores; p.lda = 1024; p.sAz = 1048576; p.B = vT; p.ldb = 1024; p.sBz = 65536;
    p.gqa = 1; p.C = acat; p.ldc = 1024; p.czmode = 1;
    p.M = 1024; p.N = 64; p.K = 1024;
    gemm_k<0, 64><<<dim3(1, 8, 32), 256, 0, stream>>>(p); }
  { GemmP p{}; p.A = acat; p.lda = 1024; p.B = owt; p.ldb = 1024; p.C = outat; p.ldc = 1024;
    p.M = 2048; p.N = 1024; p.K = 1024;
    gemm_k<1, 64><<<dim3(16, 16, 1), 256, 0, stream>>>(p); }

  conv_k<<<2048, 256, 0, stream>>>(xn, dww, dwb, cva);
  { GemmP p{}; p.A = cva; p.lda = 1024; p.B = pwwt; p.ldb = 1024; p.C = outcv; p.ldc = 1024;
    p.M = 2048; p.N = 1024; p.K = 1024; p.p0 = pwb;
    gemm_k<3, 64><<<dim3(16, 16, 1), 256, 0, stream>>>(p); }

  mix_k<<<2048, 256, 0, stream>>>(x, wr, outss, outat, outcv, mem, x2, x2b);
  moegate_k<<<2048, 256, 0, stream>>>(x2, n2w, mgw, wfull);

  for (int pr = 0; pr < 2; ++pr) {             // expert pairs {0,1}, {2,3}
    int e0 = pr * 2;
    // w1 (interleaved swiglu layout), 2 experts
    wtrans_k<<<dim3(128, 16), 256, 0, stream>>>(ew1 + (long long)e0 * 8388608, ew1t, 1024, 8192, 1);
    wtrans_k<<<dim3(128, 16), 256, 0, stream>>>(ew1 + (long long)(e0 + 1) * 8388608, ew1t + 8388608ull, 1024, 8192, 1);
    { GemmP p{}; p.A = x2b; p.lda = 1024; p.sAz = 0; p.B = ew1t; p.ldb = 1024; p.sBz = 8192ull * 1024;
      p.C = actb; p.ldc = 4096; p.sCz = 2048ull * 4096; p.M = 2048; p.N = 8192; p.K = 1024;
      gemm_k<8, 128><<<dim3(64, 16, 2), 256, 0, stream>>>(p); }
    wtrans_k<<<dim3(16, 64), 256, 0, stream>>>(ew2 + (long long)e0 * 4194304, ew2t, 4096, 1024, 0);
    wtrans_k<<<dim3(16, 64), 256, 0, stream>>>(ew2 + (long long)(e0 + 1) * 4194304, ew2t + 4194304ull, 4096, 1024, 0);
    { GemmP p{}; p.A = actb; p.lda = 4096; p.sAz = 2048ull * 4096; p.B = ew2t; p.ldb = 4096;
      p.sBz = 1024ull * 4096; p.C = t2; p.ldc = 1024; p.sCz = 2048ull * 1024;
      p.M = 2048; p.N = 1024; p.K = 4096;
      gemm_k<0, 64><<<dim3(16, 16, 2), 256, 0, stream>>>(p); }
    wtrans_k<<<dim3(16, 16), 256, 0, stream>>>(elw + (long long)e0 * 1048576, ewlt, 1024, 1024, 0);
    wtrans_k<<<dim3(16, 16), 256, 0, stream>>>(elw + (long long)(e0 + 1) * 1048576, ewlt + 1048576ull, 1024, 1024, 0);
    { GemmP p{}; p.A = t2; p.lda = 1024; p.sAz = 2048ull * 1024; p.B = ewlt; p.ldb = 1024;
      p.sBz = 1024ull * 1024; p.C = moe4 + (long long)e0 * 2097152; p.ldc = 1024; p.sCz = 2048ull * 1024;
      p.M = 2048; p.N = 1024; p.K = 1024;
      p.p0 = elb + e0 * 1024; p.p1 = wfull; p.eidx = e0;
      gemm_k<4, 64><<<dim3(16, 16, 2), 256, 0, stream>>>(p); }
  }

  final_k<<<2048, 256, 0, stream>>>(x2, moe4, moe4 + 2097152, moe4 + 2ull * 2097152,
                                    moe4 + 3ull * 2097152, out);
}

// Round 4
// 774.422 us; speedup vs baseline: 2.7148x; 1.0048x over previous
//
#include <hip/hip_runtime.h>
#include <hip/hip_bf16.h>
#include <cstdint>

typedef unsigned short u16;
typedef __attribute__((ext_vector_type(4))) float f32x4;
typedef __attribute__((ext_vector_type(8))) short s16x8;

#define DEV __device__ __forceinline__

DEV u16 f2bf(float x) {                       // RNE f32 -> bf16
  unsigned u = __float_as_uint(x);
  u += 0x7FFFu + ((u >> 16) & 1u);
  return (u16)(u >> 16);
}
DEV float bf2f(u16 b) { return __uint_as_float(((unsigned)b) << 16); }

DEV void gload16(const void* g, void* l) {    // async global->LDS, 16B/lane
  __builtin_amdgcn_global_load_lds(
      (const __attribute__((address_space(1))) void*)g,
      (__attribute__((address_space(3))) void*)l, 16, 0, 0);
}

template<bool MAXOP>
DEV float blockRed256(float v) {
  for (int o = 32; o; o >>= 1) {
    float t = __shfl_xor(v, o);
    v = MAXOP ? fmaxf(v, t) : v + t;
  }
  __shared__ float s[4];
  __syncthreads();
  if ((threadIdx.x & 63) == 0) s[threadIdx.x >> 6] = v;
  __syncthreads();
  return MAXOP ? fmaxf(fmaxf(s[0], s[1]), fmaxf(s[2], s[3]))
               : (s[0] + s[1] + s[2] + s[3]);
}

// ------------------------------------------------- weight transpose ------
// f32 (K,N) row-major -> bf16 (N,K) row-major. ilv=1: swiglu row interleave.
__global__ __launch_bounds__(256) void wtrans_k(const float* __restrict__ in,
                                                u16* __restrict__ out,
                                                int K, int N, int ilv) {
  __shared__ float t[64][68];
  const int n0 = blockIdx.x * 64, k0 = blockIdx.y * 64;
  const int tt = threadIdx.x;
  const int kl = tt >> 4, nl = (tt & 15) * 4;
#pragma unroll
  for (int i = 0; i < 4; ++i) {
    int k = kl + i * 16;
    float4 v{0.f, 0.f, 0.f, 0.f};
    if (n0 + nl + 3 < N) {
      v = *(const float4*)(in + (long long)(k0 + k) * N + n0 + nl);
    } else {
      for (int j = 0; j < 4; ++j)
        if (n0 + nl + j < N) ((float*)&v)[j] = in[(long long)(k0 + k) * N + n0 + nl + j];
    }
    t[nl + 0][k] = v.x; t[nl + 1][k] = v.y; t[nl + 2][k] = v.z; t[nl + 3][k] = v.w;
  }
  __syncthreads();
  const int n = tt >> 2, kq = (tt & 3) * 16;
  if (n0 + n < N) {
    s16x8 o0, o1;
#pragma unroll
    for (int j = 0; j < 8; ++j) { o0[j] = (short)f2bf(t[n][kq + j]); o1[j] = (short)f2bf(t[n][kq + 8 + j]); }
    int c = n0 + n;
    int r = ilv ? ((((c & 4095) >> 4) << 5) + ((c >> 12) << 4) + (c & 15)) : c;
    u16* op = out + (long long)r * K + k0 + kq;
    *(s16x8*)op = o0; *(s16x8*)(op + 8) = o1;
  }
}

// ---------------------------------------------------------------- GEMM ----
struct GemmP {
  const u16* A; int lda; long long sAz;
  const u16* B; int ldb; long long sBz;
  void* C; int ldc; long long sCz;
  int M, N, K;
  int gqa;      // 1: B batch index = (z>>4)*4 + ((z&15)>>2)   (GQA 16q/4kv)
  int czmode;   // 1: C base = b*1048576 + h*64  (attn concat store)
  const float *p0, *p1, *p2, *p3;
  float scale; int eidx;
  u16 *aux0, *aux1, *aux2;   // EPI7: qpre, kpre, vT
};

// ---- 128xTN tile, 4 waves, double-buffered (proven) — front/attn GEMMs --
template<int EPI, int TN>
__global__ __launch_bounds__(256) void gemm_k(GemmP p) {
  constexpr int NF = TN / 32;                 // B fragments per wave
  __shared__ u16 Al[2][128 * 64];
  __shared__ u16 Bl[2][TN * 64];
  const int z = blockIdx.z;
  const int t = threadIdx.x;
  const int lane = t & 63, wid = t >> 6;
  const int wm = wid >> 1, wn = wid & 1;
  const int m0 = blockIdx.y * 128, n0 = blockIdx.x * TN;

  const u16* Ab = p.A + (long long)z * p.sAz;
  const u16* Bb = p.B + (p.gqa ? (long long)(((z >> 4) << 2) + ((z & 15) >> 2)) * p.sBz
                               : (long long)z * p.sBz);
  const int sr = lane >> 3;                 // sub-row 0..7
  const int sg = (lane & 7) ^ sr;           // pre-swizzled k-group
  long long pao[4]; int lao[4];
  long long pbo[NF]; int lbo[NF];
#pragma unroll
  for (int c = 0; c < 4; ++c) {
    int rbase = c * 32 + wid * 8;
    int ra = m0 + rbase + sr; if (ra > p.M - 1) ra = p.M - 1;
    pao[c] = (long long)ra * p.lda + sg * 8;
    lao[c] = rbase * 64;
  }
#pragma unroll
  for (int c = 0; c < NF; ++c) {
    int rbase = c * 32 + wid * 8;
    int rb = n0 + rbase + sr; if (rb > p.N - 1) rb = p.N - 1;
    pbo[c] = (long long)rb * p.ldb + sg * 8;
    lbo[c] = rbase * 64;
  }

  f32x4 acc[4][NF];
#pragma unroll
  for (int i = 0; i < 4; ++i)
#pragma unroll
    for (int j = 0; j < NF; ++j) acc[i][j] = f32x4{0.f, 0.f, 0.f, 0.f};

#pragma unroll
  for (int c = 0; c < 4; ++c) gload16(Ab + pao[c], &Al[0][lao[c]]);
#pragma unroll
  for (int c = 0; c < NF; ++c) gload16(Bb + pbo[c], &Bl[0][lbo[c]]);
  __syncthreads();

  const int lr = lane & 15, lk = lane >> 4;
  int cur = 0;
  for (int k0 = 0; k0 < p.K; k0 += 64) {
    int nxt = cur ^ 1;
    if (k0 + 64 < p.K) {
#pragma unroll
      for (int c = 0; c < 4; ++c) gload16(Ab + pao[c] + k0 + 64, &Al[nxt][lao[c]]);
#pragma unroll
      for (int c = 0; c < NF; ++c) gload16(Bb + pbo[c] + k0 + 64, &Bl[nxt][lbo[c]]);
    }
#pragma unroll
    for (int kk = 0; kk < 2; ++kk) {
      s16x8 af[4], bfr[NF];
      int g = kk * 4 + lk;
#pragma unroll
      for (int i = 0; i < 4; ++i) {
        int ra = wm * 64 + i * 16 + lr;
        af[i] = *(const s16x8*)&Al[cur][ra * 64 + ((g ^ (ra & 7)) * 8)];
      }
#pragma unroll
      for (int j = 0; j < NF; ++j) {
        int rb = wn * (TN / 2) + j * 16 + lr;
        bfr[j] = *(const s16x8*)&Bl[cur][rb * 64 + ((g ^ (rb & 7)) * 8)];
      }
#pragma unroll
      for (int i = 0; i < 4; ++i)
#pragma unroll
        for (int j = 0; j < NF; ++j)
          acc[i][j] = __builtin_amdgcn_mfma_f32_16x16x32_bf16(af[i], bfr[j], acc[i][j], 0, 0, 0);
    }
    __syncthreads();
    cur = nxt;
  }

  long long cb;
  if (p.czmode == 1) { int b = z >> 4, h = z & 15; cb = (long long)b * 1048576 + h * 64; }
  else cb = (long long)z * p.sCz;
  const int lq = lane >> 4;
#pragma unroll
  for (int i = 0; i < 4; ++i) {
#pragma unroll
    for (int j = 0; j < NF; ++j) {
      int col = n0 + wn * (TN / 2) + j * 16 + lr;
      if (col >= p.N) continue;
#pragma unroll
      for (int q = 0; q < 4; ++q) {
        int row = m0 + wm * 64 + i * 16 + lq * 4 + q;
        float v = acc[i][j][q];
        if (EPI == 0) {          // plain bf16 store
          ((u16*)p.C)[cb + (long long)row * p.ldc + col] = f2bf(v);
        } else if (EPI == 1) {   // plain f32 store
          ((float*)p.C)[cb + (long long)row * p.ldc + col] = v;
        } else if (EPI == 2) {   // sigmoid(acc+gb) * (y_small + xn*Dp) -> bf16
          float gg = 1.f / (1.f + __expf(-(v + p.p0[col])));
          float yv = p.p1[row * 16 + (col >> 6)] +
                     p.p2[(long long)row * 1024 + col] * p.p3[col >> 6];
          ((u16*)p.C)[cb + (long long)row * p.ldc + col] = f2bf(gg * yv);
        } else if (EPI == 3) {   // +bias -> f32
          ((float*)p.C)[cb + (long long)row * p.ldc + col] = v + p.p0[col];
        } else if (EPI == 5) {   // scaled bf16 (attention scores)
          ((u16*)p.C)[cb + (long long)row * p.ldc + col] = f2bf(v * p.scale);
        } else if (EPI == 7) {   // fused qkv routing
          if (col < 1024) {
            p.aux0[(long long)row * 1024 + col] = f2bf(v);
          } else if (col < 1280) {
            p.aux1[(long long)row * 256 + (col - 1024)] = f2bf(v);
          } else {
            int cc = col - 1280;
            int b = row >> 10, l = row & 1023, kvh = cc >> 6, d = cc & 63;
            p.aux2[(((long long)(b * 4 + kvh) * 64 + d) << 10) + l] = f2bf(v);
          }
        }
      }
    }
  }
}

// ---- 256x128 tile, 8 waves, ring-3 LDS + counted vmcnt — MoE GEMMs ------
// EPI: 8 = fused swiglu (interleaved B rows), 0 = bf16 store, 4 = moe partial
template<int EPI>
__global__ __launch_bounds__(512) void gemm256_k(GemmP p) {
  __shared__ u16 Al[3][256 * 64];   // 96 KB
  __shared__ u16 Bl[3][128 * 64];   // 48 KB
  // bijective XCD-chunk swizzle (requires nwg % 8 == 0)
  const int nx = gridDim.x, ny = gridDim.y;
  const int nwg = nx * ny * gridDim.z;
  int flat = (blockIdx.z * ny + blockIdx.y) * nx + blockIdx.x;
  if ((nwg & 7) == 0) flat = (flat & 7) * (nwg >> 3) + (flat >> 3);
  const int bx = flat % nx; int rem = flat / nx;
  const int by = rem % ny;  const int bz = rem / ny;

  const int t = threadIdx.x;
  const int lane = t & 63, wid = t >> 6;      // 8 waves
  const int wm = wid >> 1, wn = wid & 1;      // 4 x 2
  const int m0 = by * 256, n0 = bx * 128;

  const u16* Ab = p.A + (long long)bz * p.sAz;
  const u16* Bb = p.B + (long long)bz * p.sBz;
  const int sr = lane >> 3;
  const int sg = (lane & 7) ^ sr;
  long long pao[4]; int lao[4];
  long long pbo[2]; int lbo[2];
#pragma unroll
  for (int c = 0; c < 4; ++c) {               // A: 256 rows = 8 waves x 4 x 8
    int rbase = c * 64 + wid * 8;
    pao[c] = (long long)(m0 + rbase + sr) * p.lda + sg * 8;
    lao[c] = rbase * 64;
  }
#pragma unroll
  for (int c = 0; c < 2; ++c) {               // B: 128 rows = 8 waves x 2 x 8
    int rbase = c * 64 + wid * 8;
    pbo[c] = (long long)(n0 + rbase + sr) * p.ldb + sg * 8;
    lbo[c] = rbase * 64;
  }

  f32x4 acc[4][4];
#pragma unroll
  for (int i = 0; i < 4; ++i)
#pragma unroll
    for (int j = 0; j < 4; ++j) acc[i][j] = f32x4{0.f, 0.f, 0.f, 0.f};

  const int NT = p.K >> 6;
  // prologue: stage batches 0 and 1
#pragma unroll
  for (int c = 0; c < 4; ++c) gload16(Ab + pao[c], &Al[0][lao[c]]);
#pragma unroll
  for (int c = 0; c < 2; ++c) gload16(Bb + pbo[c], &Bl[0][lbo[c]]);
  if (NT > 1) {
#pragma unroll
    for (int c = 0; c < 4; ++c) gload16(Ab + pao[c] + 64, &Al[1][lao[c]]);
#pragma unroll
    for (int c = 0; c < 2; ++c) gload16(Bb + pbo[c] + 64, &Bl[1][lbo[c]]);
  }
  asm volatile("s_waitcnt vmcnt(6)" ::: "memory");   // batch 0 landed
  __builtin_amdgcn_s_barrier();

  const int lr = lane & 15, lk = lane >> 4;
  int cur = 0, stg = 2;
  for (int ts = 0; ts < NT; ++ts) {
    if (ts + 2 < NT) {                 // stage batch ts+2, keep 6 in flight
      long long ko = (long long)(ts + 2) * 64;
#pragma unroll
      for (int c = 0; c < 4; ++c) gload16(Ab + pao[c] + ko, &Al[stg][lao[c]]);
#pragma unroll
      for (int c = 0; c < 2; ++c) gload16(Bb + pbo[c] + ko, &Bl[stg][lbo[c]]);
      asm volatile("s_waitcnt vmcnt(6)" ::: "memory");  // batch ts+1 landed
    } else {
      asm volatile("s_waitcnt vmcnt(0)" ::: "memory");  // tail drain
    }
#pragma unroll
    for (int kk = 0; kk < 2; ++kk) {
      s16x8 af[4], bfr[4];
      int g = kk * 4 + lk;
#pragma unroll
      for (int i = 0; i < 4; ++i) {
        int ra = wm * 64 + i * 16 + lr;
        af[i] = *(const s16x8*)&Al[cur][ra * 64 + ((g ^ (ra & 7)) * 8)];
        int rb = wn * 64 + i * 16 + lr;
        bfr[i] = *(const s16x8*)&Bl[cur][rb * 64 + ((g ^ (rb & 7)) * 8)];
      }
      __builtin_amdgcn_s_setprio(1);
#pragma unroll
      for (int i = 0; i < 4; ++i)
#pragma unroll
        for (int j = 0; j < 4; ++j)
          acc[i][j] = __builtin_amdgcn_mfma_f32_16x16x32_bf16(af[i], bfr[j], acc[i][j], 0, 0, 0);
      __builtin_amdgcn_s_setprio(0);
    }
    asm volatile("s_waitcnt lgkmcnt(0)" ::: "memory");
    __builtin_amdgcn_s_barrier();
    cur = (cur + 1 == 3) ? 0 : cur + 1;
    stg = (stg + 1 == 3) ? 0 : stg + 1;
  }

  long long cb = (long long)bz * p.sCz;
  const int lq = lane >> 4;
  if (EPI == 8) {                      // fused swiglu epilogue
#pragma unroll
    for (int i = 0; i < 4; ++i) {
#pragma unroll
      for (int u = 0; u < 2; ++u) {
        int pcol = (n0 >> 1) + wn * 32 + u * 16 + lr;
#pragma unroll
        for (int q = 0; q < 4; ++q) {
          int row = m0 + wm * 64 + i * 16 + lq * 4 + q;
          float a = acc[i][2 * u][q], gg = acc[i][2 * u + 1][q];
          ((u16*)p.C)[cb + (long long)row * p.ldc + pcol] =
              f2bf(a / (1.f + __expf(-a)) * gg);
        }
      }
    }
    return;
  }
#pragma unroll
  for (int i = 0; i < 4; ++i) {
#pragma unroll
    for (int j = 0; j < 4; ++j) {
      int col = n0 + wn * 64 + j * 16 + lr;
#pragma unroll
      for (int q = 0; q < 4; ++q) {
        int row = m0 + wm * 64 + i * 16 + lq * 4 + q;
        float v = acc[i][j][q];
        if (EPI == 0) {
          ((u16*)p.C)[cb + (long long)row * p.ldc + col] = f2bf(v);
        } else if (EPI == 4) {         // moe partial: wfull[:,z]*(acc+bias)
          float wv = p.p1[row * 4 + bz];
          ((float*)p.C)[cb + (long long)row * p.ldc + col] =
              wv * (v + p.p0[bz * 1024 + col]);
        }
      }
    }
  }
}

// --------------------------------------------------------- small kernels --
__global__ void rms1_k(const float* x, const float* goal, const float* w,
                       float* xn, u16* xnb) {
  int m = blockIdx.x, t = threadIdx.x;
  const float* xr = x + (long long)m * 1024;
  float v[4]; float ss = 0.f;
#pragma unroll
  for (int i = 0; i < 4; ++i) { v[i] = xr[t + i * 256]; ss += v[i] * v[i]; }
  ss = blockRed256<false>(ss);
  float r = rsqrtf(ss * (1.f / 1024.f) + 1e-6f);
#pragma unroll
  for (int i = 0; i < 4; ++i) {
    int c = t + i * 256;
    float o = v[i] * r * w[c] + goal[(long long)m * 1024 + c];
    xn[(long long)m * 1024 + c] = o;
    xnb[(long long)m * 1024 + c] = f2bf(o);
  }
}

__global__ void router_k(const float* xn, const float* rw, float* wout) {
  int m = blockIdx.x, t = threadIdx.x;
  const float* xr = xn + (long long)m * 1024;
  float a[4] = {0.f, 0.f, 0.f, 0.f};
  for (int i = t; i < 1024; i += 256) {
    float xv = xr[i];
    const float* r = rw + i * 4;
    a[0] += xv * r[0]; a[1] += xv * r[1]; a[2] += xv * r[2]; a[3] += xv * r[3];
  }
#pragma unroll
  for (int j = 0; j < 4; ++j) a[j] = blockRed256<false>(a[j]);
  if (t == 0) {
    float mx = fmaxf(fmaxf(a[0], a[1]), fmaxf(a[2], a[3]));
    float e[4]; float s = 0.f;
    for (int j = 0; j < 4; ++j) { e[j] = __expf(a[j] - mx); s += e[j]; }
    const float mix[4] = {0.5f, 0.2f, 0.15f, 0.15f};
    float ws = 0.f;
    for (int j = 0; j < 4; ++j) { e[j] = e[j] / s * mix[j]; ws += e[j]; }
    for (int j = 0; j < 4; ++j) wout[m * 4 + j] = e[j] / ws;
  }
}

DEV float softplus_f(float x) { return x > 15.f ? x : log1pf(__expf(x)); }

__global__ void scanA_k(const float* ssm, const float* A, float* aprod, float* sloc) {
  int blk = blockIdx.x, n = threadIdx.x;
  int c = blk & 63, h = (blk >> 6) & 15, b = blk >> 10;
  float Ah = A[h * 64 + n];
  float ap = 1.f, s = 0.f;
  int l0 = c * 16;
  for (int j = 0; j < 16; ++j) {
    long long off = (long long)(b * 1024 + l0 + j) * 144;
    float d = softplus_f(ssm[off + 128 + h] + ssm[off + n]);
    float a = __expf(d * Ah);
    s = a * s + d * d;
    ap *= a;
  }
  long long o = (long long)blk * 64 + n;
  aprod[o] = ap; sloc[o] = s;
}

__global__ void scanB_k(const float* aprod, const float* sloc, float* cin) {
  int bh = blockIdx.x, n = threadIdx.x;
  float carry = 0.f;
  for (int c = 0; c < 64; ++c) {
    long long o = (long long)(bh * 64 + c) * 64 + n;
    cin[o] = carry;
    carry = aprod[o] * carry + sloc[o];
  }
}

__global__ void scanC_k(const float* ssm, const float* A, const float* cin, float* ysm) {
  int blk = blockIdx.x, n = threadIdx.x;
  int c = blk & 63, h = (blk >> 6) & 15, b = blk >> 10;
  float Ah = A[h * 64 + n];
  float s = cin[(long long)blk * 64 + n];
  int l0 = c * 16;
  for (int j = 0; j < 16; ++j) {
    long long off = (long long)(b * 1024 + l0 + j) * 144;
    float d = softplus_f(ssm[off + 128 + h] + ssm[off + n]);
    float a = __expf(d * Ah);
    s = a * s + d * d;
    float yv = s * ssm[off + 64 + n];
    for (int o2 = 32; o2; o2 >>= 1) yv += __shfl_xor(yv, o2);
    if (n == 0) ysm[(long long)(b * 1024 + l0 + j) * 16 + h] = yv;
  }
}

__global__ void rope_k(const u16* qpre, const u16* kpre, const float* qnw,
                       const float* knw, u16* qro, u16* kro) {
  int rid = blockIdx.x * 4 + (threadIdx.x >> 6);
  int lane = threadIdx.x & 63;
  float v; const float* nw; int l; u16* dst;
  if (rid < 32768) {
    int b = rid >> 14, h = (rid >> 10) & 15; l = rid & 1023;
    v = bf2f(qpre[(long long)(b * 1024 + l) * 1024 + h * 64 + lane]);
    nw = qnw; dst = qro + (long long)rid * 64;
  } else {
    int r2 = rid - 32768;
    int b = r2 >> 12, kvh = (r2 >> 10) & 3; l = r2 & 1023;
    v = bf2f(kpre[(long long)(b * 1024 + l) * 256 + kvh * 64 + lane]);
    nw = knw; dst = kro + (long long)r2 * 64;
  }
  float ss = v * v;
  for (int o = 32; o; o >>= 1) ss += __shfl_xor(ss, o);
  float r = rsqrtf(ss * (1.f / 64.f) + 1e-6f);
  float vn = v * r * nw[lane];
  float pt = __shfl_xor(vn, 32);
  int i = lane & 31;
  float invf = powf(10000.f, -(float)i * (1.f / 32.f));
  float fr = (float)l * invf;
  float o2 = vn * cosf(fr) + ((lane < 32) ? -pt : pt) * sinf(fr);
  dst[lane] = f2bf(o2);
}

__global__ void softmax_k(u16* sc) {
  u16* r = sc + (long long)blockIdx.x * 1024;
  int t = threadIdx.x;
  float v[4]; float mx = -1e30f;
#pragma unroll
  for (int i = 0; i < 4; ++i) { v[i] = bf2f(r[t + i * 256]); mx = fmaxf(mx, v[i]); }
  mx = blockRed256<true>(mx);
  float s = 0.f;
#pragma unroll
  for (int i = 0; i < 4; ++i) { v[i] = __expf(v[i] - mx); s += v[i]; }
  s = blockRed256<false>(s);
  float inv = 1.f / s;
#pragma unroll
  for (int i = 0; i < 4; ++i) r[t + i * 256] = f2bf(v[i] * inv);
}

__global__ void conv_k(const float* xn, const float* dww, const float* dwb, u16* outb) {
  int m = blockIdx.x; int l = m & 1023;
#pragma unroll
  for (int i = 0; i < 4; ++i) {
    int d = threadIdx.x + i * 256;
    float xm = l > 0    ? xn[(long long)(m - 1) * 1024 + d] : 0.f;
    float x0 =            xn[(long long)m * 1024 + d];
    float xp = l < 1023 ? xn[(long long)(m + 1) * 1024 + d] : 0.f;
    float dv = xm * dww[d * 3] + x0 * dww[d * 3 + 1] + xp * dww[d * 3 + 2] + dwb[d];
    outb[(long long)m * 1024 + d] = f2bf(dv / (1.f + __expf(-dv)));
  }
}

__global__ void mix_k(const float* x, const float* w, const float* oss,
                      const float* oat, const float* ocv, const float* mem,
                      float* x2, u16* x2b) {
  int m = blockIdx.x;
  float w0 = w[m * 4], w1 = w[m * 4 + 1], w2 = w[m * 4 + 2], w3 = w[m * 4 + 3];
#pragma unroll
  for (int j = 0; j < 4; ++j) {
    long long i = (long long)m * 1024 + threadIdx.x + j * 256;
    float v = x[i] + w0 * oss[i] + w1 * oat[i] + w2 * ocv[i] + w3 * mem[i];
    x2[i] = v; x2b[i] = f2bf(v);
  }
}

__global__ void moegate_k(const float* x2, const float* n2w, const float* mg, float* wf) {
  int m = blockIdx.x, t = threadIdx.x;
  const float* xr = x2 + (long long)m * 1024;
  float ss = 0.f, a[4] = {0.f, 0.f, 0.f, 0.f};
  for (int i = t; i < 1024; i += 256) {
    float v = xr[i]; ss += v * v;
    float vw = v * n2w[i];
    const float* g = mg + i * 4;
    a[0] += vw * g[0]; a[1] += vw * g[1]; a[2] += vw * g[2]; a[3] += vw * g[3];
  }
  ss = blockRed256<false>(ss);
#pragma unroll
  for (int j = 0; j < 4; ++j) a[j] = blockRed256<false>(a[j]);
  if (t == 0) {
    float r = rsqrtf(ss * (1.f / 1024.f) + 1e-6f);
    float mx = -1e30f;
    for (int j = 0; j < 4; ++j) { a[j] *= r; mx = fmaxf(mx, a[j]); }
    float e[4]; float s = 0.f;
    for (int j = 0; j < 4; ++j) { e[j] = __expf(a[j] - mx); s += e[j]; }
    for (int j = 0; j < 4; ++j) e[j] /= s;
    int i0 = 0;
    for (int j = 1; j < 4; ++j) if (e[j] > e[i0]) i0 = j;
    int i1 = -1;
    for (int j = 0; j < 4; ++j) { if (j == i0) continue; if (i1 < 0 || e[j] > e[i1]) i1 = j; }
    for (int j = 0; j < 4; ++j) wf[m * 4 + j] = (j == i0 || j == i1) ? e[j] : 0.f;
  }
}

__global__ void final_k(const float* x2, const float* m0, const float* m1,
                        const float* m2, const float* m3, float* out) {
  long long i = ((long long)blockIdx.x * 256 + threadIdx.x) * 4;
  float4 a = *(const float4*)(x2 + i);
  float4 b0 = *(const float4*)(m0 + i);
  float4 b1 = *(const float4*)(m1 + i);
  float4 b2 = *(const float4*)(m2 + i);
  float4 b3 = *(const float4*)(m3 + i);
  float4 o{a.x + b0.x + b1.x + b2.x + b3.x, a.y + b0.y + b1.y + b2.y + b3.y,
           a.z + b0.z + b1.z + b2.z + b3.z, a.w + b0.w + b1.w + b2.w + b3.w};
  *(float4*)(out + i) = o;
}

// ------------------------------------------------------------------ host --
extern "C" void kernel_launch(void* const* d_in, const int* in_sizes, int n_in,
                              void* d_out, int out_size, void* d_ws, size_t ws_size,
                              hipStream_t stream) {
  const float* x    = (const float*)d_in[0];
  const float* goal = (const float*)d_in[1];
  const float* mem  = (const float*)d_in[2];
  const float* n1w  = (const float*)d_in[3];
  const float* n2w  = (const float*)d_in[4];
  const float* rw   = (const float*)d_in[5];
  const float* xpw  = (const float*)d_in[6];
  const float* Amat = (const float*)d_in[7];
  const float* Dp   = (const float*)d_in[8];
  const float* gw   = (const float*)d_in[9];
  const float* gb   = (const float*)d_in[10];
  const float* sow  = (const float*)d_in[11];
  const float* qw   = (const float*)d_in[12];
  const float* kw   = (const float*)d_in[13];
  const float* vw   = (const float*)d_in[14];
  const float* ow   = (const float*)d_in[15];
  const float* qnw  = (const float*)d_in[16];
  const float* knw  = (const float*)d_in[17];
  const float* dww  = (const float*)d_in[18];
  const float* dwb  = (const float*)d_in[19];
  const float* pww  = (const float*)d_in[20];
  const float* pwb  = (const float*)d_in[21];
  const float* mgw  = (const float*)d_in[22];
  const float* ew1  = (const float*)d_in[23];
  const float* ew2  = (const float*)d_in[24];
  const float* elw  = (const float*)d_in[25];
  const float* elb  = (const float*)d_in[26];
  float* out = (float*)d_out;

  char* base = (char*)d_ws; size_t off = 0;
  auto alloc = [&](size_t b) { void* p = base + off; off += (b + 255) & ~(size_t)255; return p; };
  // ---- R0: front temporaries (all dead before MoE) — aliased by moe4 ----
  float* xn    = (float*)alloc(2048ull * 1024 * 4);
  u16*   xnb   = (u16*)  alloc(2048ull * 1024 * 2);
  float* wr    = (float*)alloc(2048ull * 4 * 4);
  float* ssm   = (float*)alloc(2048ull * 144 * 4);
  float* aprod = (float*)alloc(2048ull * 64 * 4);
  float* sloc  = (float*)alloc(2048ull * 64 * 4);
  float* cin   = (float*)alloc(2048ull * 64 * 4);
  float* ysm   = (float*)alloc(2048ull * 16 * 4);
  u16*   ssdin = (u16*)  alloc(2048ull * 1024 * 2);
  u16*   qpre  = (u16*)  alloc(2048ull * 1024 * 2);
  u16*   kpre  = (u16*)  alloc(2048ull * 256 * 2);
  u16*   vT    = (u16*)  alloc(2048ull * 256 * 2);
  u16*   qro   = (u16*)  alloc(2048ull * 1024 * 2);
  u16*   kro   = (u16*)  alloc(2048ull * 256 * 2);
  u16*   acat  = (u16*)  alloc(2048ull * 1024 * 2);
  u16*   cva   = (u16*)  alloc(2048ull * 1024 * 2);
  float* moe4  = (float*)base;                     // 32MB alias over R0 (~38MB)
  // ---- persistent past mix ----
  float* x2    = (float*)alloc(2048ull * 1024 * 4);
  u16*   x2b   = (u16*)  alloc(2048ull * 1024 * 2);
  float* wfull = (float*)alloc(2048ull * 4 * 4);
  u16* xpwt = (u16*)alloc(256ull  * 1024 * 2);
  u16* gwt  = (u16*)alloc(1024ull * 1024 * 2);
  u16* sowt = (u16*)alloc(1024ull * 1024 * 2);
  u16* qkvt = (u16*)alloc(1536ull * 1024 * 2);
  u16* owt  = (u16*)alloc(1024ull * 1024 * 2);
  u16* pwwt = (u16*)alloc(1024ull * 1024 * 2);
  // U1 24MB: front = outss|outat|outcv ; MoE = t2_4 (16MB)
  char*  U1    = (char*) alloc(25165824ull);
  float* outss = (float*)U1;
  float* outat = (float*)(U1 + 8388608);
  float* outcv = (float*)(U1 + 16777216);
  u16*   t2_4  = (u16*)  U1;
  // BIG 64MB: scores (attn) ∪ act4 (MoE, 4 x 2048x4096 bf16)
  char* BIG = (char*)alloc(67108864ull);
  u16* scores = (u16*)BIG;
  u16* act4   = (u16*)BIG;
  // EW 32MB: ew1t pair ∪ ew2t4 ∪ ewlt4 (sequential reuse)
  char* EW = (char*)alloc(33554432ull);
  u16* ew1t  = (u16*)EW;
  u16* ew2t4 = (u16*)EW;
  u16* ewlt4 = (u16*)EW;

  // ---- front weight transposes
  wtrans_k<<<dim3(3, 16), 256, 0, stream>>>(xpw, xpwt, 1024, 144, 0);
  wtrans_k<<<dim3(16, 16), 256, 0, stream>>>(gw, gwt, 1024, 1024, 0);
  wtrans_k<<<dim3(16, 16), 256, 0, stream>>>(sow, sowt, 1024, 1024, 0);
  wtrans_k<<<dim3(16, 16), 256, 0, stream>>>(qw, qkvt, 1024, 1024, 0);
  wtrans_k<<<dim3(4, 16), 256, 0, stream>>>(kw, qkvt + 1024ull * 1024, 1024, 256, 0);
  wtrans_k<<<dim3(4, 16), 256, 0, stream>>>(vw, qkvt + 1280ull * 1024, 1024, 256, 0);
  wtrans_k<<<dim3(16, 16), 256, 0, stream>>>(ow, owt, 1024, 1024, 0);
  wtrans_k<<<dim3(16, 16), 256, 0, stream>>>(pww, pwwt, 1024, 1024, 0);

  rms1_k<<<2048, 256, 0, stream>>>(x, goal, n1w, xn, xnb);
  router_k<<<2048, 256, 0, stream>>>(xn, rw, wr);

  { GemmP p{}; p.A = xnb; p.lda = 1024; p.B = xpwt; p.ldb = 1024; p.C = ssm; p.ldc = 144;
    p.M = 2048; p.N = 144; p.K = 1024;
    gemm_k<1, 64><<<dim3(3, 16, 1), 256, 0, stream>>>(p); }

  scanA_k<<<2048, 64, 0, stream>>>(ssm, Amat, aprod, sloc);
  scanB_k<<<32, 64, 0, stream>>>(aprod, sloc, cin);
  scanC_k<<<2048, 64, 0, stream>>>(ssm, Amat, cin, ysm);

  { GemmP p{}; p.A = xnb; p.lda = 1024; p.B = gwt; p.ldb = 1024; p.C = ssdin; p.ldc = 1024;
    p.M = 2048; p.N = 1024; p.K = 1024; p.p0 = gb; p.p1 = ysm; p.p2 = xn; p.p3 = Dp;
    gemm_k<2, 64><<<dim3(16, 16, 1), 256, 0, stream>>>(p); }
  { GemmP p{}; p.A = ssdin; p.lda = 1024; p.B = sowt; p.ldb = 1024; p.C = outss; p.ldc = 1024;
    p.M = 2048; p.N = 1024; p.K = 1024;
    gemm_k<1, 64><<<dim3(16, 16, 1), 256, 0, stream>>>(p); }

  { GemmP p{}; p.A = xnb; p.lda = 1024; p.B = qkvt; p.ldb = 1024; p.C = nullptr; p.ldc = 0;
    p.M = 2048; p.N = 1536; p.K = 1024; p.aux0 = qpre; p.aux1 = kpre; p.aux2 = vT;
    gemm_k<7, 64><<<dim3(24, 16, 1), 256, 0, stream>>>(p); }

  rope_k<<<10240, 256, 0, stream>>>(qpre, kpre, qnw, knw, qro, kro);

  { GemmP p{}; p.A = qro; p.lda = 64; p.sAz = 65536; p.B = kro; p.ldb = 64; p.sBz = 65536;
    p.gqa = 1; p.C = scores; p.ldc = 1024; p.sCz = 1048576;
    p.M = 1024; p.N = 1024; p.K = 64; p.scale = 0.125f;
    gemm_k<5, 128><<<dim3(8, 8, 32), 256, 0, stream>>>(p); }
  softmax_k<<<32768, 256, 0, stream>>>(scores);
  { GemmP p{}; p.A = scores; p.lda = 1024; p.sAz = 1048576; p.B = vT; p.ldb = 1024; p.sBz = 65536;
    p.gqa = 1; p.C = acat; p.ldc = 1024; p.czmode = 1;
    p.M = 1024; p.N = 64; p.K = 1024;
    gemm_k<0, 64><<<dim3(1, 8, 32), 256, 0, stream>>>(p); }
  { GemmP p{}; p.A = acat; p.lda = 1024; p.B = owt; p.ldb = 1024; p.C = outat; p.ldc = 1024;
    p.M = 2048; p.N = 1024; p.K = 1024;
    gemm_k<1, 64><<<dim3(16, 16, 1), 256, 0, stream>>>(p); }

  conv_k<<<2048, 256, 0, stream>>>(xn, dww, dwb, cva);
  { GemmP p{}; p.A = cva; p.lda = 1024; p.B = pwwt; p.ldb = 1024; p.C = outcv; p.ldc = 1024;
    p.M = 2048; p.N = 1024; p.K = 1024; p.p0 = pwb;
    gemm_k<3, 64><<<dim3(16, 16, 1), 256, 0, stream>>>(p); }

  mix_k<<<2048, 256, 0, stream>>>(x, wr, outss, outat, outcv, mem, x2, x2b);
  moegate_k<<<2048, 256, 0, stream>>>(x2, n2w, mgw, wfull);

  // ---- MoE: e_w1 (fused swiglu) per pair, then e_w2 / e_lin over z=4 ----
  for (int pr = 0; pr < 2; ++pr) {
    int e0 = pr * 2;
    wtrans_k<<<dim3(128, 16), 256, 0, stream>>>(ew1 + (long long)e0 * 8388608, ew1t, 1024, 8192, 1);
    wtrans_k<<<dim3(128, 16), 256, 0, stream>>>(ew1 + (long long)(e0 + 1) * 8388608, ew1t + 8388608ull, 1024, 8192, 1);
    GemmP p{}; p.A = x2b; p.lda = 1024; p.sAz = 0; p.B = ew1t; p.ldb = 1024; p.sBz = 8192ll * 1024;
    p.C = act4 + (long long)e0 * (2048ll * 4096); p.ldc = 4096; p.sCz = 2048ll * 4096;
    p.M = 2048; p.N = 8192; p.K = 1024;
    gemm256_k<8><<<dim3(64, 8, 2), 512, 0, stream>>>(p);
  }
  for (int e = 0; e < 4; ++e)
    wtrans_k<<<dim3(16, 64), 256, 0, stream>>>(ew2 + (long long)e * 4194304,
                                               ew2t4 + (long long)e * (1024ll * 4096), 4096, 1024, 0);
  { GemmP p{}; p.A = act4; p.lda = 4096; p.sAz = 2048ll * 4096; p.B = ew2t4; p.ldb = 4096;
    p.sBz = 1024ll * 4096; p.C = t2_4; p.ldc = 1024; p.sCz = 2048ll * 1024;
    p.M = 2048; p.N = 1024; p.K = 4096;
    gemm256_k<0><<<dim3(8, 8, 4), 512, 0, stream>>>(p); }
  for (int e = 0; e < 4; ++e)
    wtrans_k<<<dim3(16, 16), 256, 0, stream>>>(elw + (long long)e * 1048576,
                                               ewlt4 + (long long)e * (1024ll * 1024), 1024, 1024, 0);
  { GemmP p{}; p.A = t2_4; p.lda = 1024; p.sAz = 2048ll * 1024; p.B = ewlt4; p.ldb = 1024;
    p.sBz = 1024ll * 1024; p.C = moe4; p.ldc = 1024; p.sCz = 2048ll * 1024;
    p.M = 2048; p.N = 1024; p.K = 1024; p.p0 = elb; p.p1 = wfull; p.eidx = 0;
    gemm256_k<4><<<dim3(8, 8, 4), 512, 0, stream>>>(p); }

  final_k<<<2048, 256, 0, stream>>>(x2, moe4, moe4 + 2097152, moe4 + 2ull * 2097152,
                                    moe4 + 3ull * 2097152, out);
}

// Round 5
// 762.659 us; speedup vs baseline: 2.7567x; 1.0154x over previous
//
#include <hip/hip_runtime.h>
#include <hip/hip_bf16.h>
#include <cstdint>

typedef unsigned short u16;
typedef __attribute__((ext_vector_type(4))) float f32x4;
typedef __attribute__((ext_vector_type(8))) short s16x8;

#define DEV __device__ __forceinline__

DEV u16 f2bf(float x) {                       // RNE f32 -> bf16
  unsigned u = __float_as_uint(x);
  u += 0x7FFFu + ((u >> 16) & 1u);
  return (u16)(u >> 16);
}
DEV float bf2f(u16 b) { return __uint_as_float(((unsigned)b) << 16); }

DEV void gload16(const void* g, void* l) {    // async global->LDS, 16B/lane
  __builtin_amdgcn_global_load_lds(
      (const __attribute__((address_space(1))) void*)g,
      (__attribute__((address_space(3))) void*)l, 16, 0, 0);
}

template<bool MAXOP>
DEV float blockRed256(float v) {
  for (int o = 32; o; o >>= 1) {
    float t = __shfl_xor(v, o);
    v = MAXOP ? fmaxf(v, t) : v + t;
  }
  __shared__ float s[4];
  __syncthreads();
  if ((threadIdx.x & 63) == 0) s[threadIdx.x >> 6] = v;
  __syncthreads();
  return MAXOP ? fmaxf(fmaxf(s[0], s[1]), fmaxf(s[2], s[3]))
               : (s[0] + s[1] + s[2] + s[3]);
}

// ------------------------------------------------- weight transpose ------
// f32 (K,N) row-major -> bf16 (N,K) row-major. ilv=1: swiglu row interleave.
__global__ __launch_bounds__(256) void wtrans_k(const float* __restrict__ in,
                                                u16* __restrict__ out,
                                                int K, int N, int ilv) {
  __shared__ float t[64][68];
  const int n0 = blockIdx.x * 64, k0 = blockIdx.y * 64;
  const int tt = threadIdx.x;
  const int kl = tt >> 4, nl = (tt & 15) * 4;
#pragma unroll
  for (int i = 0; i < 4; ++i) {
    int k = kl + i * 16;
    float4 v{0.f, 0.f, 0.f, 0.f};
    if (n0 + nl + 3 < N) {
      v = *(const float4*)(in + (long long)(k0 + k) * N + n0 + nl);
    } else {
      for (int j = 0; j < 4; ++j)
        if (n0 + nl + j < N) ((float*)&v)[j] = in[(long long)(k0 + k) * N + n0 + nl + j];
    }
    t[nl + 0][k] = v.x; t[nl + 1][k] = v.y; t[nl + 2][k] = v.z; t[nl + 3][k] = v.w;
  }
  __syncthreads();
  const int n = tt >> 2, kq = (tt & 3) * 16;
  if (n0 + n < N) {
    s16x8 o0, o1;
#pragma unroll
    for (int j = 0; j < 8; ++j) { o0[j] = (short)f2bf(t[n][kq + j]); o1[j] = (short)f2bf(t[n][kq + 8 + j]); }
    int c = n0 + n;
    int r = ilv ? ((((c & 4095) >> 4) << 5) + ((c >> 12) << 4) + (c & 15)) : c;
    u16* op = out + (long long)r * K + k0 + kq;
    *(s16x8*)op = o0; *(s16x8*)(op + 8) = o1;
  }
}

// ---------------------------------------------------------------- GEMM ----
struct GemmP {
  const u16* A; int lda; long long sAz;
  const u16* B; int ldb; long long sBz;
  void* C; int ldc; long long sCz;
  int M, N, K;
  int gqa;      // 1: B batch index = (z>>4)*4 + ((z&15)>>2)   (GQA 16q/4kv)
  int czmode;   // 1: C base = b*1048576 + h*64  (attn concat store)
  const float *p0, *p1, *p2, *p3;
  float scale; int eidx;
  u16 *aux0, *aux1, *aux2;   // EPI7: qpre, kpre, vT
};

// ---- 128xTN tile, 4 waves, double-buffered (proven) — front/attn GEMMs --
template<int EPI, int TN>
__global__ __launch_bounds__(256) void gemm_k(GemmP p) {
  constexpr int NF = TN / 32;                 // B fragments per wave
  __shared__ u16 Al[2][128 * 64];
  __shared__ u16 Bl[2][TN * 64];
  const int z = blockIdx.z;
  const int t = threadIdx.x;
  const int lane = t & 63, wid = t >> 6;
  const int wm = wid >> 1, wn = wid & 1;
  const int m0 = blockIdx.y * 128, n0 = blockIdx.x * TN;

  const u16* Ab = p.A + (long long)z * p.sAz;
  const u16* Bb = p.B + (p.gqa ? (long long)(((z >> 4) << 2) + ((z & 15) >> 2)) * p.sBz
                               : (long long)z * p.sBz);
  const int sr = lane >> 3;                 // sub-row 0..7
  const int sg = (lane & 7) ^ sr;           // pre-swizzled k-group
  long long pao[4]; int lao[4];
  long long pbo[NF]; int lbo[NF];
#pragma unroll
  for (int c = 0; c < 4; ++c) {
    int rbase = c * 32 + wid * 8;
    int ra = m0 + rbase + sr; if (ra > p.M - 1) ra = p.M - 1;
    pao[c] = (long long)ra * p.lda + sg * 8;
    lao[c] = rbase * 64;
  }
#pragma unroll
  for (int c = 0; c < NF; ++c) {
    int rbase = c * 32 + wid * 8;
    int rb = n0 + rbase + sr; if (rb > p.N - 1) rb = p.N - 1;
    pbo[c] = (long long)rb * p.ldb + sg * 8;
    lbo[c] = rbase * 64;
  }

  f32x4 acc[4][NF];
#pragma unroll
  for (int i = 0; i < 4; ++i)
#pragma unroll
    for (int j = 0; j < NF; ++j) acc[i][j] = f32x4{0.f, 0.f, 0.f, 0.f};

#pragma unroll
  for (int c = 0; c < 4; ++c) gload16(Ab + pao[c], &Al[0][lao[c]]);
#pragma unroll
  for (int c = 0; c < NF; ++c) gload16(Bb + pbo[c], &Bl[0][lbo[c]]);
  __syncthreads();

  const int lr = lane & 15, lk = lane >> 4;
  int cur = 0;
  for (int k0 = 0; k0 < p.K; k0 += 64) {
    int nxt = cur ^ 1;
    if (k0 + 64 < p.K) {
#pragma unroll
      for (int c = 0; c < 4; ++c) gload16(Ab + pao[c] + k0 + 64, &Al[nxt][lao[c]]);
#pragma unroll
      for (int c = 0; c < NF; ++c) gload16(Bb + pbo[c] + k0 + 64, &Bl[nxt][lbo[c]]);
    }
#pragma unroll
    for (int kk = 0; kk < 2; ++kk) {
      s16x8 af[4], bfr[NF];
      int g = kk * 4 + lk;
#pragma unroll
      for (int i = 0; i < 4; ++i) {
        int ra = wm * 64 + i * 16 + lr;
        af[i] = *(const s16x8*)&Al[cur][ra * 64 + ((g ^ (ra & 7)) * 8)];
      }
#pragma unroll
      for (int j = 0; j < NF; ++j) {
        int rb = wn * (TN / 2) + j * 16 + lr;
        bfr[j] = *(const s16x8*)&Bl[cur][rb * 64 + ((g ^ (rb & 7)) * 8)];
      }
#pragma unroll
      for (int i = 0; i < 4; ++i)
#pragma unroll
        for (int j = 0; j < NF; ++j)
          acc[i][j] = __builtin_amdgcn_mfma_f32_16x16x32_bf16(af[i], bfr[j], acc[i][j], 0, 0, 0);
    }
    __syncthreads();
    cur = nxt;
  }

  long long cb;
  if (p.czmode == 1) { int b = z >> 4, h = z & 15; cb = (long long)b * 1048576 + h * 64; }
  else cb = (long long)z * p.sCz;
  const int lq = lane >> 4;
#pragma unroll
  for (int i = 0; i < 4; ++i) {
#pragma unroll
    for (int j = 0; j < NF; ++j) {
      int col = n0 + wn * (TN / 2) + j * 16 + lr;
      if (col >= p.N) continue;
#pragma unroll
      for (int q = 0; q < 4; ++q) {
        int row = m0 + wm * 64 + i * 16 + lq * 4 + q;
        float v = acc[i][j][q];
        if (EPI == 0) {          // plain bf16 store
          ((u16*)p.C)[cb + (long long)row * p.ldc + col] = f2bf(v);
        } else if (EPI == 1) {   // plain f32 store
          ((float*)p.C)[cb + (long long)row * p.ldc + col] = v;
        } else if (EPI == 2) {   // sigmoid(acc+gb) * (y_small + xn*Dp) -> bf16
          float gg = 1.f / (1.f + __expf(-(v + p.p0[col])));
          float yv = p.p1[row * 16 + (col >> 6)] +
                     p.p2[(long long)row * 1024 + col] * p.p3[col >> 6];
          ((u16*)p.C)[cb + (long long)row * p.ldc + col] = f2bf(gg * yv);
        } else if (EPI == 3) {   // +bias -> f32
          ((float*)p.C)[cb + (long long)row * p.ldc + col] = v + p.p0[col];
        } else if (EPI == 5) {   // scaled bf16 (attention scores)
          ((u16*)p.C)[cb + (long long)row * p.ldc + col] = f2bf(v * p.scale);
        } else if (EPI == 7) {   // fused qkv routing
          if (col < 1024) {
            p.aux0[(long long)row * 1024 + col] = f2bf(v);
          } else if (col < 1280) {
            p.aux1[(long long)row * 256 + (col - 1024)] = f2bf(v);
          } else {
            int cc = col - 1280;
            int b = row >> 10, l = row & 1023, kvh = cc >> 6, d = cc & 63;
            p.aux2[(((long long)(b * 4 + kvh) * 64 + d) << 10) + l] = f2bf(v);
          }
        }
      }
    }
  }
}

// ---- 256x128 tile, 8 waves, ring-3 LDS + counted vmcnt — MoE GEMMs ------
// EPI: 8 = fused swiglu (interleaved B rows), 0 = bf16 store, 4 = moe partial
// NOTE: natural blockIdx order (x-fastest). Chunked XCD swizzle measured
// HURTFUL here (R4: FETCH 63->139MB) — problem is L3-fit, swizzle broke the
// shared-B-stripe temporal locality of the concurrent block set.
template<int EPI>
__global__ __launch_bounds__(512) void gemm256_k(GemmP p) {
  __shared__ u16 Al[3][256 * 64];   // 96 KB
  __shared__ u16 Bl[3][128 * 64];   // 48 KB
  const int bx = blockIdx.x, by = blockIdx.y, bz = blockIdx.z;

  const int t = threadIdx.x;
  const int lane = t & 63, wid = t >> 6;      // 8 waves
  const int wm = wid >> 1, wn = wid & 1;      // 4 x 2
  const int m0 = by * 256, n0 = bx * 128;

  const u16* Ab = p.A + (long long)bz * p.sAz;
  const u16* Bb = p.B + (long long)bz * p.sBz;
  const int sr = lane >> 3;
  const int sg = (lane & 7) ^ sr;
  long long pao[4]; int lao[4];
  long long pbo[2]; int lbo[2];
#pragma unroll
  for (int c = 0; c < 4; ++c) {               // A: 256 rows = 8 waves x 4 x 8
    int rbase = c * 64 + wid * 8;
    pao[c] = (long long)(m0 + rbase + sr) * p.lda + sg * 8;
    lao[c] = rbase * 64;
  }
#pragma unroll
  for (int c = 0; c < 2; ++c) {               // B: 128 rows = 8 waves x 2 x 8
    int rbase = c * 64 + wid * 8;
    pbo[c] = (long long)(n0 + rbase + sr) * p.ldb + sg * 8;
    lbo[c] = rbase * 64;
  }

  f32x4 acc[4][4];
#pragma unroll
  for (int i = 0; i < 4; ++i)
#pragma unroll
    for (int j = 0; j < 4; ++j) acc[i][j] = f32x4{0.f, 0.f, 0.f, 0.f};

  const int NT = p.K >> 6;
  // prologue: stage batches 0 and 1
#pragma unroll
  for (int c = 0; c < 4; ++c) gload16(Ab + pao[c], &Al[0][lao[c]]);
#pragma unroll
  for (int c = 0; c < 2; ++c) gload16(Bb + pbo[c], &Bl[0][lbo[c]]);
  if (NT > 1) {
#pragma unroll
    for (int c = 0; c < 4; ++c) gload16(Ab + pao[c] + 64, &Al[1][lao[c]]);
#pragma unroll
    for (int c = 0; c < 2; ++c) gload16(Bb + pbo[c] + 64, &Bl[1][lbo[c]]);
  }
  asm volatile("s_waitcnt vmcnt(6)" ::: "memory");   // batch 0 landed
  __builtin_amdgcn_s_barrier();

  const int lr = lane & 15, lk = lane >> 4;
  int cur = 0, stg = 2;
  for (int ts = 0; ts < NT; ++ts) {
    if (ts + 2 < NT) {                 // stage batch ts+2, keep 6 in flight
      long long ko = (long long)(ts + 2) * 64;
#pragma unroll
      for (int c = 0; c < 4; ++c) gload16(Ab + pao[c] + ko, &Al[stg][lao[c]]);
#pragma unroll
      for (int c = 0; c < 2; ++c) gload16(Bb + pbo[c] + ko, &Bl[stg][lbo[c]]);
      asm volatile("s_waitcnt vmcnt(6)" ::: "memory");  // batch ts+1 landed
    } else {
      asm volatile("s_waitcnt vmcnt(0)" ::: "memory");  // tail drain
    }
#pragma unroll
    for (int kk = 0; kk < 2; ++kk) {
      s16x8 af[4], bfr[4];
      int g = kk * 4 + lk;
#pragma unroll
      for (int i = 0; i < 4; ++i) {
        int ra = wm * 64 + i * 16 + lr;
        af[i] = *(const s16x8*)&Al[cur][ra * 64 + ((g ^ (ra & 7)) * 8)];
        int rb = wn * 64 + i * 16 + lr;
        bfr[i] = *(const s16x8*)&Bl[cur][rb * 64 + ((g ^ (rb & 7)) * 8)];
      }
      __builtin_amdgcn_s_setprio(1);
#pragma unroll
      for (int i = 0; i < 4; ++i)
#pragma unroll
        for (int j = 0; j < 4; ++j)
          acc[i][j] = __builtin_amdgcn_mfma_f32_16x16x32_bf16(af[i], bfr[j], acc[i][j], 0, 0, 0);
      __builtin_amdgcn_s_setprio(0);
    }
    asm volatile("s_waitcnt lgkmcnt(0)" ::: "memory");
    __builtin_amdgcn_s_barrier();
    cur = (cur + 1 == 3) ? 0 : cur + 1;
    stg = (stg + 1 == 3) ? 0 : stg + 1;
  }

  long long cb = (long long)bz * p.sCz;
  const int lq = lane >> 4;
  if (EPI == 8) {                      // fused swiglu epilogue
#pragma unroll
    for (int i = 0; i < 4; ++i) {
#pragma unroll
      for (int u = 0; u < 2; ++u) {
        int pcol = (n0 >> 1) + wn * 32 + u * 16 + lr;
#pragma unroll
        for (int q = 0; q < 4; ++q) {
          int row = m0 + wm * 64 + i * 16 + lq * 4 + q;
          float a = acc[i][2 * u][q], gg = acc[i][2 * u + 1][q];
          ((u16*)p.C)[cb + (long long)row * p.ldc + pcol] =
              f2bf(a / (1.f + __expf(-a)) * gg);
        }
      }
    }
    return;
  }
#pragma unroll
  for (int i = 0; i < 4; ++i) {
#pragma unroll
    for (int j = 0; j < 4; ++j) {
      int col = n0 + wn * 64 + j * 16 + lr;
#pragma unroll
      for (int q = 0; q < 4; ++q) {
        int row = m0 + wm * 64 + i * 16 + lq * 4 + q;
        float v = acc[i][j][q];
        if (EPI == 0) {
          ((u16*)p.C)[cb + (long long)row * p.ldc + col] = f2bf(v);
        } else if (EPI == 4) {         // moe partial: wfull[:,z]*(acc+bias)
          float wv = p.p1[row * 4 + bz];
          ((float*)p.C)[cb + (long long)row * p.ldc + col] =
              wv * (v + p.p0[bz * 1024 + col]);
        }
      }
    }
  }
}

// --------------------------------------------------------- small kernels --
__global__ void rms1_k(const float* x, const float* goal, const float* w,
                       float* xn, u16* xnb) {
  int m = blockIdx.x, t = threadIdx.x;
  const float* xr = x + (long long)m * 1024;
  float v[4]; float ss = 0.f;
#pragma unroll
  for (int i = 0; i < 4; ++i) { v[i] = xr[t + i * 256]; ss += v[i] * v[i]; }
  ss = blockRed256<false>(ss);
  float r = rsqrtf(ss * (1.f / 1024.f) + 1e-6f);
#pragma unroll
  for (int i = 0; i < 4; ++i) {
    int c = t + i * 256;
    float o = v[i] * r * w[c] + goal[(long long)m * 1024 + c];
    xn[(long long)m * 1024 + c] = o;
    xnb[(long long)m * 1024 + c] = f2bf(o);
  }
}

__global__ void router_k(const float* xn, const float* rw, float* wout) {
  int m = blockIdx.x, t = threadIdx.x;
  const float* xr = xn + (long long)m * 1024;
  float a[4] = {0.f, 0.f, 0.f, 0.f};
  for (int i = t; i < 1024; i += 256) {
    float xv = xr[i];
    const float* r = rw + i * 4;
    a[0] += xv * r[0]; a[1] += xv * r[1]; a[2] += xv * r[2]; a[3] += xv * r[3];
  }
#pragma unroll
  for (int j = 0; j < 4; ++j) a[j] = blockRed256<false>(a[j]);
  if (t == 0) {
    float mx = fmaxf(fmaxf(a[0], a[1]), fmaxf(a[2], a[3]));
    float e[4]; float s = 0.f;
    for (int j = 0; j < 4; ++j) { e[j] = __expf(a[j] - mx); s += e[j]; }
    const float mix[4] = {0.5f, 0.2f, 0.15f, 0.15f};
    float ws = 0.f;
    for (int j = 0; j < 4; ++j) { e[j] = e[j] / s * mix[j]; ws += e[j]; }
    for (int j = 0; j < 4; ++j) wout[m * 4 + j] = e[j] / ws;
  }
}

DEV float softplus_f(float x) { return x > 15.f ? x : log1pf(__expf(x)); }

__global__ void scanA_k(const float* ssm, const float* A, float* aprod, float* sloc) {
  int blk = blockIdx.x, n = threadIdx.x;
  int c = blk & 63, h = (blk >> 6) & 15, b = blk >> 10;
  float Ah = A[h * 64 + n];
  float ap = 1.f, s = 0.f;
  int l0 = c * 16;
  for (int j = 0; j < 16; ++j) {
    long long off = (long long)(b * 1024 + l0 + j) * 144;
    float d = softplus_f(ssm[off + 128 + h] + ssm[off + n]);
    float a = __expf(d * Ah);
    s = a * s + d * d;
    ap *= a;
  }
  long long o = (long long)blk * 64 + n;
  aprod[o] = ap; sloc[o] = s;
}

__global__ void scanB_k(const float* aprod, const float* sloc, float* cin) {
  int bh = blockIdx.x, n = threadIdx.x;
  float carry = 0.f;
  for (int c = 0; c < 64; ++c) {
    long long o = (long long)(bh * 64 + c) * 64 + n;
    cin[o] = carry;
    carry = aprod[o] * carry + sloc[o];
  }
}

__global__ void scanC_k(const float* ssm, const float* A, const float* cin, float* ysm) {
  int blk = blockIdx.x, n = threadIdx.x;
  int c = blk & 63, h = (blk >> 6) & 15, b = blk >> 10;
  float Ah = A[h * 64 + n];
  float s = cin[(long long)blk * 64 + n];
  int l0 = c * 16;
  for (int j = 0; j < 16; ++j) {
    long long off = (long long)(b * 1024 + l0 + j) * 144;
    float d = softplus_f(ssm[off + 128 + h] + ssm[off + n]);
    float a = __expf(d * Ah);
    s = a * s + d * d;
    float yv = s * ssm[off + 64 + n];
    for (int o2 = 32; o2; o2 >>= 1) yv += __shfl_xor(yv, o2);
    if (n == 0) ysm[(long long)(b * 1024 + l0 + j) * 16 + h] = yv;
  }
}

__global__ void rope_k(const u16* qpre, const u16* kpre, const float* qnw,
                       const float* knw, u16* qro, u16* kro) {
  int rid = blockIdx.x * 4 + (threadIdx.x >> 6);
  int lane = threadIdx.x & 63;
  float v; const float* nw; int l; u16* dst;
  if (rid < 32768) {
    int b = rid >> 14, h = (rid >> 10) & 15; l = rid & 1023;
    v = bf2f(qpre[(long long)(b * 1024 + l) * 1024 + h * 64 + lane]);
    nw = qnw; dst = qro + (long long)rid * 64;
  } else {
    int r2 = rid - 32768;
    int b = r2 >> 12, kvh = (r2 >> 10) & 3; l = r2 & 1023;
    v = bf2f(kpre[(long long)(b * 1024 + l) * 256 + kvh * 64 + lane]);
    nw = knw; dst = kro + (long long)r2 * 64;
  }
  float ss = v * v;
  for (int o = 32; o; o >>= 1) ss += __shfl_xor(ss, o);
  float r = rsqrtf(ss * (1.f / 64.f) + 1e-6f);
  float vn = v * r * nw[lane];
  float pt = __shfl_xor(vn, 32);
  int i = lane & 31;
  float invf = powf(10000.f, -(float)i * (1.f / 32.f));
  float fr = (float)l * invf;
  float o2 = vn * cosf(fr) + ((lane < 32) ? -pt : pt) * sinf(fr);
  dst[lane] = f2bf(o2);
}

__global__ void softmax_k(u16* sc) {
  u16* r = sc + (long long)blockIdx.x * 1024;
  int t = threadIdx.x;
  float v[4]; float mx = -1e30f;
#pragma unroll
  for (int i = 0; i < 4; ++i) { v[i] = bf2f(r[t + i * 256]); mx = fmaxf(mx, v[i]); }
  mx = blockRed256<true>(mx);
  float s = 0.f;
#pragma unroll
  for (int i = 0; i < 4; ++i) { v[i] = __expf(v[i] - mx); s += v[i]; }
  s = blockRed256<false>(s);
  float inv = 1.f / s;
#pragma unroll
  for (int i = 0; i < 4; ++i) r[t + i * 256] = f2bf(v[i] * inv);
}

__global__ void conv_k(const float* xn, const float* dww, const float* dwb, u16* outb) {
  int m = blockIdx.x; int l = m & 1023;
#pragma unroll
  for (int i = 0; i < 4; ++i) {
    int d = threadIdx.x + i * 256;
    float xm = l > 0    ? xn[(long long)(m - 1) * 1024 + d] : 0.f;
    float x0 =            xn[(long long)m * 1024 + d];
    float xp = l < 1023 ? xn[(long long)(m + 1) * 1024 + d] : 0.f;
    float dv = xm * dww[d * 3] + x0 * dww[d * 3 + 1] + xp * dww[d * 3 + 2] + dwb[d];
    outb[(long long)m * 1024 + d] = f2bf(dv / (1.f + __expf(-dv)));
  }
}

__global__ void mix_k(const float* x, const float* w, const float* oss,
                      const float* oat, const float* ocv, const float* mem,
                      float* x2, u16* x2b) {
  int m = blockIdx.x;
  float w0 = w[m * 4], w1 = w[m * 4 + 1], w2 = w[m * 4 + 2], w3 = w[m * 4 + 3];
#pragma unroll
  for (int j = 0; j < 4; ++j) {
    long long i = (long long)m * 1024 + threadIdx.x + j * 256;
    float v = x[i] + w0 * oss[i] + w1 * oat[i] + w2 * ocv[i] + w3 * mem[i];
    x2[i] = v; x2b[i] = f2bf(v);
  }
}

__global__ void moegate_k(const float* x2, const float* n2w, const float* mg, float* wf) {
  int m = blockIdx.x, t = threadIdx.x;
  const float* xr = x2 + (long long)m * 1024;
  float ss = 0.f, a[4] = {0.f, 0.f, 0.f, 0.f};
  for (int i = t; i < 1024; i += 256) {
    float v = xr[i]; ss += v * v;
    float vw = v * n2w[i];
    const float* g = mg + i * 4;
    a[0] += vw * g[0]; a[1] += vw * g[1]; a[2] += vw * g[2]; a[3] += vw * g[3];
  }
  ss = blockRed256<false>(ss);
#pragma unroll
  for (int j = 0; j < 4; ++j) a[j] = blockRed256<false>(a[j]);
  if (t == 0) {
    float r = rsqrtf(ss * (1.f / 1024.f) + 1e-6f);
    float mx = -1e30f;
    for (int j = 0; j < 4; ++j) { a[j] *= r; mx = fmaxf(mx, a[j]); }
    float e[4]; float s = 0.f;
    for (int j = 0; j < 4; ++j) { e[j] = __expf(a[j] - mx); s += e[j]; }
    for (int j = 0; j < 4; ++j) e[j] /= s;
    int i0 = 0;
    for (int j = 1; j < 4; ++j) if (e[j] > e[i0]) i0 = j;
    int i1 = -1;
    for (int j = 0; j < 4; ++j) { if (j == i0) continue; if (i1 < 0 || e[j] > e[i1]) i1 = j; }
    for (int j = 0; j < 4; ++j) wf[m * 4 + j] = (j == i0 || j == i1) ? e[j] : 0.f;
  }
}

__global__ void final_k(const float* x2, const float* m0, const float* m1,
                        const float* m2, const float* m3, float* out) {
  long long i = ((long long)blockIdx.x * 256 + threadIdx.x) * 4;
  float4 a = *(const float4*)(x2 + i);
  float4 b0 = *(const float4*)(m0 + i);
  float4 b1 = *(const float4*)(m1 + i);
  float4 b2 = *(const float4*)(m2 + i);
  float4 b3 = *(const float4*)(m3 + i);
  float4 o{a.x + b0.x + b1.x + b2.x + b3.x, a.y + b0.y + b1.y + b2.y + b3.y,
           a.z + b0.z + b1.z + b2.z + b3.z, a.w + b0.w + b1.w + b2.w + b3.w};
  *(float4*)(out + i) = o;
}

// ------------------------------------------------------------------ host --
extern "C" void kernel_launch(void* const* d_in, const int* in_sizes, int n_in,
                              void* d_out, int out_size, void* d_ws, size_t ws_size,
                              hipStream_t stream) {
  const float* x    = (const float*)d_in[0];
  const float* goal = (const float*)d_in[1];
  const float* mem  = (const float*)d_in[2];
  const float* n1w  = (const float*)d_in[3];
  const float* n2w  = (const float*)d_in[4];
  const float* rw   = (const float*)d_in[5];
  const float* xpw  = (const float*)d_in[6];
  const float* Amat = (const float*)d_in[7];
  const float* Dp   = (const float*)d_in[8];
  const float* gw   = (const float*)d_in[9];
  const float* gb   = (const float*)d_in[10];
  const float* sow  = (const float*)d_in[11];
  const float* qw   = (const float*)d_in[12];
  const float* kw   = (const float*)d_in[13];
  const float* vw   = (const float*)d_in[14];
  const float* ow   = (const float*)d_in[15];
  const float* qnw  = (const float*)d_in[16];
  const float* knw  = (const float*)d_in[17];
  const float* dww  = (const float*)d_in[18];
  const float* dwb  = (const float*)d_in[19];
  const float* pww  = (const float*)d_in[20];
  const float* pwb  = (const float*)d_in[21];
  const float* mgw  = (const float*)d_in[22];
  const float* ew1  = (const float*)d_in[23];
  const float* ew2  = (const float*)d_in[24];
  const float* elw  = (const float*)d_in[25];
  const float* elb  = (const float*)d_in[26];
  float* out = (float*)d_out;

  char* base = (char*)d_ws; size_t off = 0;
  auto alloc = [&](size_t b) { void* p = base + off; off += (b + 255) & ~(size_t)255; return p; };
  // ---- R0: front temporaries (all dead before MoE) — aliased by moe4 ----
  float* xn    = (float*)alloc(2048ull * 1024 * 4);
  u16*   xnb   = (u16*)  alloc(2048ull * 1024 * 2);
  float* wr    = (float*)alloc(2048ull * 4 * 4);
  float* ssm   = (float*)alloc(2048ull * 144 * 4);
  float* aprod = (float*)alloc(2048ull * 64 * 4);
  float* sloc  = (float*)alloc(2048ull * 64 * 4);
  float* cin   = (float*)alloc(2048ull * 64 * 4);
  float* ysm   = (float*)alloc(2048ull * 16 * 4);
  u16*   ssdin = (u16*)  alloc(2048ull * 1024 * 2);
  u16*   qpre  = (u16*)  alloc(2048ull * 1024 * 2);
  u16*   kpre  = (u16*)  alloc(2048ull * 256 * 2);
  u16*   vT    = (u16*)  alloc(2048ull * 256 * 2);
  u16*   qro   = (u16*)  alloc(2048ull * 1024 * 2);
  u16*   kro   = (u16*)  alloc(2048ull * 256 * 2);
  u16*   acat  = (u16*)  alloc(2048ull * 1024 * 2);
  u16*   cva   = (u16*)  alloc(2048ull * 1024 * 2);
  float* moe4  = (float*)base;                     // 32MB alias over R0 (~38MB)
  // ---- persistent past mix ----
  float* x2    = (float*)alloc(2048ull * 1024 * 4);
  u16*   x2b   = (u16*)  alloc(2048ull * 1024 * 2);
  float* wfull = (float*)alloc(2048ull * 4 * 4);
  u16* xpwt = (u16*)alloc(256ull  * 1024 * 2);
  u16* gwt  = (u16*)alloc(1024ull * 1024 * 2);
  u16* sowt = (u16*)alloc(1024ull * 1024 * 2);
  u16* qkvt = (u16*)alloc(1536ull * 1024 * 2);
  u16* owt  = (u16*)alloc(1024ull * 1024 * 2);
  u16* pwwt = (u16*)alloc(1024ull * 1024 * 2);
  // U1 24MB: front = outss|outat|outcv ; MoE = t2_4 (16MB)
  char*  U1    = (char*) alloc(25165824ull);
  float* outss = (float*)U1;
  float* outat = (float*)(U1 + 8388608);
  float* outcv = (float*)(U1 + 16777216);
  u16*   t2_4  = (u16*)  U1;
  // BIG 64MB: scores (attn) ∪ act4 (MoE, 4 x 2048x4096 bf16)
  char* BIG = (char*)alloc(67108864ull);
  u16* scores = (u16*)BIG;
  u16* act4   = (u16*)BIG;
  // EW 32MB: ew1t pair ∪ ew2t4 ∪ ewlt4 (sequential reuse)
  char* EW = (char*)alloc(33554432ull);
  u16* ew1t  = (u16*)EW;
  u16* ew2t4 = (u16*)EW;
  u16* ewlt4 = (u16*)EW;

  // ---- front weight transposes
  wtrans_k<<<dim3(3, 16), 256, 0, stream>>>(xpw, xpwt, 1024, 144, 0);
  wtrans_k<<<dim3(16, 16), 256, 0, stream>>>(gw, gwt, 1024, 1024, 0);
  wtrans_k<<<dim3(16, 16), 256, 0, stream>>>(sow, sowt, 1024, 1024, 0);
  wtrans_k<<<dim3(16, 16), 256, 0, stream>>>(qw, qkvt, 1024, 1024, 0);
  wtrans_k<<<dim3(4, 16), 256, 0, stream>>>(kw, qkvt + 1024ull * 1024, 1024, 256, 0);
  wtrans_k<<<dim3(4, 16), 256, 0, stream>>>(vw, qkvt + 1280ull * 1024, 1024, 256, 0);
  wtrans_k<<<dim3(16, 16), 256, 0, stream>>>(ow, owt, 1024, 1024, 0);
  wtrans_k<<<dim3(16, 16), 256, 0, stream>>>(pww, pwwt, 1024, 1024, 0);

  rms1_k<<<2048, 256, 0, stream>>>(x, goal, n1w, xn, xnb);
  router_k<<<2048, 256, 0, stream>>>(xn, rw, wr);

  { GemmP p{}; p.A = xnb; p.lda = 1024; p.B = xpwt; p.ldb = 1024; p.C = ssm; p.ldc = 144;
    p.M = 2048; p.N = 144; p.K = 1024;
    gemm_k<1, 64><<<dim3(3, 16, 1), 256, 0, stream>>>(p); }

  scanA_k<<<2048, 64, 0, stream>>>(ssm, Amat, aprod, sloc);
  scanB_k<<<32, 64, 0, stream>>>(aprod, sloc, cin);
  scanC_k<<<2048, 64, 0, stream>>>(ssm, Amat, cin, ysm);

  { GemmP p{}; p.A = xnb; p.lda = 1024; p.B = gwt; p.ldb = 1024; p.C = ssdin; p.ldc = 1024;
    p.M = 2048; p.N = 1024; p.K = 1024; p.p0 = gb; p.p1 = ysm; p.p2 = xn; p.p3 = Dp;
    gemm_k<2, 64><<<dim3(16, 16, 1), 256, 0, stream>>>(p); }
  { GemmP p{}; p.A = ssdin; p.lda = 1024; p.B = sowt; p.ldb = 1024; p.C = outss; p.ldc = 1024;
    p.M = 2048; p.N = 1024; p.K = 1024;
    gemm_k<1, 64><<<dim3(16, 16, 1), 256, 0, stream>>>(p); }

  { GemmP p{}; p.A = xnb; p.lda = 1024; p.B = qkvt; p.ldb = 1024; p.C = nullptr; p.ldc = 0;
    p.M = 2048; p.N = 1536; p.K = 1024; p.aux0 = qpre; p.aux1 = kpre; p.aux2 = vT;
    gemm_k<7, 64><<<dim3(24, 16, 1), 256, 0, stream>>>(p); }

  rope_k<<<10240, 256, 0, stream>>>(qpre, kpre, qnw, knw, qro, kro);

  { GemmP p{}; p.A = qro; p.lda = 64; p.sAz = 65536; p.B = kro; p.ldb = 64; p.sBz = 65536;
    p.gqa = 1; p.C = scores; p.ldc = 1024; p.sCz = 1048576;
    p.M = 1024; p.N = 1024; p.K = 64; p.scale = 0.125f;
    gemm_k<5, 128><<<dim3(8, 8, 32), 256, 0, stream>>>(p); }
  softmax_k<<<32768, 256, 0, stream>>>(scores);
  { GemmP p{}; p.A = scores; p.lda = 1024; p.sAz = 1048576; p.B = vT; p.ldb = 1024; p.sBz = 65536;
    p.gqa = 1; p.C = acat; p.ldc = 1024; p.czmode = 1;
    p.M = 1024; p.N = 64; p.K = 1024;
    gemm_k<0, 64><<<dim3(1, 8, 32), 256, 0, stream>>>(p); }
  { GemmP p{}; p.A = acat; p.lda = 1024; p.B = owt; p.ldb = 1024; p.C = outat; p.ldc = 1024;
    p.M = 2048; p.N = 1024; p.K = 1024;
    gemm_k<1, 64><<<dim3(16, 16, 1), 256, 0, stream>>>(p); }

  conv_k<<<2048, 256, 0, stream>>>(xn, dww, dwb, cva);
  { GemmP p{}; p.A = cva; p.lda = 1024; p.B = pwwt; p.ldb = 1024; p.C = outcv; p.ldc = 1024;
    p.M = 2048; p.N = 1024; p.K = 1024; p.p0 = pwb;
    gemm_k<3, 64><<<dim3(16, 16, 1), 256, 0, stream>>>(p); }

  mix_k<<<2048, 256, 0, stream>>>(x, wr, outss, outat, outcv, mem, x2, x2b);
  moegate_k<<<2048, 256, 0, stream>>>(x2, n2w, mgw, wfull);

  // ---- MoE: e_w1 (fused swiglu) per pair, then e_w2 / e_lin over z=4 ----
  for (int pr = 0; pr < 2; ++pr) {
    int e0 = pr * 2;
    wtrans_k<<<dim3(128, 16), 256, 0, stream>>>(ew1 + (long long)e0 * 8388608, ew1t, 1024, 8192, 1);
    wtrans_k<<<dim3(128, 16), 256, 0, stream>>>(ew1 + (long long)(e0 + 1) * 8388608, ew1t + 8388608ull, 1024, 8192, 1);
    GemmP p{}; p.A = x2b; p.lda = 1024; p.sAz = 0; p.B = ew1t; p.ldb = 1024; p.sBz = 8192ll * 1024;
    p.C = act4 + (long long)e0 * (2048ll * 4096); p.ldc = 4096; p.sCz = 2048ll * 4096;
    p.M = 2048; p.N = 8192; p.K = 1024;
    gemm256_k<8><<<dim3(64, 8, 2), 512, 0, stream>>>(p);
  }
  for (int e = 0; e < 4; ++e)
    wtrans_k<<<dim3(16, 64), 256, 0, stream>>>(ew2 + (long long)e * 4194304,
                                               ew2t4 + (long long)e * (1024ll * 4096), 4096, 1024, 0);
  { GemmP p{}; p.A = act4; p.lda = 4096; p.sAz = 2048ll * 4096; p.B = ew2t4; p.ldb = 4096;
    p.sBz = 1024ll * 4096; p.C = t2_4; p.ldc = 1024; p.sCz = 2048ll * 1024;
    p.M = 2048; p.N = 1024; p.K = 4096;
    gemm256_k<0><<<dim3(8, 8, 4), 512, 0, stream>>>(p); }
  for (int e = 0; e < 4; ++e)
    wtrans_k<<<dim3(16, 16), 256, 0, stream>>>(elw + (long long)e * 1048576,
                                               ewlt4 + (long long)e * (1024ll * 1024), 1024, 1024, 0);
  { GemmP p{}; p.A = t2_4; p.lda = 1024; p.sAz = 2048ll * 1024; p.B = ewlt4; p.ldb = 1024;
    p.sBz = 1024ll * 1024; p.C = moe4; p.ldc = 1024; p.sCz = 2048ll * 1024;
    p.M = 2048; p.N = 1024; p.K = 1024; p.p0 = elb; p.p1 = wfull; p.eidx = 0;
    gemm256_k<4><<<dim3(8, 8, 4), 512, 0, stream>>>(p); }

  final_k<<<2048, 256, 0, stream>>>(x2, moe4, moe4 + 2097152, moe4 + 2ull * 2097152,
                                    moe4 + 3ull * 2097152, out);
}

// Round 6
// 750.553 us; speedup vs baseline: 2.8012x; 1.0161x over previous
//
#include <hip/hip_runtime.h>
#include <hip/hip_bf16.h>
#include <cstdint>

typedef unsigned short u16;
typedef __attribute__((ext_vector_type(4))) float f32x4;
typedef __attribute__((ext_vector_type(8))) short s16x8;

#define DEV __device__ __forceinline__

DEV u16 f2bf(float x) {                       // RNE f32 -> bf16
  unsigned u = __float_as_uint(x);
  u += 0x7FFFu + ((u >> 16) & 1u);
  return (u16)(u >> 16);
}
DEV float bf2f(u16 b) { return __uint_as_float(((unsigned)b) << 16); }

DEV void gload16(const void* g, void* l) {    // async global->LDS, 16B/lane
  __builtin_amdgcn_global_load_lds(
      (const __attribute__((address_space(1))) void*)g,
      (__attribute__((address_space(3))) void*)l, 16, 0, 0);
}

template<bool MAXOP>
DEV float blockRed256(float v) {
  for (int o = 32; o; o >>= 1) {
    float t = __shfl_xor(v, o);
    v = MAXOP ? fmaxf(v, t) : v + t;
  }
  __shared__ float s[4];
  __syncthreads();
  if ((threadIdx.x & 63) == 0) s[threadIdx.x >> 6] = v;
  __syncthreads();
  return MAXOP ? fmaxf(fmaxf(s[0], s[1]), fmaxf(s[2], s[3]))
               : (s[0] + s[1] + s[2] + s[3]);
}

// ------------------------------------------------- weight transpose ------
// f32 (K,N) row-major -> bf16 (N,K) row-major. ilv=1: swiglu row interleave.
__global__ __launch_bounds__(256) void wtrans_k(const float* __restrict__ in,
                                                u16* __restrict__ out,
                                                int K, int N, int ilv) {
  __shared__ float t[64][68];
  const int n0 = blockIdx.x * 64, k0 = blockIdx.y * 64;
  const int tt = threadIdx.x;
  const int kl = tt >> 4, nl = (tt & 15) * 4;
#pragma unroll
  for (int i = 0; i < 4; ++i) {
    int k = kl + i * 16;
    float4 v{0.f, 0.f, 0.f, 0.f};
    if (n0 + nl + 3 < N) {
      v = *(const float4*)(in + (long long)(k0 + k) * N + n0 + nl);
    } else {
      for (int j = 0; j < 4; ++j)
        if (n0 + nl + j < N) ((float*)&v)[j] = in[(long long)(k0 + k) * N + n0 + nl + j];
    }
    t[nl + 0][k] = v.x; t[nl + 1][k] = v.y; t[nl + 2][k] = v.z; t[nl + 3][k] = v.w;
  }
  __syncthreads();
  const int n = tt >> 2, kq = (tt & 3) * 16;
  if (n0 + n < N) {
    s16x8 o0, o1;
#pragma unroll
    for (int j = 0; j < 8; ++j) { o0[j] = (short)f2bf(t[n][kq + j]); o1[j] = (short)f2bf(t[n][kq + 8 + j]); }
    int c = n0 + n;
    int r = ilv ? ((((c & 4095) >> 4) << 5) + ((c >> 12) << 4) + (c & 15)) : c;
    u16* op = out + (long long)r * K + k0 + kq;
    *(s16x8*)op = o0; *(s16x8*)(op + 8) = o1;
  }
}

// ---------------------------------------------------------------- GEMM ----
struct GemmP {
  const u16* A; int lda; long long sAz;
  const u16* B; int ldb; long long sBz;
  void* C; int ldc; long long sCz;
  int M, N, K;
  int gqa;      // 1: B batch index = (z>>4)*4 + ((z&15)>>2)   (GQA 16q/4kv)
  int czmode;   // 1: C base = b*1048576 + h*64  (attn concat store)
  const float *p0, *p1, *p2, *p3;
  float scale; int eidx;
  u16 *aux0, *aux1, *aux2;   // EPI7: qpre, kpre, vT
};

// ---- 128xTN tile, 4 waves, double-buffered (proven) — front/attn GEMMs --
template<int EPI, int TN>
__global__ __launch_bounds__(256) void gemm_k(GemmP p) {
  constexpr int NF = TN / 32;                 // B fragments per wave
  __shared__ u16 Al[2][128 * 64];
  __shared__ u16 Bl[2][TN * 64];
  const int z = blockIdx.z;
  const int t = threadIdx.x;
  const int lane = t & 63, wid = t >> 6;
  const int wm = wid >> 1, wn = wid & 1;
  const int m0 = blockIdx.y * 128, n0 = blockIdx.x * TN;

  const u16* Ab = p.A + (long long)z * p.sAz;
  const u16* Bb = p.B + (p.gqa ? (long long)(((z >> 4) << 2) + ((z & 15) >> 2)) * p.sBz
                               : (long long)z * p.sBz);
  const int sr = lane >> 3;                 // sub-row 0..7
  const int sg = (lane & 7) ^ sr;           // pre-swizzled k-group
  long long pao[4]; int lao[4];
  long long pbo[NF]; int lbo[NF];
#pragma unroll
  for (int c = 0; c < 4; ++c) {
    int rbase = c * 32 + wid * 8;
    int ra = m0 + rbase + sr; if (ra > p.M - 1) ra = p.M - 1;
    pao[c] = (long long)ra * p.lda + sg * 8;
    lao[c] = rbase * 64;
  }
#pragma unroll
  for (int c = 0; c < NF; ++c) {
    int rbase = c * 32 + wid * 8;
    int rb = n0 + rbase + sr; if (rb > p.N - 1) rb = p.N - 1;
    pbo[c] = (long long)rb * p.ldb + sg * 8;
    lbo[c] = rbase * 64;
  }

  f32x4 acc[4][NF];
#pragma unroll
  for (int i = 0; i < 4; ++i)
#pragma unroll
    for (int j = 0; j < NF; ++j) acc[i][j] = f32x4{0.f, 0.f, 0.f, 0.f};

#pragma unroll
  for (int c = 0; c < 4; ++c) gload16(Ab + pao[c], &Al[0][lao[c]]);
#pragma unroll
  for (int c = 0; c < NF; ++c) gload16(Bb + pbo[c], &Bl[0][lbo[c]]);
  __syncthreads();

  const int lr = lane & 15, lk = lane >> 4;
  int cur = 0;
  for (int k0 = 0; k0 < p.K; k0 += 64) {
    int nxt = cur ^ 1;
    if (k0 + 64 < p.K) {
#pragma unroll
      for (int c = 0; c < 4; ++c) gload16(Ab + pao[c] + k0 + 64, &Al[nxt][lao[c]]);
#pragma unroll
      for (int c = 0; c < NF; ++c) gload16(Bb + pbo[c] + k0 + 64, &Bl[nxt][lbo[c]]);
    }
#pragma unroll
    for (int kk = 0; kk < 2; ++kk) {
      s16x8 af[4], bfr[NF];
      int g = kk * 4 + lk;
#pragma unroll
      for (int i = 0; i < 4; ++i) {
        int ra = wm * 64 + i * 16 + lr;
        af[i] = *(const s16x8*)&Al[cur][ra * 64 + ((g ^ (ra & 7)) * 8)];
      }
#pragma unroll
      for (int j = 0; j < NF; ++j) {
        int rb = wn * (TN / 2) + j * 16 + lr;
        bfr[j] = *(const s16x8*)&Bl[cur][rb * 64 + ((g ^ (rb & 7)) * 8)];
      }
#pragma unroll
      for (int i = 0; i < 4; ++i)
#pragma unroll
        for (int j = 0; j < NF; ++j)
          acc[i][j] = __builtin_amdgcn_mfma_f32_16x16x32_bf16(af[i], bfr[j], acc[i][j], 0, 0, 0);
    }
    __syncthreads();
    cur = nxt;
  }

  long long cb;
  if (p.czmode == 1) { int b = z >> 4, h = z & 15; cb = (long long)b * 1048576 + h * 64; }
  else cb = (long long)z * p.sCz;
  const int lq = lane >> 4;
#pragma unroll
  for (int i = 0; i < 4; ++i) {
#pragma unroll
    for (int j = 0; j < NF; ++j) {
      int col = n0 + wn * (TN / 2) + j * 16 + lr;
      if (col >= p.N) continue;
#pragma unroll
      for (int q = 0; q < 4; ++q) {
        int row = m0 + wm * 64 + i * 16 + lq * 4 + q;
        float v = acc[i][j][q];
        if (EPI == 0) {          // plain bf16 store
          ((u16*)p.C)[cb + (long long)row * p.ldc + col] = f2bf(v);
        } else if (EPI == 1) {   // plain f32 store
          ((float*)p.C)[cb + (long long)row * p.ldc + col] = v;
        } else if (EPI == 2) {   // sigmoid(acc+gb) * (y_small + xn*Dp) -> bf16
          float gg = 1.f / (1.f + __expf(-(v + p.p0[col])));
          float yv = p.p1[row * 16 + (col >> 6)] +
                     p.p2[(long long)row * 1024 + col] * p.p3[col >> 6];
          ((u16*)p.C)[cb + (long long)row * p.ldc + col] = f2bf(gg * yv);
        } else if (EPI == 3) {   // +bias -> f32
          ((float*)p.C)[cb + (long long)row * p.ldc + col] = v + p.p0[col];
        } else if (EPI == 5) {   // scaled bf16 (attention scores)
          ((u16*)p.C)[cb + (long long)row * p.ldc + col] = f2bf(v * p.scale);
        } else if (EPI == 7) {   // fused qkv routing
          if (col < 1024) {
            p.aux0[(long long)row * 1024 + col] = f2bf(v);
          } else if (col < 1280) {
            p.aux1[(long long)row * 256 + (col - 1024)] = f2bf(v);
          } else {
            int cc = col - 1280;
            int b = row >> 10, l = row & 1023, kvh = cc >> 6, d = cc & 63;
            p.aux2[(((long long)(b * 4 + kvh) * 64 + d) << 10) + l] = f2bf(v);
          }
        }
      }
    }
  }
}

// ---- 256x128 tile, 8 waves, ring-3 LDS + counted vmcnt — e_w2/e_lin ----
template<int EPI>
__global__ __launch_bounds__(512) void gemm256_k(GemmP p) {
  __shared__ u16 Al[3][256 * 64];   // 96 KB
  __shared__ u16 Bl[3][128 * 64];   // 48 KB
  const int bx = blockIdx.x, by = blockIdx.y, bz = blockIdx.z;

  const int t = threadIdx.x;
  const int lane = t & 63, wid = t >> 6;      // 8 waves
  const int wm = wid >> 1, wn = wid & 1;      // 4 x 2
  const int m0 = by * 256, n0 = bx * 128;

  const u16* Ab = p.A + (long long)bz * p.sAz;
  const u16* Bb = p.B + (long long)bz * p.sBz;
  const int sr = lane >> 3;
  const int sg = (lane & 7) ^ sr;
  long long pao[4]; int lao[4];
  long long pbo[2]; int lbo[2];
#pragma unroll
  for (int c = 0; c < 4; ++c) {               // A: 256 rows = 8 waves x 4 x 8
    int rbase = c * 64 + wid * 8;
    pao[c] = (long long)(m0 + rbase + sr) * p.lda + sg * 8;
    lao[c] = rbase * 64;
  }
#pragma unroll
  for (int c = 0; c < 2; ++c) {               // B: 128 rows = 8 waves x 2 x 8
    int rbase = c * 64 + wid * 8;
    pbo[c] = (long long)(n0 + rbase + sr) * p.ldb + sg * 8;
    lbo[c] = rbase * 64;
  }

  f32x4 acc[4][4];
#pragma unroll
  for (int i = 0; i < 4; ++i)
#pragma unroll
    for (int j = 0; j < 4; ++j) acc[i][j] = f32x4{0.f, 0.f, 0.f, 0.f};

  const int NT = p.K >> 6;
  // prologue: stage batches 0 and 1
#pragma unroll
  for (int c = 0; c < 4; ++c) gload16(Ab + pao[c], &Al[0][lao[c]]);
#pragma unroll
  for (int c = 0; c < 2; ++c) gload16(Bb + pbo[c], &Bl[0][lbo[c]]);
  if (NT > 1) {
#pragma unroll
    for (int c = 0; c < 4; ++c) gload16(Ab + pao[c] + 64, &Al[1][lao[c]]);
#pragma unroll
    for (int c = 0; c < 2; ++c) gload16(Bb + pbo[c] + 64, &Bl[1][lbo[c]]);
  }
  asm volatile("s_waitcnt vmcnt(6)" ::: "memory");   // batch 0 landed
  __builtin_amdgcn_s_barrier();

  const int lr = lane & 15, lk = lane >> 4;
  int cur = 0, stg = 2;
  for (int ts = 0; ts < NT; ++ts) {
    if (ts + 2 < NT) {                 // stage batch ts+2, keep 6 in flight
      long long ko = (long long)(ts + 2) * 64;
#pragma unroll
      for (int c = 0; c < 4; ++c) gload16(Ab + pao[c] + ko, &Al[stg][lao[c]]);
#pragma unroll
      for (int c = 0; c < 2; ++c) gload16(Bb + pbo[c] + ko, &Bl[stg][lbo[c]]);
      asm volatile("s_waitcnt vmcnt(6)" ::: "memory");  // batch ts+1 landed
    } else {
      asm volatile("s_waitcnt vmcnt(0)" ::: "memory");  // tail drain
    }
#pragma unroll
    for (int kk = 0; kk < 2; ++kk) {
      s16x8 af[4], bfr[4];
      int g = kk * 4 + lk;
#pragma unroll
      for (int i = 0; i < 4; ++i) {
        int ra = wm * 64 + i * 16 + lr;
        af[i] = *(const s16x8*)&Al[cur][ra * 64 + ((g ^ (ra & 7)) * 8)];
        int rb = wn * 64 + i * 16 + lr;
        bfr[i] = *(const s16x8*)&Bl[cur][rb * 64 + ((g ^ (rb & 7)) * 8)];
      }
      __builtin_amdgcn_s_setprio(1);
#pragma unroll
      for (int i = 0; i < 4; ++i)
#pragma unroll
        for (int j = 0; j < 4; ++j)
          acc[i][j] = __builtin_amdgcn_mfma_f32_16x16x32_bf16(af[i], bfr[j], acc[i][j], 0, 0, 0);
      __builtin_amdgcn_s_setprio(0);
    }
    asm volatile("s_waitcnt lgkmcnt(0)" ::: "memory");
    __builtin_amdgcn_s_barrier();
    cur = (cur + 1 == 3) ? 0 : cur + 1;
    stg = (stg + 1 == 3) ? 0 : stg + 1;
  }

  long long cb = (long long)bz * p.sCz;
  const int lq = lane >> 4;
#pragma unroll
  for (int i = 0; i < 4; ++i) {
#pragma unroll
    for (int j = 0; j < 4; ++j) {
      int col = n0 + wn * 64 + j * 16 + lr;
#pragma unroll
      for (int q = 0; q < 4; ++q) {
        int row = m0 + wm * 64 + i * 16 + lq * 4 + q;
        float v = acc[i][j][q];
        if (EPI == 0) {
          ((u16*)p.C)[cb + (long long)row * p.ldc + col] = f2bf(v);
        } else if (EPI == 4) {         // moe partial: wfull[:,z]*(acc+bias)
          float wv = p.p1[row * 4 + bz];
          ((float*)p.C)[cb + (long long)row * p.ldc + col] =
              wv * (v + p.p0[bz * 1024 + col]);
        }
      }
    }
  }
}

// ---- 256x256 tile, 8 waves (2Mx4N), per-wave 128x64 (acc[8][4]) ---------
// 2-deep double buffer (128 KB LDS) + counted vmcnt, raw s_barrier.
// LDS-BW fix: 24 ds_read_b128 per 64 MFMA per wave (vs 16/32 at 4x4 frags).
template<int EPI>
__global__ __launch_bounds__(512) void gemm256sq_k(GemmP p) {
  __shared__ u16 Al[2][256 * 64];   // 64 KB
  __shared__ u16 Bl[2][256 * 64];   // 64 KB
  const int bx = blockIdx.x, by = blockIdx.y, bz = blockIdx.z;
  const int t = threadIdx.x;
  const int lane = t & 63, wid = t >> 6;      // 8 waves
  const int wm = wid >> 2, wn = wid & 3;      // 2 x 4
  const int m0 = by * 256, n0 = bx * 256;

  const u16* Ab = p.A + (long long)bz * p.sAz;
  const u16* Bb = p.B + (long long)bz * p.sBz;
  const int sr = lane >> 3;
  const int sg = (lane & 7) ^ sr;
  long long pao[4], pbo[4]; int lofs[4];
#pragma unroll
  for (int c = 0; c < 4; ++c) {               // 256 rows = 4 calls x 8w x 8r
    int rbase = c * 64 + wid * 8;
    pao[c] = (long long)(m0 + rbase + sr) * p.lda + sg * 8;
    pbo[c] = (long long)(n0 + rbase + sr) * p.ldb + sg * 8;
    lofs[c] = rbase * 64;
  }

  f32x4 acc[8][4];
#pragma unroll
  for (int i = 0; i < 8; ++i)
#pragma unroll
    for (int j = 0; j < 4; ++j) acc[i][j] = f32x4{0.f, 0.f, 0.f, 0.f};

  const int NT = p.K >> 6;
  // prologue: tiles 0 and 1 in flight (16 loads/thread)
#pragma unroll
  for (int c = 0; c < 4; ++c) gload16(Ab + pao[c], &Al[0][lofs[c]]);
#pragma unroll
  for (int c = 0; c < 4; ++c) gload16(Bb + pbo[c], &Bl[0][lofs[c]]);
#pragma unroll
  for (int c = 0; c < 4; ++c) gload16(Ab + pao[c] + 64, &Al[1][lofs[c]]);
#pragma unroll
  for (int c = 0; c < 4; ++c) gload16(Bb + pbo[c] + 64, &Bl[1][lofs[c]]);
  asm volatile("s_waitcnt vmcnt(8)" ::: "memory");   // tile 0 landed
  __builtin_amdgcn_s_barrier();

  const int lr = lane & 15, lk = lane >> 4;
  for (int ts = 0; ts < NT; ++ts) {
    const int cur = ts & 1;
#pragma unroll
    for (int kk = 0; kk < 2; ++kk) {
      s16x8 af[8], bfr[4];
      int g = kk * 4 + lk;
#pragma unroll
      for (int i = 0; i < 8; ++i) {
        int ra = wm * 128 + i * 16 + lr;
        af[i] = *(const s16x8*)&Al[cur][ra * 64 + ((g ^ (ra & 7)) * 8)];
      }
#pragma unroll
      for (int j = 0; j < 4; ++j) {
        int rb = wn * 64 + j * 16 + lr;
        bfr[j] = *(const s16x8*)&Bl[cur][rb * 64 + ((g ^ (rb & 7)) * 8)];
      }
      __builtin_amdgcn_s_setprio(1);
#pragma unroll
      for (int i = 0; i < 8; ++i)
#pragma unroll
        for (int j = 0; j < 4; ++j)
          acc[i][j] = __builtin_amdgcn_mfma_f32_16x16x32_bf16(af[i], bfr[j], acc[i][j], 0, 0, 0);
      __builtin_amdgcn_s_setprio(0);
    }
    asm volatile("s_waitcnt lgkmcnt(0)" ::: "memory");
    __builtin_amdgcn_s_barrier();                    // all reads of buf[cur] done
    if (ts + 2 < NT) {
      long long ko = (long long)(ts + 2) * 64;       // overwrite freed buffer
#pragma unroll
      for (int c = 0; c < 4; ++c) gload16(Ab + pao[c] + ko, &Al[cur][lofs[c]]);
#pragma unroll
      for (int c = 0; c < 4; ++c) gload16(Bb + pbo[c] + ko, &Bl[cur][lofs[c]]);
      asm volatile("s_waitcnt vmcnt(8)" ::: "memory"); // tile ts+1 landed
    } else {
      asm volatile("s_waitcnt vmcnt(0)" ::: "memory"); // tail drain
    }
    __builtin_amdgcn_s_barrier();                    // all waves see ts+1
  }

  long long cb = (long long)bz * p.sCz;
  const int lq = lane >> 4;
  if (EPI == 8) {                      // fused swiglu (interleaved B rows)
#pragma unroll
    for (int i = 0; i < 8; ++i) {
#pragma unroll
      for (int u = 0; u < 2; ++u) {
        int pcol = (n0 >> 1) + wn * 32 + u * 16 + lr;
#pragma unroll
        for (int q = 0; q < 4; ++q) {
          int row = m0 + wm * 128 + i * 16 + lq * 4 + q;
          float a = acc[i][2 * u][q], gg = acc[i][2 * u + 1][q];
          ((u16*)p.C)[cb + (long long)row * p.ldc + pcol] =
              f2bf(a / (1.f + __expf(-a)) * gg);
        }
      }
    }
    return;
  }
#pragma unroll
  for (int i = 0; i < 8; ++i) {
#pragma unroll
    for (int j = 0; j < 4; ++j) {
      int col = n0 + wn * 64 + j * 16 + lr;
#pragma unroll
      for (int q = 0; q < 4; ++q) {
        int row = m0 + wm * 128 + i * 16 + lq * 4 + q;
        ((u16*)p.C)[cb + (long long)row * p.ldc + col] = f2bf(acc[i][j][q]);
      }
    }
  }
}

// --------------------------------------------------------- small kernels --
__global__ void rms1_k(const float* x, const float* goal, const float* w,
                       float* xn, u16* xnb) {
  int m = blockIdx.x, t = threadIdx.x;
  const float* xr = x + (long long)m * 1024;
  float v[4]; float ss = 0.f;
#pragma unroll
  for (int i = 0; i < 4; ++i) { v[i] = xr[t + i * 256]; ss += v[i] * v[i]; }
  ss = blockRed256<false>(ss);
  float r = rsqrtf(ss * (1.f / 1024.f) + 1e-6f);
#pragma unroll
  for (int i = 0; i < 4; ++i) {
    int c = t + i * 256;
    float o = v[i] * r * w[c] + goal[(long long)m * 1024 + c];
    xn[(long long)m * 1024 + c] = o;
    xnb[(long long)m * 1024 + c] = f2bf(o);
  }
}

__global__ void router_k(const float* xn, const float* rw, float* wout) {
  int m = blockIdx.x, t = threadIdx.x;
  const float* xr = xn + (long long)m * 1024;
  float a[4] = {0.f, 0.f, 0.f, 0.f};
  for (int i = t; i < 1024; i += 256) {
    float xv = xr[i];
    const float* r = rw + i * 4;
    a[0] += xv * r[0]; a[1] += xv * r[1]; a[2] += xv * r[2]; a[3] += xv * r[3];
  }
#pragma unroll
  for (int j = 0; j < 4; ++j) a[j] = blockRed256<false>(a[j]);
  if (t == 0) {
    float mx = fmaxf(fmaxf(a[0], a[1]), fmaxf(a[2], a[3]));
    float e[4]; float s = 0.f;
    for (int j = 0; j < 4; ++j) { e[j] = __expf(a[j] - mx); s += e[j]; }
    const float mix[4] = {0.5f, 0.2f, 0.15f, 0.15f};
    float ws = 0.f;
    for (int j = 0; j < 4; ++j) { e[j] = e[j] / s * mix[j]; ws += e[j]; }
    for (int j = 0; j < 4; ++j) wout[m * 4 + j] = e[j] / ws;
  }
}

DEV float softplus_f(float x) { return x > 15.f ? x : log1pf(__expf(x)); }

__global__ void scanA_k(const float* ssm, const float* A, float* aprod, float* sloc) {
  int blk = blockIdx.x, n = threadIdx.x;
  int c = blk & 63, h = (blk >> 6) & 15, b = blk >> 10;
  float Ah = A[h * 64 + n];
  float ap = 1.f, s = 0.f;
  int l0 = c * 16;
  for (int j = 0; j < 16; ++j) {
    long long off = (long long)(b * 1024 + l0 + j) * 144;
    float d = softplus_f(ssm[off + 128 + h] + ssm[off + n]);
    float a = __expf(d * Ah);
    s = a * s + d * d;
    ap *= a;
  }
  long long o = (long long)blk * 64 + n;
  aprod[o] = ap; sloc[o] = s;
}

__global__ void scanB_k(const float* aprod, const float* sloc, float* cin) {
  int bh = blockIdx.x, n = threadIdx.x;
  float carry = 0.f;
  for (int c = 0; c < 64; ++c) {
    long long o = (long long)(bh * 64 + c) * 64 + n;
    cin[o] = carry;
    carry = aprod[o] * carry + sloc[o];
  }
}

__global__ void scanC_k(const float* ssm, const float* A, const float* cin, float* ysm) {
  int blk = blockIdx.x, n = threadIdx.x;
  int c = blk & 63, h = (blk >> 6) & 15, b = blk >> 10;
  float Ah = A[h * 64 + n];
  float s = cin[(long long)blk * 64 + n];
  int l0 = c * 16;
  for (int j = 0; j < 16; ++j) {
    long long off = (long long)(b * 1024 + l0 + j) * 144;
    float d = softplus_f(ssm[off + 128 + h] + ssm[off + n]);
    float a = __expf(d * Ah);
    s = a * s + d * d;
    float yv = s * ssm[off + 64 + n];
    for (int o2 = 32; o2; o2 >>= 1) yv += __shfl_xor(yv, o2);
    if (n == 0) ysm[(long long)(b * 1024 + l0 + j) * 16 + h] = yv;
  }
}

__global__ void rope_k(const u16* qpre, const u16* kpre, const float* qnw,
                       const float* knw, u16* qro, u16* kro) {
  int rid = blockIdx.x * 4 + (threadIdx.x >> 6);
  int lane = threadIdx.x & 63;
  float v; const float* nw; int l; u16* dst;
  if (rid < 32768) {
    int b = rid >> 14, h = (rid >> 10) & 15; l = rid & 1023;
    v = bf2f(qpre[(long long)(b * 1024 + l) * 1024 + h * 64 + lane]);
    nw = qnw; dst = qro + (long long)rid * 64;
  } else {
    int r2 = rid - 32768;
    int b = r2 >> 12, kvh = (r2 >> 10) & 3; l = r2 & 1023;
    v = bf2f(kpre[(long long)(b * 1024 + l) * 256 + kvh * 64 + lane]);
    nw = knw; dst = kro + (long long)r2 * 64;
  }
  float ss = v * v;
  for (int o = 32; o; o >>= 1) ss += __shfl_xor(ss, o);
  float r = rsqrtf(ss * (1.f / 64.f) + 1e-6f);
  float vn = v * r * nw[lane];
  float pt = __shfl_xor(vn, 32);
  int i = lane & 31;
  float invf = powf(10000.f, -(float)i * (1.f / 32.f));
  float fr = (float)l * invf;
  float o2 = vn * cosf(fr) + ((lane < 32) ? -pt : pt) * sinf(fr);
  dst[lane] = f2bf(o2);
}

__global__ void softmax_k(u16* sc) {
  u16* r = sc + (long long)blockIdx.x * 1024;
  int t = threadIdx.x;
  float v[4]; float mx = -1e30f;
#pragma unroll
  for (int i = 0; i < 4; ++i) { v[i] = bf2f(r[t + i * 256]); mx = fmaxf(mx, v[i]); }
  mx = blockRed256<true>(mx);
  float s = 0.f;
#pragma unroll
  for (int i = 0; i < 4; ++i) { v[i] = __expf(v[i] - mx); s += v[i]; }
  s = blockRed256<false>(s);
  float inv = 1.f / s;
#pragma unroll
  for (int i = 0; i < 4; ++i) r[t + i * 256] = f2bf(v[i] * inv);
}

__global__ void conv_k(const float* xn, const float* dww, const float* dwb, u16* outb) {
  int m = blockIdx.x; int l = m & 1023;
#pragma unroll
  for (int i = 0; i < 4; ++i) {
    int d = threadIdx.x + i * 256;
    float xm = l > 0    ? xn[(long long)(m - 1) * 1024 + d] : 0.f;
    float x0 =            xn[(long long)m * 1024 + d];
    float xp = l < 1023 ? xn[(long long)(m + 1) * 1024 + d] : 0.f;
    float dv = xm * dww[d * 3] + x0 * dww[d * 3 + 1] + xp * dww[d * 3 + 2] + dwb[d];
    outb[(long long)m * 1024 + d] = f2bf(dv / (1.f + __expf(-dv)));
  }
}

__global__ void mix_k(const float* x, const float* w, const float* oss,
                      const float* oat, const float* ocv, const float* mem,
                      float* x2, u16* x2b) {
  int m = blockIdx.x;
  float w0 = w[m * 4], w1 = w[m * 4 + 1], w2 = w[m * 4 + 2], w3 = w[m * 4 + 3];
#pragma unroll
  for (int j = 0; j < 4; ++j) {
    long long i = (long long)m * 1024 + threadIdx.x + j * 256;
    float v = x[i] + w0 * oss[i] + w1 * oat[i] + w2 * ocv[i] + w3 * mem[i];
    x2[i] = v; x2b[i] = f2bf(v);
  }
}

__global__ void moegate_k(const float* x2, const float* n2w, const float* mg, float* wf) {
  int m = blockIdx.x, t = threadIdx.x;
  const float* xr = x2 + (long long)m * 1024;
  float ss = 0.f, a[4] = {0.f, 0.f, 0.f, 0.f};
  for (int i = t; i < 1024; i += 256) {
    float v = xr[i]; ss += v * v;
    float vw = v * n2w[i];
    const float* g = mg + i * 4;
    a[0] += vw * g[0]; a[1] += vw * g[1]; a[2] += vw * g[2]; a[3] += vw * g[3];
  }
  ss = blockRed256<false>(ss);
#pragma unroll
  for (int j = 0; j < 4; ++j) a[j] = blockRed256<false>(a[j]);
  if (t == 0) {
    float r = rsqrtf(ss * (1.f / 1024.f) + 1e-6f);
    float mx = -1e30f;
    for (int j = 0; j < 4; ++j) { a[j] *= r; mx = fmaxf(mx, a[j]); }
    float e[4]; float s = 0.f;
    for (int j = 0; j < 4; ++j) { e[j] = __expf(a[j] - mx); s += e[j]; }
    for (int j = 0; j < 4; ++j) e[j] /= s;
    int i0 = 0;
    for (int j = 1; j < 4; ++j) if (e[j] > e[i0]) i0 = j;
    int i1 = -1;
    for (int j = 0; j < 4; ++j) { if (j == i0) continue; if (i1 < 0 || e[j] > e[i1]) i1 = j; }
    for (int j = 0; j < 4; ++j) wf[m * 4 + j] = (j == i0 || j == i1) ? e[j] : 0.f;
  }
}

__global__ void final_k(const float* x2, const float* m0, const float* m1,
                        const float* m2, const float* m3, float* out) {
  long long i = ((long long)blockIdx.x * 256 + threadIdx.x) * 4;
  float4 a = *(const float4*)(x2 + i);
  float4 b0 = *(const float4*)(m0 + i);
  float4 b1 = *(const float4*)(m1 + i);
  float4 b2 = *(const float4*)(m2 + i);
  float4 b3 = *(const float4*)(m3 + i);
  float4 o{a.x + b0.x + b1.x + b2.x + b3.x, a.y + b0.y + b1.y + b2.y + b3.y,
           a.z + b0.z + b1.z + b2.z + b3.z, a.w + b0.w + b1.w + b2.w + b3.w};
  *(float4*)(out + i) = o;
}

// ------------------------------------------------------------------ host --
extern "C" void kernel_launch(void* const* d_in, const int* in_sizes, int n_in,
                              void* d_out, int out_size, void* d_ws, size_t ws_size,
                              hipStream_t stream) {
  const float* x    = (const float*)d_in[0];
  const float* goal = (const float*)d_in[1];
  const float* mem  = (const float*)d_in[2];
  const float* n1w  = (const float*)d_in[3];
  const float* n2w  = (const float*)d_in[4];
  const float* rw   = (const float*)d_in[5];
  const float* xpw  = (const float*)d_in[6];
  const float* Amat = (const float*)d_in[7];
  const float* Dp   = (const float*)d_in[8];
  const float* gw   = (const float*)d_in[9];
  const float* gb   = (const float*)d_in[10];
  const float* sow  = (const float*)d_in[11];
  const float* qw   = (const float*)d_in[12];
  const float* kw   = (const float*)d_in[13];
  const float* vw   = (const float*)d_in[14];
  const float* ow   = (const float*)d_in[15];
  const float* qnw  = (const float*)d_in[16];
  const float* knw  = (const float*)d_in[17];
  const float* dww  = (const float*)d_in[18];
  const float* dwb  = (const float*)d_in[19];
  const float* pww  = (const float*)d_in[20];
  const float* pwb  = (const float*)d_in[21];
  const float* mgw  = (const float*)d_in[22];
  const float* ew1  = (const float*)d_in[23];
  const float* ew2  = (const float*)d_in[24];
  const float* elw  = (const float*)d_in[25];
  const float* elb  = (const float*)d_in[26];
  float* out = (float*)d_out;

  char* base = (char*)d_ws; size_t off = 0;
  auto alloc = [&](size_t b) { void* p = base + off; off += (b + 255) & ~(size_t)255; return p; };
  // ---- R0: front temporaries (all dead before MoE) — aliased by moe4 ----
  float* xn    = (float*)alloc(2048ull * 1024 * 4);
  u16*   xnb   = (u16*)  alloc(2048ull * 1024 * 2);
  float* wr    = (float*)alloc(2048ull * 4 * 4);
  float* ssm   = (float*)alloc(2048ull * 144 * 4);
  float* aprod = (float*)alloc(2048ull * 64 * 4);
  float* sloc  = (float*)alloc(2048ull * 64 * 4);
  float* cin   = (float*)alloc(2048ull * 64 * 4);
  float* ysm   = (float*)alloc(2048ull * 16 * 4);
  u16*   ssdin = (u16*)  alloc(2048ull * 1024 * 2);
  u16*   qpre  = (u16*)  alloc(2048ull * 1024 * 2);
  u16*   kpre  = (u16*)  alloc(2048ull * 256 * 2);
  u16*   vT    = (u16*)  alloc(2048ull * 256 * 2);
  u16*   qro   = (u16*)  alloc(2048ull * 1024 * 2);
  u16*   kro   = (u16*)  alloc(2048ull * 256 * 2);
  u16*   acat  = (u16*)  alloc(2048ull * 1024 * 2);
  u16*   cva   = (u16*)  alloc(2048ull * 1024 * 2);
  float* moe4  = (float*)base;                     // 32MB alias over R0 (~38MB)
  // ---- persistent past mix ----
  float* x2    = (float*)alloc(2048ull * 1024 * 4);
  u16*   x2b   = (u16*)  alloc(2048ull * 1024 * 2);
  float* wfull = (float*)alloc(2048ull * 4 * 4);
  u16* xpwt = (u16*)alloc(256ull  * 1024 * 2);
  u16* gwt  = (u16*)alloc(1024ull * 1024 * 2);
  u16* sowt = (u16*)alloc(1024ull * 1024 * 2);
  u16* qkvt = (u16*)alloc(1536ull * 1024 * 2);
  u16* owt  = (u16*)alloc(1024ull * 1024 * 2);
  u16* pwwt = (u16*)alloc(1024ull * 1024 * 2);
  // U1 24MB: front = outss|outat|outcv ; MoE = t2_4 (16MB)
  char*  U1    = (char*) alloc(25165824ull);
  float* outss = (float*)U1;
  float* outat = (float*)(U1 + 8388608);
  float* outcv = (float*)(U1 + 16777216);
  u16*   t2_4  = (u16*)  U1;
  // BIG 64MB: scores (attn) ∪ act4 (MoE, 4 x 2048x4096 bf16)
  char* BIG = (char*)alloc(67108864ull);
  u16* scores = (u16*)BIG;
  u16* act4   = (u16*)BIG;
  // EW 32MB: ew1t pair ∪ ew2t4 ∪ ewlt4 (sequential reuse)
  char* EW = (char*)alloc(33554432ull);
  u16* ew1t  = (u16*)EW;
  u16* ew2t4 = (u16*)EW;
  u16* ewlt4 = (u16*)EW;

  // ---- front weight transposes
  wtrans_k<<<dim3(3, 16), 256, 0, stream>>>(xpw, xpwt, 1024, 144, 0);
  wtrans_k<<<dim3(16, 16), 256, 0, stream>>>(gw, gwt, 1024, 1024, 0);
  wtrans_k<<<dim3(16, 16), 256, 0, stream>>>(sow, sowt, 1024, 1024, 0);
  wtrans_k<<<dim3(16, 16), 256, 0, stream>>>(qw, qkvt, 1024, 1024, 0);
  wtrans_k<<<dim3(4, 16), 256, 0, stream>>>(kw, qkvt + 1024ull * 1024, 1024, 256, 0);
  wtrans_k<<<dim3(4, 16), 256, 0, stream>>>(vw, qkvt + 1280ull * 1024, 1024, 256, 0);
  wtrans_k<<<dim3(16, 16), 256, 0, stream>>>(ow, owt, 1024, 1024, 0);
  wtrans_k<<<dim3(16, 16), 256, 0, stream>>>(pww, pwwt, 1024, 1024, 0);

  rms1_k<<<2048, 256, 0, stream>>>(x, goal, n1w, xn, xnb);
  router_k<<<2048, 256, 0, stream>>>(xn, rw, wr);

  { GemmP p{}; p.A = xnb; p.lda = 1024; p.B = xpwt; p.ldb = 1024; p.C = ssm; p.ldc = 144;
    p.M = 2048; p.N = 144; p.K = 1024;
    gemm_k<1, 64><<<dim3(3, 16, 1), 256, 0, stream>>>(p); }

  scanA_k<<<2048, 64, 0, stream>>>(ssm, Amat, aprod, sloc);
  scanB_k<<<32, 64, 0, stream>>>(aprod, sloc, cin);
  scanC_k<<<2048, 64, 0, stream>>>(ssm, Amat, cin, ysm);

  { GemmP p{}; p.A = xnb; p.lda = 1024; p.B = gwt; p.ldb = 1024; p.C = ssdin; p.ldc = 1024;
    p.M = 2048; p.N = 1024; p.K = 1024; p.p0 = gb; p.p1 = ysm; p.p2 = xn; p.p3 = Dp;
    gemm_k<2, 64><<<dim3(16, 16, 1), 256, 0, stream>>>(p); }
  { GemmP p{}; p.A = ssdin; p.lda = 1024; p.B = sowt; p.ldb = 1024; p.C = outss; p.ldc = 1024;
    p.M = 2048; p.N = 1024; p.K = 1024;
    gemm_k<1, 64><<<dim3(16, 16, 1), 256, 0, stream>>>(p); }

  { GemmP p{}; p.A = xnb; p.lda = 1024; p.B = qkvt; p.ldb = 1024; p.C = nullptr; p.ldc = 0;
    p.M = 2048; p.N = 1536; p.K = 1024; p.aux0 = qpre; p.aux1 = kpre; p.aux2 = vT;
    gemm_k<7, 64><<<dim3(24, 16, 1), 256, 0, stream>>>(p); }

  rope_k<<<10240, 256, 0, stream>>>(qpre, kpre, qnw, knw, qro, kro);

  { GemmP p{}; p.A = qro; p.lda = 64; p.sAz = 65536; p.B = kro; p.ldb = 64; p.sBz = 65536;
    p.gqa = 1; p.C = scores; p.ldc = 1024; p.sCz = 1048576;
    p.M = 1024; p.N = 1024; p.K = 64; p.scale = 0.125f;
    gemm_k<5, 128><<<dim3(8, 8, 32), 256, 0, stream>>>(p); }
  softmax_k<<<32768, 256, 0, stream>>>(scores);
  { GemmP p{}; p.A = scores; p.lda = 1024; p.sAz = 1048576; p.B = vT; p.ldb = 1024; p.sBz = 65536;
    p.gqa = 1; p.C = acat; p.ldc = 1024; p.czmode = 1;
    p.M = 1024; p.N = 64; p.K = 1024;
    gemm_k<0, 64><<<dim3(1, 8, 32), 256, 0, stream>>>(p); }
  { GemmP p{}; p.A = acat; p.lda = 1024; p.B = owt; p.ldb = 1024; p.C = outat; p.ldc = 1024;
    p.M = 2048; p.N = 1024; p.K = 1024;
    gemm_k<1, 64><<<dim3(16, 16, 1), 256, 0, stream>>>(p); }

  conv_k<<<2048, 256, 0, stream>>>(xn, dww, dwb, cva);
  { GemmP p{}; p.A = cva; p.lda = 1024; p.B = pwwt; p.ldb = 1024; p.C = outcv; p.ldc = 1024;
    p.M = 2048; p.N = 1024; p.K = 1024; p.p0 = pwb;
    gemm_k<3, 64><<<dim3(16, 16, 1), 256, 0, stream>>>(p); }

  mix_k<<<2048, 256, 0, stream>>>(x, wr, outss, outat, outcv, mem, x2, x2b);
  moegate_k<<<2048, 256, 0, stream>>>(x2, n2w, mgw, wfull);

  // ---- MoE: e_w1 (fused swiglu, 256^2 kernel), e_w2 / e_lin ring-3 ----
  for (int pr = 0; pr < 2; ++pr) {
    int e0 = pr * 2;
    wtrans_k<<<dim3(128, 16), 256, 0, stream>>>(ew1 + (long long)e0 * 8388608, ew1t, 1024, 8192, 1);
    wtrans_k<<<dim3(128, 16), 256, 0, stream>>>(ew1 + (long long)(e0 + 1) * 8388608, ew1t + 8388608ull, 1024, 8192, 1);
    GemmP p{}; p.A = x2b; p.lda = 1024; p.sAz = 0; p.B = ew1t; p.ldb = 1024; p.sBz = 8192ll * 1024;
    p.C = act4 + (long long)e0 * (2048ll * 4096); p.ldc = 4096; p.sCz = 2048ll * 4096;
    p.M = 2048; p.N = 8192; p.K = 1024;
    gemm256sq_k<8><<<dim3(32, 8, 2), 512, 0, stream>>>(p);
  }
  for (int e = 0; e < 4; ++e)
    wtrans_k<<<dim3(16, 64), 256, 0, stream>>>(ew2 + (long long)e * 4194304,
                                               ew2t4 + (long long)e * (1024ll * 4096), 4096, 1024, 0);
  { GemmP p{}; p.A = act4; p.lda = 4096; p.sAz = 2048ll * 4096; p.B = ew2t4; p.ldb = 4096;
    p.sBz = 1024ll * 4096; p.C = t2_4; p.ldc = 1024; p.sCz = 2048ll * 1024;
    p.M = 2048; p.N = 1024; p.K = 4096;
    gemm256_k<0><<<dim3(8, 8, 4), 512, 0, stream>>>(p); }
  for (int e = 0; e < 4; ++e)
    wtrans_k<<<dim3(16, 16), 256, 0, stream>>>(elw + (long long)e * 1048576,
                                               ewlt4 + (long long)e * (1024ll * 1024), 1024, 1024, 0);
  { GemmP p{}; p.A = t2_4; p.lda = 1024; p.sAz = 2048ll * 1024; p.B = ewlt4; p.ldb = 1024;
    p.sBz = 1024ll * 1024; p.C = moe4; p.ldc = 1024; p.sCz = 2048ll * 1024;
    p.M = 2048; p.N = 1024; p.K = 1024; p.p0 = elb; p.p1 = wfull; p.eidx = 0;
    gemm256_k<4><<<dim3(8, 8, 4), 512, 0, stream>>>(p); }

  final_k<<<2048, 256, 0, stream>>>(x2, moe4, moe4 + 2097152, moe4 + 2ull * 2097152,
                                    moe4 + 3ull * 2097152, out);
}